// Round 1
// baseline (583.040 us; speedup 1.0000x reference)
//
#include <hip/hip_runtime.h>
#include <cstdint>
#include <cstddef>

// ---------- types ----------
typedef float f32x4 __attribute__((ext_vector_type(4)));
typedef short bf16x8 __attribute__((ext_vector_type(8)));

typedef __attribute__((address_space(1))) void void_g;
typedef __attribute__((address_space(3))) void void_l;

__device__ __forceinline__ void gld16(const void* g, void* l) {
  // async global->LDS, 16B per lane; LDS dest = wave-uniform base + lane*16
  __builtin_amdgcn_global_load_lds((void_g*)g, (void_l*)l, 16, 0, 0);
}

__device__ __forceinline__ unsigned short f2b(float f) {
  union { float f; uint32_t u; } c; c.f = f;
  uint32_t u = c.u;
  return (unsigned short)((u + 0x7fffu + ((u >> 16) & 1u)) >> 16);  // RNE
}

// ---------- weight cast fp32 -> bf16 ----------
__global__ __launch_bounds__(256) void cast_bf16(const float* __restrict__ src,
                                                 unsigned short* __restrict__ dst,
                                                 int n4) {
  int i = blockIdx.x * 256 + threadIdx.x;
  if (i >= n4) return;
  float4 v = ((const float4*)src)[i];
  ushort4 o;
  o.x = f2b(v.x); o.y = f2b(v.y); o.z = f2b(v.z); o.w = f2b(v.w);
  ((ushort4*)dst)[i] = o;
}

// ---------- LayerNorm (unbiased std, scalar alpha/beta) -> bf16 ----------
__global__ __launch_bounds__(256) void ln_bf16(const float* __restrict__ X,
                                               unsigned short* __restrict__ out,
                                               const float* __restrict__ alpha,
                                               const float* __restrict__ beta) {
  int row = blockIdx.x;
  int tid = threadIdx.x;
  float4 v = ((const float4*)(X + (size_t)row * 1024))[tid];
  float s = v.x + v.y + v.z + v.w;
  float q = v.x * v.x + v.y * v.y + v.z * v.z + v.w * v.w;
#pragma unroll
  for (int m = 1; m < 64; m <<= 1) { s += __shfl_xor(s, m); q += __shfl_xor(q, m); }
  __shared__ float red[8];
  int wave = tid >> 6;
  if ((tid & 63) == 0) { red[wave] = s; red[4 + wave] = q; }
  __syncthreads();
  s = red[0] + red[1] + red[2] + red[3];
  q = red[4] + red[5] + red[6] + red[7];
  float mean = s * (1.0f / 1024.0f);
  float var = fmaxf((q - 1024.0f * mean * mean) * (1.0f / 1023.0f), 0.0f);
  float inv = alpha[0] / (sqrtf(var) + 1e-6f);
  float b = beta[0];
  ushort4 o;
  o.x = f2b((v.x - mean) * inv + b);
  o.y = f2b((v.y - mean) * inv + b);
  o.z = f2b((v.z - mean) * inv + b);
  o.w = f2b((v.w - mean) * inv + b);
  ((ushort4*)(out + (size_t)row * 1024))[tid] = o;
}

// ---------- GEMM: C[M,N] = act(A[M,K] @ W[N,K]^T + bias) (+ fp32 residual) ----------
// 128x128 tile, BK=32, 4 waves (2x2), 4x4 16x16x32 bf16 MFMA frags per wave.
template <int RELU, int RES>
__global__ __launch_bounds__(256) void gemm_bt(const unsigned short* __restrict__ A,
                                               const unsigned short* __restrict__ W,
                                               const float* __restrict__ bias,
                                               const float* __restrict__ resid,
                                               float* __restrict__ outF,
                                               unsigned short* __restrict__ outB,
                                               int M, int N, int K) {
  __shared__ unsigned short Al[128 * 32];
  __shared__ unsigned short Bl[128 * 32];
  int nbn = N >> 7;
  int nwg = gridDim.x;
  int bid = blockIdx.x;
  int wg = (bid & 7) * (nwg >> 3) + (bid >> 3);  // XCD swizzle (nwg % 8 == 0)
  int tm = wg / nbn, tn = wg % nbn;
  int tid = threadIdx.x;
  int wave = tid >> 6, lane = tid & 63;
  int wm = wave >> 1, wn = wave & 1;
  const unsigned short* Ab = A + (size_t)tm * 128 * K;
  const unsigned short* Wb = W + (size_t)tn * 128 * K;
  f32x4 acc[4][4] = {};
  // staging: chunk c = wave*128 + issue*64 + lane; row=c>>2, col=(c&3)*8
  int c0 = wave * 128 + lane;
  int r0 = c0 >> 2, cc0 = (c0 & 3) * 8;
  int c1 = c0 + 64;
  int r1 = c1 >> 2, cc1 = (c1 & 3) * 8;
  int arow = wm * 64 + (lane & 15);
  int brow = wn * 64 + (lane & 15);
  int kf = (lane >> 4) * 8;

  for (int k0 = 0; k0 < K; k0 += 32) {
    __syncthreads();  // prior reads done before overwrite
    gld16(Ab + (size_t)r0 * K + k0 + cc0, &Al[(wave * 128) * 8]);
    gld16(Ab + (size_t)r1 * K + k0 + cc1, &Al[(wave * 128 + 64) * 8]);
    gld16(Wb + (size_t)r0 * K + k0 + cc0, &Bl[(wave * 128) * 8]);
    gld16(Wb + (size_t)r1 * K + k0 + cc1, &Bl[(wave * 128 + 64) * 8]);
    __syncthreads();  // drains vmcnt before barrier
    bf16x8 af[4], bfr[4];
#pragma unroll
    for (int i = 0; i < 4; ++i) af[i] = *(const bf16x8*)&Al[(arow + i * 16) * 32 + kf];
#pragma unroll
    for (int j = 0; j < 4; ++j) bfr[j] = *(const bf16x8*)&Bl[(brow + j * 16) * 32 + kf];
#pragma unroll
    for (int i = 0; i < 4; ++i)
#pragma unroll
      for (int j = 0; j < 4; ++j)
        acc[i][j] = __builtin_amdgcn_mfma_f32_16x16x32_bf16(af[i], bfr[j], acc[i][j], 0, 0, 0);
  }

  int row0 = tm * 128 + wm * 64 + (lane >> 4) * 4;
  int col0 = tn * 128 + wn * 64 + (lane & 15);
#pragma unroll
  for (int i = 0; i < 4; ++i) {
#pragma unroll
    for (int j = 0; j < 4; ++j) {
      int col = col0 + j * 16;
      float bb = bias[col];
#pragma unroll
      for (int r = 0; r < 4; ++r) {
        int row = row0 + i * 16 + r;
        float v = acc[i][j][r] + bb;
        if (RELU) v = fmaxf(v, 0.0f);
        size_t idx = (size_t)row * N + col;
        if (RES) outF[idx] = resid[idx] + v;
        else outB[idx] = f2b(v);
      }
    }
  }
}

// ---------- flash attention: 1 block = (b, h, 64-row q-tile), 4 waves x 16 rows ----------
__global__ __launch_bounds__(256) void attn_fwd(const unsigned short* __restrict__ Q,
                                                const unsigned short* __restrict__ Kg,
                                                const unsigned short* __restrict__ Vg,
                                                const int* __restrict__ mask,
                                                unsigned short* __restrict__ O) {
  __shared__ unsigned short Kl[64 * 72];      // [key][d], +8 pad vs stride-128B conflicts
  __shared__ unsigned short Vt[64 * 72];      // [d][key] transposed
  __shared__ unsigned short Pl[4][16 * 72];   // per-wave P relayout buffer
  int bid = blockIdx.x;
  int qt = bid & 15;
  int bh = bid >> 4;
  int b = bh >> 4, h = bh & 15;
  int tid = threadIdx.x, wave = tid >> 6, lane = tid & 63;
  int l15 = lane & 15, l4 = lane >> 4;
  int q0 = qt * 64;

  const unsigned short* Qrow = Q + ((size_t)(b * 1024 + q0 + wave * 16 + l15)) * 1024 + h * 64;
  bf16x8 qf0 = *(const bf16x8*)(Qrow + l4 * 8);
  bf16x8 qf1 = *(const bf16x8*)(Qrow + 32 + l4 * 8);

  float m_r[4], l_r[4];
  f32x4 o[4] = {};
#pragma unroll
  for (int r = 0; r < 4; ++r) { m_r[r] = -1e30f; l_r[r] = 0.0f; }

  int srow = tid >> 2;          // 0..63 key (or row)
  int scol = (tid & 3) * 16;    // 0,16,32,48 along d
  const float scale = 0.125f;

  for (int kt = 0; kt < 16; ++kt) {
    __syncthreads();
    // stage K tile [64 keys][64 d]
    const unsigned short* Ks = Kg + ((size_t)(b * 1024 + kt * 64 + srow)) * 1024 + h * 64 + scol;
    bf16x8 k0v = *(const bf16x8*)Ks;
    bf16x8 k1v = *(const bf16x8*)(Ks + 8);
    *(bf16x8*)&Kl[srow * 72 + scol] = k0v;
    *(bf16x8*)&Kl[srow * 72 + scol + 8] = k1v;
    // stage V transposed -> Vt[d][key]
    const unsigned short* Vs = Vg + ((size_t)(b * 1024 + kt * 64 + srow)) * 1024 + h * 64 + scol;
    bf16x8 v0 = *(const bf16x8*)Vs;
    bf16x8 v1 = *(const bf16x8*)(Vs + 8);
#pragma unroll
    for (int e = 0; e < 8; ++e) {
      Vt[(scol + e) * 72 + srow] = (unsigned short)v0[e];
      Vt[(scol + 8 + e) * 72 + srow] = (unsigned short)v1[e];
    }
    __syncthreads();

    // QK^T: S[16 q x 64 keys] per wave
    f32x4 s[4];
#pragma unroll
    for (int j = 0; j < 4; ++j) {
      bf16x8 kb0 = *(const bf16x8*)&Kl[(j * 16 + l15) * 72 + l4 * 8];
      bf16x8 kb1 = *(const bf16x8*)&Kl[(j * 16 + l15) * 72 + 32 + l4 * 8];
      f32x4 z = {};
      s[j] = __builtin_amdgcn_mfma_f32_16x16x32_bf16(qf0, kb0, z, 0, 0, 0);
      s[j] = __builtin_amdgcn_mfma_f32_16x16x32_bf16(qf1, kb1, s[j], 0, 0, 0);
    }

    // online softmax (rows live across 16-lane groups; reduce via shfl_xor)
    float sv[4][4], tmax[4];
#pragma unroll
    for (int r = 0; r < 4; ++r) tmax[r] = -1e30f;
#pragma unroll
    for (int j = 0; j < 4; ++j) {
      int key = kt * 64 + j * 16 + l15;
      int mk = mask[b * 1024 + key];
#pragma unroll
      for (int r = 0; r < 4; ++r) {
        float v = s[j][r] * scale;
        if (mk == 0) v = -1e9f;
        sv[j][r] = v;
        tmax[r] = fmaxf(tmax[r], v);
      }
    }
#pragma unroll
    for (int r = 0; r < 4; ++r)
#pragma unroll
      for (int mm = 1; mm < 16; mm <<= 1) tmax[r] = fmaxf(tmax[r], __shfl_xor(tmax[r], mm));

    float sc[4], lt[4];
#pragma unroll
    for (int r = 0; r < 4; ++r) {
      float mnew = fmaxf(m_r[r], tmax[r]);
      sc[r] = __expf(m_r[r] - mnew);
      m_r[r] = mnew;
      lt[r] = 0.0f;
    }
    unsigned short pb[4][4];
#pragma unroll
    for (int j = 0; j < 4; ++j)
#pragma unroll
      for (int r = 0; r < 4; ++r) {
        float p = __expf(sv[j][r] - m_r[r]);
        lt[r] += p;
        pb[j][r] = f2b(p);
      }
#pragma unroll
    for (int r = 0; r < 4; ++r) {
#pragma unroll
      for (int mm = 1; mm < 16; mm <<= 1) lt[r] += __shfl_xor(lt[r], mm);
      l_r[r] = l_r[r] * sc[r] + lt[r];
    }
#pragma unroll
    for (int d = 0; d < 4; ++d)
#pragma unroll
      for (int r = 0; r < 4; ++r) o[d][r] *= sc[r];

    // P -> per-wave LDS (C-layout) and back as A-frags (within-wave, in-order LDS)
#pragma unroll
    for (int j = 0; j < 4; ++j)
#pragma unroll
      for (int r = 0; r < 4; ++r)
        Pl[wave][(l4 * 4 + r) * 72 + j * 16 + l15] = pb[j][r];

#pragma unroll
    for (int kk = 0; kk < 2; ++kk) {
      bf16x8 pa = *(const bf16x8*)&Pl[wave][l15 * 72 + kk * 32 + l4 * 8];
#pragma unroll
      for (int d = 0; d < 4; ++d) {
        bf16x8 vb = *(const bf16x8*)&Vt[(d * 16 + l15) * 72 + kk * 32 + l4 * 8];
        o[d] = __builtin_amdgcn_mfma_f32_16x16x32_bf16(pa, vb, o[d], 0, 0, 0);
      }
    }
  }

  int orow = b * 1024 + q0 + wave * 16 + l4 * 4;
#pragma unroll
  for (int d = 0; d < 4; ++d)
#pragma unroll
    for (int r = 0; r < 4; ++r) {
      float v = o[d][r] / l_r[r];
      O[((size_t)(orow + r)) * 1024 + h * 64 + d * 16 + l15] = f2b(v);
    }
}

// ---------- launch ----------
extern "C" void kernel_launch(void* const* d_in, const int* in_sizes, int n_in,
                              void* d_out, int out_size, void* d_ws, size_t ws_size,
                              hipStream_t stream) {
  const float* X = (const float*)d_in[0];
  const int* mask = (const int*)d_in[1];
  const float* wq = (const float*)d_in[2];
  const float* bq = (const float*)d_in[3];
  const float* wk = (const float*)d_in[4];
  const float* bk = (const float*)d_in[5];
  const float* wv = (const float*)d_in[6];
  const float* bv = (const float*)d_in[7];
  const float* wo = (const float*)d_in[8];
  const float* bo = (const float*)d_in[9];
  const float* w1 = (const float*)d_in[10];
  const float* b1 = (const float*)d_in[11];
  const float* w2 = (const float*)d_in[12];
  const float* b2 = (const float*)d_in[13];
  const float* ln1a = (const float*)d_in[14];
  const float* ln1b = (const float*)d_in[15];
  const float* ln2a = (const float*)d_in[16];
  const float* ln2b = (const float*)d_in[17];
  float* out = (float*)d_out;
  char* ws = (char*)d_ws;
  const size_t MB = 1024 * 1024;

  unsigned short* wq_b = (unsigned short*)(ws + 0 * MB);
  unsigned short* wk_b = (unsigned short*)(ws + 2 * MB);
  unsigned short* wv_b = (unsigned short*)(ws + 4 * MB);
  unsigned short* wo_b = (unsigned short*)(ws + 6 * MB);
  unsigned short* w1_b = (unsigned short*)(ws + 8 * MB);
  unsigned short* w2_b = (unsigned short*)(ws + 16 * MB);
  unsigned short* xn = (unsigned short*)(ws + 24 * MB);   // LN1 out, then attn O
  unsigned short* Qb = (unsigned short*)(ws + 40 * MB);   // Q, then LN2 out
  unsigned short* Kb = (unsigned short*)(ws + 56 * MB);   // K, then FFN h chunk (32MB w/ Vb)
  unsigned short* Vb = (unsigned short*)(ws + 72 * MB);   // V
  unsigned short* hb = Kb;

  // weights -> bf16
  cast_bf16<<<1024, 256, 0, stream>>>(wq, wq_b, 262144);
  cast_bf16<<<1024, 256, 0, stream>>>(wk, wk_b, 262144);
  cast_bf16<<<1024, 256, 0, stream>>>(wv, wv_b, 262144);
  cast_bf16<<<1024, 256, 0, stream>>>(wo, wo_b, 262144);
  cast_bf16<<<4096, 256, 0, stream>>>(w1, w1_b, 1048576);
  cast_bf16<<<4096, 256, 0, stream>>>(w2, w2_b, 1048576);

  // LN1
  ln_bf16<<<8192, 256, 0, stream>>>(X, xn, ln1a, ln1b);
  // QKV
  gemm_bt<0, 0><<<512, 256, 0, stream>>>(xn, wq_b, bq, nullptr, nullptr, Qb, 8192, 1024, 1024);
  gemm_bt<0, 0><<<512, 256, 0, stream>>>(xn, wk_b, bk, nullptr, nullptr, Kb, 8192, 1024, 1024);
  gemm_bt<0, 0><<<512, 256, 0, stream>>>(xn, wv_b, bv, nullptr, nullptr, Vb, 8192, 1024, 1024);
  // attention (writes O into xn buffer)
  attn_fwd<<<2048, 256, 0, stream>>>(Qb, Kb, Vb, mask, xn);
  // out = X + O @ wo^T + bo
  gemm_bt<0, 1><<<512, 256, 0, stream>>>(xn, wo_b, bo, X, out, nullptr, 8192, 1024, 1024);
  // LN2 (reads out, writes into Qb)
  ln_bf16<<<8192, 256, 0, stream>>>(out, Qb, ln2a, ln2b);
  // FFN in two 4096-row chunks (h reuses Kb+Vb = 32MB)
  for (int c = 0; c < 2; ++c) {
    const unsigned short* a2 = Qb + (size_t)c * 4096 * 1024;
    float* outc = out + (size_t)c * 4096 * 1024;
    gemm_bt<1, 0><<<1024, 256, 0, stream>>>(a2, w1_b, b1, nullptr, nullptr, hb, 4096, 4096, 1024);
    gemm_bt<0, 1><<<256, 256, 0, stream>>>(hb, w2_b, b2, outc, outc, nullptr, 4096, 1024, 4096);
  }
}

// Round 2
// 532.183 us; speedup vs baseline: 1.0956x; 1.0956x over previous
//
#include <hip/hip_runtime.h>
#include <cstdint>
#include <cstddef>

// ---------- types ----------
typedef float f32x4 __attribute__((ext_vector_type(4)));
typedef short bf16x8 __attribute__((ext_vector_type(8)));
typedef short bf16x4 __attribute__((ext_vector_type(4)));

typedef __attribute__((address_space(1))) void void_g;
typedef __attribute__((address_space(3))) void void_l;

__device__ __forceinline__ void gld16(const void* g, void* l) {
  // async global->LDS, 16B per lane; LDS dest = wave-uniform base + lane*16
  __builtin_amdgcn_global_load_lds((void_g*)g, (void_l*)l, 16, 0, 0);
}

__device__ __forceinline__ unsigned short f2b(float f) {
  union { float f; uint32_t u; } c; c.f = f;
  uint32_t u = c.u;
  return (unsigned short)((u + 0x7fffu + ((u >> 16) & 1u)) >> 16);  // RNE
}

__device__ __forceinline__ uint32_t pk2(float lo, float hi) {
  return ((uint32_t)f2b(hi) << 16) | (uint32_t)f2b(lo);
}

// ---------- weight cast fp32 -> bf16 ----------
__global__ __launch_bounds__(256) void cast_bf16(const float* __restrict__ src,
                                                 unsigned short* __restrict__ dst,
                                                 int n4) {
  int i = blockIdx.x * 256 + threadIdx.x;
  if (i >= n4) return;
  float4 v = ((const float4*)src)[i];
  ushort4 o;
  o.x = f2b(v.x); o.y = f2b(v.y); o.z = f2b(v.z); o.w = f2b(v.w);
  ((ushort4*)dst)[i] = o;
}

// ---------- LayerNorm (unbiased std, scalar alpha/beta) -> bf16 ----------
__global__ __launch_bounds__(256) void ln_bf16(const float* __restrict__ X,
                                               unsigned short* __restrict__ out,
                                               const float* __restrict__ alpha,
                                               const float* __restrict__ beta) {
  int row = blockIdx.x;
  int tid = threadIdx.x;
  float4 v = ((const float4*)(X + (size_t)row * 1024))[tid];
  float s = v.x + v.y + v.z + v.w;
  float q = v.x * v.x + v.y * v.y + v.z * v.z + v.w * v.w;
#pragma unroll
  for (int m = 1; m < 64; m <<= 1) { s += __shfl_xor(s, m); q += __shfl_xor(q, m); }
  __shared__ float red[8];
  int wave = tid >> 6;
  if ((tid & 63) == 0) { red[wave] = s; red[4 + wave] = q; }
  __syncthreads();
  s = red[0] + red[1] + red[2] + red[3];
  q = red[4] + red[5] + red[6] + red[7];
  float mean = s * (1.0f / 1024.0f);
  float var = fmaxf((q - 1024.0f * mean * mean) * (1.0f / 1023.0f), 0.0f);
  float inv = alpha[0] / (sqrtf(var) + 1e-6f);
  float b = beta[0];
  ushort4 o;
  o.x = f2b((v.x - mean) * inv + b);
  o.y = f2b((v.y - mean) * inv + b);
  o.z = f2b((v.z - mean) * inv + b);
  o.w = f2b((v.w - mean) * inv + b);
  ((ushort4*)(out + (size_t)row * 1024))[tid] = o;
}

// ---------- GEMM: C[M,N] = act(A[M,K] @ W[N,K]^T + bias) (+ fp32 residual) ----------
// 128x128 tile, BK=32, 4 waves (2x2), 4x4 16x16x32 bf16 MFMA frags per wave.
// ROWBIAS: bias indexed by output row (for the transposed-V GEMM).
template <int RELU, int RES, int ROWBIAS>
__global__ __launch_bounds__(256) void gemm_bt(const unsigned short* __restrict__ A,
                                               const unsigned short* __restrict__ W,
                                               const float* __restrict__ bias,
                                               const float* __restrict__ resid,
                                               float* __restrict__ outF,
                                               unsigned short* __restrict__ outB,
                                               int M, int N, int K) {
  __shared__ unsigned short Al[128 * 32];
  __shared__ unsigned short Bl[128 * 32];
  int nbn = N >> 7;
  int nwg = gridDim.x;
  int bid = blockIdx.x;
  int wg = (bid & 7) * (nwg >> 3) + (bid >> 3);  // XCD swizzle (nwg % 8 == 0)
  int tm = wg / nbn, tn = wg % nbn;
  int tid = threadIdx.x;
  int wave = tid >> 6, lane = tid & 63;
  int wm = wave >> 1, wn = wave & 1;
  const unsigned short* Ab = A + (size_t)tm * 128 * K;
  const unsigned short* Wb = W + (size_t)tn * 128 * K;
  f32x4 acc[4][4] = {};
  int c0 = wave * 128 + lane;
  int r0 = c0 >> 2, cc0 = (c0 & 3) * 8;
  int c1 = c0 + 64;
  int r1 = c1 >> 2, cc1 = (c1 & 3) * 8;
  int arow = wm * 64 + (lane & 15);
  int brow = wn * 64 + (lane & 15);
  int kf = (lane >> 4) * 8;

  for (int k0 = 0; k0 < K; k0 += 32) {
    __syncthreads();
    gld16(Ab + (size_t)r0 * K + k0 + cc0, &Al[(wave * 128) * 8]);
    gld16(Ab + (size_t)r1 * K + k0 + cc1, &Al[(wave * 128 + 64) * 8]);
    gld16(Wb + (size_t)r0 * K + k0 + cc0, &Bl[(wave * 128) * 8]);
    gld16(Wb + (size_t)r1 * K + k0 + cc1, &Bl[(wave * 128 + 64) * 8]);
    __syncthreads();
    bf16x8 af[4], bfr[4];
#pragma unroll
    for (int i = 0; i < 4; ++i) af[i] = *(const bf16x8*)&Al[(arow + i * 16) * 32 + kf];
#pragma unroll
    for (int j = 0; j < 4; ++j) bfr[j] = *(const bf16x8*)&Bl[(brow + j * 16) * 32 + kf];
#pragma unroll
    for (int i = 0; i < 4; ++i)
#pragma unroll
      for (int j = 0; j < 4; ++j)
        acc[i][j] = __builtin_amdgcn_mfma_f32_16x16x32_bf16(af[i], bfr[j], acc[i][j], 0, 0, 0);
  }

  int row0 = tm * 128 + wm * 64 + (lane >> 4) * 4;
  int col0 = tn * 128 + wn * 64 + (lane & 15);
#pragma unroll
  for (int i = 0; i < 4; ++i) {
#pragma unroll
    for (int j = 0; j < 4; ++j) {
      int col = col0 + j * 16;
      float bb = ROWBIAS ? 0.0f : bias[col];
#pragma unroll
      for (int r = 0; r < 4; ++r) {
        int row = row0 + i * 16 + r;
        float v = acc[i][j][r] + (ROWBIAS ? bias[row] : bb);
        if (RELU) v = fmaxf(v, 0.0f);
        size_t idx = (size_t)row * N + col;
        if (RES) outF[idx] = resid[idx] + v;
        else outB[idx] = f2b(v);
      }
    }
  }
}

// ---------- flash attention v2: swapped QK^T, register P, V^T from global ----------
// Q [b*1024+s][1024] bf16, K [b*1024+s][1024] bf16, Vt [h*64+d][b*1024+s] bf16.
// 1 block = (b,h,64-q-tile); 4 waves x 16 q-rows. KV tile = 64 keys.
// LDS tiles [64][64] linear, chunk-XOR-swizzled via pre-swizzled global source.
__global__ __launch_bounds__(256) void attn_fwd2(const unsigned short* __restrict__ Q,
                                                 const unsigned short* __restrict__ Kg,
                                                 const unsigned short* __restrict__ Vt,
                                                 const int* __restrict__ mask,
                                                 unsigned short* __restrict__ O) {
  __shared__ unsigned short Kl[64 * 64];
  __shared__ unsigned short Vl[64 * 64];
  __shared__ float biasl[1024];
  int bid = blockIdx.x;
  int wg = (bid & 7) * 256 + (bid >> 3);  // XCD swizzle: a head's 16 q-tiles on one XCD
  int qt = wg & 15, bh = wg >> 4;
  int b = bh >> 4, h = bh & 15;
  int tid = threadIdx.x, wave = tid >> 6, lane = tid & 63;
  int l15 = lane & 15, g = lane >> 4;
  int q0 = qt * 64;

  // mask -> additive bias in LDS (one row per b)
  for (int i = tid; i < 1024; i += 256) biasl[i] = (mask[b * 1024 + i] == 0) ? -1e9f : 0.0f;

  // Q fragments: wave owns q rows q0+wave*16+l15; B-frag k = g*8+e over d
  const unsigned short* Qrow = Q + ((size_t)(b * 1024 + q0 + wave * 16 + l15)) * 1024 + h * 64;
  bf16x8 qf0 = *(const bf16x8*)(Qrow + g * 8);
  bf16x8 qf1 = *(const bf16x8*)(Qrow + 32 + g * 8);

  float m_q = -1e30f, l_q = 0.0f;  // softmax stats for q = l15 (lane-local)
  f32x4 o[4] = {};                 // o[dt][r]: O[q=g*4+r][dt*16+l15]

  // staging: lane -> (row-within-8, chunk-pos); fetch logical chunk pos^row (XOR swizzle)
  int srow = lane >> 3;
  int clog = (lane & 7) ^ srow;
  int h7 = l15 & 7;
  const float scale = 0.125f;  // 1/sqrt(64)

  for (int kt = 0; kt < 16; ++kt) {
    __syncthreads();
    // stage K tile [64 keys][64 d] and V^T tile [64 d][64 keys], swizzled
#pragma unroll
    for (int i = 0; i < 2; ++i) {
      int rk = wave * 16 + i * 8 + srow;  // rk & 7 == srow
      gld16(Kg + ((size_t)(b * 1024 + kt * 64 + rk)) * 1024 + h * 64 + clog * 8,
            &Kl[(wave * 16 + i * 8) * 64]);
      gld16(Vt + ((size_t)(h * 64 + rk)) * 8192 + b * 1024 + kt * 64 + clog * 8,
            &Vl[(wave * 16 + i * 8) * 64]);
    }
    __syncthreads();

    // S^T[key][q] = mfma(A=K, B=Q): lane holds q=l15, keys j*16+g*4+r
    f32x4 st[4];
#pragma unroll
    for (int j = 0; j < 4; ++j) {
      int kr = j * 16 + l15;
      bf16x8 ka = *(const bf16x8*)&Kl[kr * 64 + ((g ^ h7) * 8)];
      bf16x8 kb = *(const bf16x8*)&Kl[kr * 64 + (((4 + g) ^ h7) * 8)];
      f32x4 z = {};
      st[j] = __builtin_amdgcn_mfma_f32_16x16x32_bf16(ka, qf0, z, 0, 0, 0);
      st[j] = __builtin_amdgcn_mfma_f32_16x16x32_bf16(kb, qf1, st[j], 0, 0, 0);
    }

    // scale + mask bias; in-lane max over 16 keys + 2 shuffles
    float p[4][4];
    float tmax = -1e30f;
#pragma unroll
    for (int j = 0; j < 4; ++j) {
      float4 b4 = *(const float4*)&biasl[kt * 64 + j * 16 + g * 4];
#pragma unroll
      for (int r = 0; r < 4; ++r) {
        float v = st[j][r] * scale + ((const float*)&b4)[r];
        p[j][r] = v;
        tmax = fmaxf(tmax, v);
      }
    }
    tmax = fmaxf(tmax, __shfl_xor(tmax, 16));
    tmax = fmaxf(tmax, __shfl_xor(tmax, 32));
    float mnew = fmaxf(m_q, tmax);
    float scq = __expf(m_q - mnew);
    m_q = mnew;
    float lsum = 0.0f;
#pragma unroll
    for (int j = 0; j < 4; ++j)
#pragma unroll
      for (int r = 0; r < 4; ++r) {
        float e = __expf(p[j][r] - mnew);
        p[j][r] = e;
        lsum += e;
      }
    lsum += __shfl_xor(lsum, 16);
    lsum += __shfl_xor(lsum, 32);
    l_q = l_q * scq + lsum;

    // rescale O: o rows are q=g*4+r; fetch scq from lane (g*4+r)
    float sc0 = __shfl(scq, g * 4 + 0);
    float sc1 = __shfl(scq, g * 4 + 1);
    float sc2 = __shfl(scq, g * 4 + 2);
    float sc3 = __shfl(scq, g * 4 + 3);
#pragma unroll
    for (int dt = 0; dt < 4; ++dt) {
      o[dt][0] *= sc0; o[dt][1] *= sc1; o[dt][2] *= sc2; o[dt][3] *= sc3;
    }

    // pack P into A-frags: pa[kk] element e: key = 32kk + 16*(e>>2) + 4g + (e&3)
    union U8 { uint32_t u[4]; bf16x8 v; } pa[2];
#pragma unroll
    for (int j = 0; j < 4; ++j) {
      pa[j >> 1].u[(j & 1) * 2 + 0] = pk2(p[j][0], p[j][1]);
      pa[j >> 1].u[(j & 1) * 2 + 1] = pk2(p[j][2], p[j][3]);
    }

    // PV: B-frags from V^T in matching permuted key order (two b64 per frag)
#pragma unroll
    for (int kk = 0; kk < 2; ++kk) {
#pragma unroll
      for (int dt = 0; dt < 4; ++dt) {
        int vr = dt * 16 + l15;
        bf16x4 lo = *(const bf16x4*)&Vl[vr * 64 + (((4 * kk + (g >> 1)) ^ h7) * 8) + (g & 1) * 4];
        bf16x4 hi = *(const bf16x4*)&Vl[vr * 64 + (((4 * kk + 2 + (g >> 1)) ^ h7) * 8) + (g & 1) * 4];
        bf16x8 vb;
#pragma unroll
        for (int e = 0; e < 4; ++e) { vb[e] = lo[e]; vb[e + 4] = hi[e]; }
        o[dt] = __builtin_amdgcn_mfma_f32_16x16x32_bf16(pa[kk].v, vb, o[dt], 0, 0, 0);
      }
    }
  }

  // epilogue: divide by l (per row q=g*4+r) and store
  float lb0 = __shfl(l_q, g * 4 + 0);
  float lb1 = __shfl(l_q, g * 4 + 1);
  float lb2 = __shfl(l_q, g * 4 + 2);
  float lb3 = __shfl(l_q, g * 4 + 3);
  float inv0 = 1.0f / lb0, inv1 = 1.0f / lb1, inv2 = 1.0f / lb2, inv3 = 1.0f / lb3;
  size_t obase = ((size_t)(b * 1024 + q0 + wave * 16 + g * 4)) * 1024 + h * 64 + l15;
#pragma unroll
  for (int dt = 0; dt < 4; ++dt) {
    O[obase + (size_t)0 * 1024 + dt * 16] = f2b(o[dt][0] * inv0);
    O[obase + (size_t)1 * 1024 + dt * 16] = f2b(o[dt][1] * inv1);
    O[obase + (size_t)2 * 1024 + dt * 16] = f2b(o[dt][2] * inv2);
    O[obase + (size_t)3 * 1024 + dt * 16] = f2b(o[dt][3] * inv3);
  }
}

// ---------- launch ----------
extern "C" void kernel_launch(void* const* d_in, const int* in_sizes, int n_in,
                              void* d_out, int out_size, void* d_ws, size_t ws_size,
                              hipStream_t stream) {
  const float* X = (const float*)d_in[0];
  const int* mask = (const int*)d_in[1];
  const float* wq = (const float*)d_in[2];
  const float* bq = (const float*)d_in[3];
  const float* wk = (const float*)d_in[4];
  const float* bk = (const float*)d_in[5];
  const float* wv = (const float*)d_in[6];
  const float* bv = (const float*)d_in[7];
  const float* wo = (const float*)d_in[8];
  const float* bo = (const float*)d_in[9];
  const float* w1 = (const float*)d_in[10];
  const float* b1 = (const float*)d_in[11];
  const float* w2 = (const float*)d_in[12];
  const float* b2 = (const float*)d_in[13];
  const float* ln1a = (const float*)d_in[14];
  const float* ln1b = (const float*)d_in[15];
  const float* ln2a = (const float*)d_in[16];
  const float* ln2b = (const float*)d_in[17];
  float* out = (float*)d_out;
  char* ws = (char*)d_ws;
  const size_t MB = 1024 * 1024;

  unsigned short* wq_b = (unsigned short*)(ws + 0 * MB);
  unsigned short* wk_b = (unsigned short*)(ws + 2 * MB);
  unsigned short* wv_b = (unsigned short*)(ws + 4 * MB);
  unsigned short* wo_b = (unsigned short*)(ws + 6 * MB);
  unsigned short* w1_b = (unsigned short*)(ws + 8 * MB);
  unsigned short* w2_b = (unsigned short*)(ws + 16 * MB);
  unsigned short* xn = (unsigned short*)(ws + 24 * MB);   // LN1 out, then attn O
  unsigned short* Qb = (unsigned short*)(ws + 40 * MB);   // Q, then LN2 out
  unsigned short* Kb = (unsigned short*)(ws + 56 * MB);   // K, then FFN h chunk
  unsigned short* Vtb = (unsigned short*)(ws + 72 * MB);  // V^T [1024 hd][8192 tok]
  unsigned short* hb = Kb;

  // weights -> bf16
  cast_bf16<<<1024, 256, 0, stream>>>(wq, wq_b, 262144);
  cast_bf16<<<1024, 256, 0, stream>>>(wk, wk_b, 262144);
  cast_bf16<<<1024, 256, 0, stream>>>(wv, wv_b, 262144);
  cast_bf16<<<1024, 256, 0, stream>>>(wo, wo_b, 262144);
  cast_bf16<<<4096, 256, 0, stream>>>(w1, w1_b, 1048576);
  cast_bf16<<<4096, 256, 0, stream>>>(w2, w2_b, 1048576);

  // LN1
  ln_bf16<<<8192, 256, 0, stream>>>(X, xn, ln1a, ln1b);
  // Q, K as [token][hd]; V transposed: Vt[hd][token] = wv @ xn^T + bv (row bias)
  gemm_bt<0, 0, 0><<<512, 256, 0, stream>>>(xn, wq_b, bq, nullptr, nullptr, Qb, 8192, 1024, 1024);
  gemm_bt<0, 0, 0><<<512, 256, 0, stream>>>(xn, wk_b, bk, nullptr, nullptr, Kb, 8192, 1024, 1024);
  gemm_bt<0, 0, 1><<<512, 256, 0, stream>>>(wv_b, xn, bv, nullptr, nullptr, Vtb, 1024, 8192, 1024);
  // attention (writes O into xn buffer)
  attn_fwd2<<<2048, 256, 0, stream>>>(Qb, Kb, Vtb, mask, xn);
  // out = X + O @ wo^T + bo
  gemm_bt<0, 1, 0><<<512, 256, 0, stream>>>(xn, wo_b, bo, X, out, nullptr, 8192, 1024, 1024);
  // LN2 (reads out, writes into Qb)
  ln_bf16<<<8192, 256, 0, stream>>>(out, Qb, ln2a, ln2b);
  // FFN in two 4096-row chunks (h reuses Kb+Vtb region = 32MB)
  for (int c = 0; c < 2; ++c) {
    const unsigned short* a2 = Qb + (size_t)c * 4096 * 1024;
    float* outc = out + (size_t)c * 4096 * 1024;
    gemm_bt<1, 0, 0><<<1024, 256, 0, stream>>>(a2, w1_b, b1, nullptr, nullptr, hb, 4096, 4096, 1024);
    gemm_bt<0, 1, 0><<<256, 256, 0, stream>>>(hb, w2_b, b2, outc, outc, nullptr, 4096, 1024, 4096);
  }
}

// Round 3
// 484.274 us; speedup vs baseline: 1.2039x; 1.0989x over previous
//
#include <hip/hip_runtime.h>
#include <cstdint>
#include <cstddef>

// ---------- types ----------
typedef float f32x4 __attribute__((ext_vector_type(4)));
typedef short bf16x8 __attribute__((ext_vector_type(8)));
typedef short bf16x4 __attribute__((ext_vector_type(4)));

typedef __attribute__((address_space(1))) void void_g;
typedef __attribute__((address_space(3))) void void_l;

__device__ __forceinline__ void gld16(const void* g, void* l) {
  // async global->LDS, 16B per lane; LDS dest = wave-uniform base + lane*16
  __builtin_amdgcn_global_load_lds((void_g*)g, (void_l*)l, 16, 0, 0);
}

__device__ __forceinline__ unsigned short f2b(float f) {
  union { float f; uint32_t u; } c; c.f = f;
  uint32_t u = c.u;
  return (unsigned short)((u + 0x7fffu + ((u >> 16) & 1u)) >> 16);  // RNE
}

__device__ __forceinline__ uint32_t pk2(float lo, float hi) {
  return ((uint32_t)f2b(hi) << 16) | (uint32_t)f2b(lo);
}

// ---------- weight cast fp32 -> bf16 ----------
__global__ __launch_bounds__(256) void cast_bf16(const float* __restrict__ src,
                                                 unsigned short* __restrict__ dst,
                                                 int n4) {
  int i = blockIdx.x * 256 + threadIdx.x;
  if (i >= n4) return;
  float4 v = ((const float4*)src)[i];
  ushort4 o;
  o.x = f2b(v.x); o.y = f2b(v.y); o.z = f2b(v.z); o.w = f2b(v.w);
  ((ushort4*)dst)[i] = o;
}

// ---------- LayerNorm (unbiased std, scalar alpha/beta) -> bf16 ----------
__global__ __launch_bounds__(256) void ln_bf16(const float* __restrict__ X,
                                               unsigned short* __restrict__ out,
                                               const float* __restrict__ alpha,
                                               const float* __restrict__ beta) {
  int row = blockIdx.x;
  int tid = threadIdx.x;
  float4 v = ((const float4*)(X + (size_t)row * 1024))[tid];
  float s = v.x + v.y + v.z + v.w;
  float q = v.x * v.x + v.y * v.y + v.z * v.z + v.w * v.w;
#pragma unroll
  for (int m = 1; m < 64; m <<= 1) { s += __shfl_xor(s, m); q += __shfl_xor(q, m); }
  __shared__ float red[8];
  int wave = tid >> 6;
  if ((tid & 63) == 0) { red[wave] = s; red[4 + wave] = q; }
  __syncthreads();
  s = red[0] + red[1] + red[2] + red[3];
  q = red[4] + red[5] + red[6] + red[7];
  float mean = s * (1.0f / 1024.0f);
  float var = fmaxf((q - 1024.0f * mean * mean) * (1.0f / 1023.0f), 0.0f);
  float inv = alpha[0] / (sqrtf(var) + 1e-6f);
  float b = beta[0];
  ushort4 o;
  o.x = f2b((v.x - mean) * inv + b);
  o.y = f2b((v.y - mean) * inv + b);
  o.z = f2b((v.z - mean) * inv + b);
  o.w = f2b((v.w - mean) * inv + b);
  ((ushort4*)(out + (size_t)row * 1024))[tid] = o;
}

// ---------- GEMM: C[M,N] = act(A[M,K] @ W[N,K]^T + bias) variants ----------
// 128x128 tile, BK=32, 4 waves (2x2), 4x4 16x16x32 bf16 MFMA frags per wave.
// sA/sW: row strides (elements). RELU; RES: outF=resid+v; ACCUM: outF+=v (no bias);
// ROWBIAS: bias indexed by row; bias2/b2off: cols >= b2off use bias2[col-b2off].
template <int RELU, int RES, int ROWBIAS, int ACCUM>
__global__ __launch_bounds__(256) void gemm_bt(const unsigned short* __restrict__ A,
                                               const unsigned short* __restrict__ W,
                                               const float* __restrict__ bias,
                                               const float* __restrict__ bias2, int b2off,
                                               const float* __restrict__ resid,
                                               float* __restrict__ outF,
                                               unsigned short* __restrict__ outB,
                                               int M, int N, int K, int sA, int sW) {
  __shared__ unsigned short Al[128 * 32];
  __shared__ unsigned short Bl[128 * 32];
  int nbn = N >> 7;
  int nwg = gridDim.x;
  int bid = blockIdx.x;
  int wg = (bid & 7) * (nwg >> 3) + (bid >> 3);  // XCD swizzle (nwg % 8 == 0)
  int tm = wg / nbn, tn = wg % nbn;
  int tid = threadIdx.x;
  int wave = tid >> 6, lane = tid & 63;
  int wm = wave >> 1, wn = wave & 1;
  const unsigned short* Ab = A + (size_t)tm * 128 * sA;
  const unsigned short* Wb = W + (size_t)tn * 128 * sW;
  f32x4 acc[4][4] = {};
  int c0 = wave * 128 + lane;
  int r0 = c0 >> 2, cc0 = (c0 & 3) * 8;
  int c1 = c0 + 64;
  int r1 = c1 >> 2, cc1 = (c1 & 3) * 8;
  int arow = wm * 64 + (lane & 15);
  int brow = wn * 64 + (lane & 15);
  int kf = (lane >> 4) * 8;

  for (int k0 = 0; k0 < K; k0 += 32) {
    __syncthreads();
    gld16(Ab + (size_t)r0 * sA + k0 + cc0, &Al[(wave * 128) * 8]);
    gld16(Ab + (size_t)r1 * sA + k0 + cc1, &Al[(wave * 128 + 64) * 8]);
    gld16(Wb + (size_t)r0 * sW + k0 + cc0, &Bl[(wave * 128) * 8]);
    gld16(Wb + (size_t)r1 * sW + k0 + cc1, &Bl[(wave * 128 + 64) * 8]);
    __syncthreads();
    bf16x8 af[4], bfr[4];
#pragma unroll
    for (int i = 0; i < 4; ++i) af[i] = *(const bf16x8*)&Al[(arow + i * 16) * 32 + kf];
#pragma unroll
    for (int j = 0; j < 4; ++j) bfr[j] = *(const bf16x8*)&Bl[(brow + j * 16) * 32 + kf];
#pragma unroll
    for (int i = 0; i < 4; ++i)
#pragma unroll
      for (int j = 0; j < 4; ++j)
        acc[i][j] = __builtin_amdgcn_mfma_f32_16x16x32_bf16(af[i], bfr[j], acc[i][j], 0, 0, 0);
  }

  int row0 = tm * 128 + wm * 64 + (lane >> 4) * 4;
  int col0 = tn * 128 + wn * 64 + (lane & 15);
#pragma unroll
  for (int i = 0; i < 4; ++i) {
#pragma unroll
    for (int j = 0; j < 4; ++j) {
      int col = col0 + j * 16;
      float bb = 0.0f;
      if (!ROWBIAS && bias != nullptr)
        bb = (bias2 != nullptr && col >= b2off) ? bias2[col - b2off] : bias[col];
#pragma unroll
      for (int r = 0; r < 4; ++r) {
        int row = row0 + i * 16 + r;
        float v = acc[i][j][r] + (ROWBIAS ? bias[row] : bb);
        if (RELU) v = fmaxf(v, 0.0f);
        size_t idx = (size_t)row * N + col;
        if (ACCUM) outF[idx] += v;
        else if (RES) outF[idx] = resid[idx] + v;
        else outB[idx] = f2b(v);
      }
    }
  }
}

// ---------- flash attention: swapped QK^T, register P, V^T from global ----------
// QK [b*1024+s][2048] bf16 (Q cols 0-1023, K cols 1024-2047), Vt [h*64+d][b*1024+s].
// 1 block = (b,h,64-q-tile); 4 waves x 16 q-rows. KV tile = 64 keys.
// LDS tiles [64][64] linear, chunk-XOR-swizzled via pre-swizzled global source.
__global__ __launch_bounds__(256) void attn_fwd2(const unsigned short* __restrict__ QK,
                                                 const unsigned short* __restrict__ Vt,
                                                 const int* __restrict__ mask,
                                                 unsigned short* __restrict__ O) {
  __shared__ unsigned short Kl[64 * 64];
  __shared__ unsigned short Vl[64 * 64];
  __shared__ float biasl[1024];
  int bid = blockIdx.x;
  int wg = (bid & 7) * 256 + (bid >> 3);  // XCD swizzle: a head's 16 q-tiles on one XCD
  int qt = wg & 15, bh = wg >> 4;
  int b = bh >> 4, h = bh & 15;
  int tid = threadIdx.x, wave = tid >> 6, lane = tid & 63;
  int l15 = lane & 15, g = lane >> 4;
  int q0 = qt * 64;

  for (int i = tid; i < 1024; i += 256) biasl[i] = (mask[b * 1024 + i] == 0) ? -1e9f : 0.0f;

  const unsigned short* Qrow = QK + ((size_t)(b * 1024 + q0 + wave * 16 + l15)) * 2048 + h * 64;
  bf16x8 qf0 = *(const bf16x8*)(Qrow + g * 8);
  bf16x8 qf1 = *(const bf16x8*)(Qrow + 32 + g * 8);

  float m_q = -1e30f, l_q = 0.0f;  // softmax stats for q = l15 (lane-local)
  f32x4 o[4] = {};                 // o[dt][r]: O[q=g*4+r][dt*16+l15]

  int srow = lane >> 3;
  int clog = (lane & 7) ^ srow;
  int h7 = l15 & 7;
  const float scale = 0.125f;  // 1/sqrt(64)

  for (int kt = 0; kt < 16; ++kt) {
    __syncthreads();
#pragma unroll
    for (int i = 0; i < 2; ++i) {
      int rk = wave * 16 + i * 8 + srow;  // rk & 7 == srow
      gld16(QK + ((size_t)(b * 1024 + kt * 64 + rk)) * 2048 + 1024 + h * 64 + clog * 8,
            &Kl[(wave * 16 + i * 8) * 64]);
      gld16(Vt + ((size_t)(h * 64 + rk)) * 8192 + b * 1024 + kt * 64 + clog * 8,
            &Vl[(wave * 16 + i * 8) * 64]);
    }
    __syncthreads();

    // S^T[key][q] = mfma(A=K, B=Q): lane holds q=l15, keys j*16+g*4+r
    f32x4 st[4];
#pragma unroll
    for (int j = 0; j < 4; ++j) {
      int kr = j * 16 + l15;
      bf16x8 ka = *(const bf16x8*)&Kl[kr * 64 + ((g ^ h7) * 8)];
      bf16x8 kb = *(const bf16x8*)&Kl[kr * 64 + (((4 + g) ^ h7) * 8)];
      f32x4 z = {};
      st[j] = __builtin_amdgcn_mfma_f32_16x16x32_bf16(ka, qf0, z, 0, 0, 0);
      st[j] = __builtin_amdgcn_mfma_f32_16x16x32_bf16(kb, qf1, st[j], 0, 0, 0);
    }

    float p[4][4];
    float tmax = -1e30f;
#pragma unroll
    for (int j = 0; j < 4; ++j) {
      float4 b4 = *(const float4*)&biasl[kt * 64 + j * 16 + g * 4];
#pragma unroll
      for (int r = 0; r < 4; ++r) {
        float v = st[j][r] * scale + ((const float*)&b4)[r];
        p[j][r] = v;
        tmax = fmaxf(tmax, v);
      }
    }
    tmax = fmaxf(tmax, __shfl_xor(tmax, 16));
    tmax = fmaxf(tmax, __shfl_xor(tmax, 32));
    float mnew = fmaxf(m_q, tmax);
    float scq = __expf(m_q - mnew);
    m_q = mnew;
    float lsum = 0.0f;
#pragma unroll
    for (int j = 0; j < 4; ++j)
#pragma unroll
      for (int r = 0; r < 4; ++r) {
        float e = __expf(p[j][r] - mnew);
        p[j][r] = e;
        lsum += e;
      }
    lsum += __shfl_xor(lsum, 16);
    lsum += __shfl_xor(lsum, 32);
    l_q = l_q * scq + lsum;

    float sc0 = __shfl(scq, g * 4 + 0);
    float sc1 = __shfl(scq, g * 4 + 1);
    float sc2 = __shfl(scq, g * 4 + 2);
    float sc3 = __shfl(scq, g * 4 + 3);
#pragma unroll
    for (int dt = 0; dt < 4; ++dt) {
      o[dt][0] *= sc0; o[dt][1] *= sc1; o[dt][2] *= sc2; o[dt][3] *= sc3;
    }

    // pack P into A-frags: pa[kk] element e: key = 32kk + 16*(e>>2) + 4g + (e&3)
    union U8 { uint32_t u[4]; bf16x8 v; } pa[2];
#pragma unroll
    for (int j = 0; j < 4; ++j) {
      pa[j >> 1].u[(j & 1) * 2 + 0] = pk2(p[j][0], p[j][1]);
      pa[j >> 1].u[(j & 1) * 2 + 1] = pk2(p[j][2], p[j][3]);
    }

    // PV: B-frags from V^T in matching permuted key order
#pragma unroll
    for (int kk = 0; kk < 2; ++kk) {
#pragma unroll
      for (int dt = 0; dt < 4; ++dt) {
        int vr = dt * 16 + l15;
        bf16x4 lo = *(const bf16x4*)&Vl[vr * 64 + (((4 * kk + (g >> 1)) ^ h7) * 8) + (g & 1) * 4];
        bf16x4 hi = *(const bf16x4*)&Vl[vr * 64 + (((4 * kk + 2 + (g >> 1)) ^ h7) * 8) + (g & 1) * 4];
        bf16x8 vb;
#pragma unroll
        for (int e = 0; e < 4; ++e) { vb[e] = lo[e]; vb[e + 4] = hi[e]; }
        o[dt] = __builtin_amdgcn_mfma_f32_16x16x32_bf16(pa[kk].v, vb, o[dt], 0, 0, 0);
      }
    }
  }

  float lb0 = __shfl(l_q, g * 4 + 0);
  float lb1 = __shfl(l_q, g * 4 + 1);
  float lb2 = __shfl(l_q, g * 4 + 2);
  float lb3 = __shfl(l_q, g * 4 + 3);
  float inv0 = 1.0f / lb0, inv1 = 1.0f / lb1, inv2 = 1.0f / lb2, inv3 = 1.0f / lb3;
  size_t obase = ((size_t)(b * 1024 + q0 + wave * 16 + g * 4)) * 1024 + h * 64 + l15;
#pragma unroll
  for (int dt = 0; dt < 4; ++dt) {
    O[obase + (size_t)0 * 1024 + dt * 16] = f2b(o[dt][0] * inv0);
    O[obase + (size_t)1 * 1024 + dt * 16] = f2b(o[dt][1] * inv1);
    O[obase + (size_t)2 * 1024 + dt * 16] = f2b(o[dt][2] * inv2);
    O[obase + (size_t)3 * 1024 + dt * 16] = f2b(o[dt][3] * inv3);
  }
}

// ---------- launch ----------
extern "C" void kernel_launch(void* const* d_in, const int* in_sizes, int n_in,
                              void* d_out, int out_size, void* d_ws, size_t ws_size,
                              hipStream_t stream) {
  const float* X = (const float*)d_in[0];
  const int* mask = (const int*)d_in[1];
  const float* wq = (const float*)d_in[2];
  const float* bq = (const float*)d_in[3];
  const float* wk = (const float*)d_in[4];
  const float* bk = (const float*)d_in[5];
  const float* wv = (const float*)d_in[6];
  const float* bv = (const float*)d_in[7];
  const float* wo = (const float*)d_in[8];
  const float* bo = (const float*)d_in[9];
  const float* w1 = (const float*)d_in[10];
  const float* b1 = (const float*)d_in[11];
  const float* w2 = (const float*)d_in[12];
  const float* b2 = (const float*)d_in[13];
  const float* ln1a = (const float*)d_in[14];
  const float* ln1b = (const float*)d_in[15];
  const float* ln2a = (const float*)d_in[16];
  const float* ln2b = (const float*)d_in[17];
  float* out = (float*)d_out;
  char* ws = (char*)d_ws;
  const size_t MB = 1024 * 1024;

  // layout (88MB): [0,8) w1_b | [8,16) w2_b | [16,20) wqk_b | [20,22) wv_b |
  // [22,24) wo_b | [24,40) xn (LN1 out -> attn O -> LN2 out) | [40,72) QKb -> hb |
  // [72,88) Vtb
  unsigned short* w1_b = (unsigned short*)(ws + 0 * MB);
  unsigned short* w2_b = (unsigned short*)(ws + 8 * MB);
  unsigned short* wqk_b = (unsigned short*)(ws + 16 * MB);
  unsigned short* wv_b = (unsigned short*)(ws + 20 * MB);
  unsigned short* wo_b = (unsigned short*)(ws + 22 * MB);
  unsigned short* xn = (unsigned short*)(ws + 24 * MB);
  unsigned short* QKb = (unsigned short*)(ws + 40 * MB);
  unsigned short* Vtb = (unsigned short*)(ws + 72 * MB);
  unsigned short* hb = QKb;

  // weights -> bf16 (wq,wk stacked into wqk_b)
  cast_bf16<<<4096, 256, 0, stream>>>(w1, w1_b, 1048576);
  cast_bf16<<<4096, 256, 0, stream>>>(w2, w2_b, 1048576);
  cast_bf16<<<1024, 256, 0, stream>>>(wq, wqk_b, 262144);
  cast_bf16<<<1024, 256, 0, stream>>>(wk, wqk_b + 1024 * 1024, 262144);
  cast_bf16<<<1024, 256, 0, stream>>>(wv, wv_b, 262144);
  cast_bf16<<<1024, 256, 0, stream>>>(wo, wo_b, 262144);

  // LN1
  ln_bf16<<<8192, 256, 0, stream>>>(X, xn, ln1a, ln1b);
  // fused Q+K projection: QK[token][2048]
  gemm_bt<0, 0, 0, 0><<<1024, 256, 0, stream>>>(xn, wqk_b, bq, bk, 1024, nullptr, nullptr, QKb,
                                                8192, 2048, 1024, 1024, 1024);
  // V transposed: Vt[hd][token] = wv @ xn^T + bv (row bias)
  gemm_bt<0, 0, 1, 0><<<512, 256, 0, stream>>>(wv_b, xn, bv, nullptr, 0, nullptr, nullptr, Vtb,
                                               1024, 8192, 1024, 1024, 1024);
  // attention (writes O into xn buffer)
  attn_fwd2<<<2048, 256, 0, stream>>>(QKb, Vtb, mask, xn);
  // out = X + O @ wo^T + bo
  gemm_bt<0, 1, 0, 0><<<512, 256, 0, stream>>>(xn, wo_b, bo, nullptr, 0, X, out, nullptr,
                                               8192, 1024, 1024, 1024, 1024);
  // LN2 (reads out, writes into xn region)
  ln_bf16<<<8192, 256, 0, stream>>>(out, xn, ln2a, ln2b);
  // FFN chunked along hidden dim: h half = [8192][2048] in hb (QKb region)
  for (int hc = 0; hc < 2; ++hc) {
    // h = relu(xn @ w1[hc*2048:(hc+1)*2048]^T + b1[hc*2048:])
    gemm_bt<1, 0, 0, 0><<<1024, 256, 0, stream>>>(xn, w1_b + (size_t)hc * 2048 * 1024,
                                                  b1 + hc * 2048, nullptr, 0, nullptr, nullptr, hb,
                                                  8192, 2048, 1024, 1024, 1024);
    if (hc == 0)  // out = out + b2 + h_half @ w2[:, 0:2048]^T
      gemm_bt<0, 1, 0, 0><<<512, 256, 0, stream>>>(hb, w2_b, b2, nullptr, 0, out, out, nullptr,
                                                   8192, 1024, 2048, 2048, 4096);
    else          // out += h_half @ w2[:, 2048:4096]^T
      gemm_bt<0, 0, 0, 1><<<512, 256, 0, stream>>>(hb, w2_b + 2048, nullptr, nullptr, 0, nullptr,
                                                   out, nullptr, 8192, 1024, 2048, 2048, 4096);
  }
}

// Round 5
// 458.709 us; speedup vs baseline: 1.2710x; 1.0557x over previous
//
#include <hip/hip_runtime.h>
#include <cstdint>
#include <cstddef>

// ---------- types ----------
typedef float f32x4 __attribute__((ext_vector_type(4)));
typedef short bf16x8 __attribute__((ext_vector_type(8)));
typedef short bf16x4 __attribute__((ext_vector_type(4)));

typedef __attribute__((address_space(1))) void void_g;
typedef __attribute__((address_space(3))) void void_l;

__device__ __forceinline__ void gld16(const void* g, void* l) {
  // async global->LDS, 16B per lane; LDS dest = wave-uniform base + lane*16
  __builtin_amdgcn_global_load_lds((void_g*)g, (void_l*)l, 16, 0, 0);
}

__device__ __forceinline__ unsigned short f2b(float f) {
  union { float f; uint32_t u; } c; c.f = f;
  uint32_t u = c.u;
  return (unsigned short)((u + 0x7fffu + ((u >> 16) & 1u)) >> 16);  // RNE
}

__device__ __forceinline__ uint32_t cvtpk(float lo, float hi) {
  uint32_t r;
  asm("v_cvt_pk_bf16_f32 %0, %1, %2" : "=v"(r) : "v"(lo), "v"(hi));
  return r;  // low16 = bf16(lo), high16 = bf16(hi)
}

__device__ __forceinline__ float exp2_fast(float x) {
  return __builtin_exp2f(x);  // lowers to v_exp_f32 (2^x) on gfx950
}

// ---------- all weight casts fp32 -> bf16 in one launch ----------
__global__ __launch_bounds__(256) void cast_all(const float* __restrict__ w1,
                                                const float* __restrict__ w2,
                                                const float* __restrict__ wq,
                                                const float* __restrict__ wk,
                                                const float* __restrict__ wv,
                                                const float* __restrict__ wo,
                                                unsigned short* __restrict__ d1,
                                                unsigned short* __restrict__ d2,
                                                unsigned short* __restrict__ dqk,
                                                unsigned short* __restrict__ dv,
                                                unsigned short* __restrict__ dod) {
  int blk = blockIdx.x;
  const float* s;
  unsigned short* d;
  int off;
  if (blk < 4096) { s = w1; d = d1; off = blk; }
  else if (blk < 8192) { s = w2; d = d2; off = blk - 4096; }
  else if (blk < 9216) { s = wq; d = dqk; off = blk - 8192; }
  else if (blk < 10240) { s = wk; d = dqk + (1 << 20); off = blk - 9216; }
  else if (blk < 11264) { s = wv; d = dv; off = blk - 10240; }
  else { s = wo; d = dod; off = blk - 11264; }
  int i = off * 256 + threadIdx.x;
  float4 v = ((const float4*)s)[i];
  ushort4 o;
  o.x = f2b(v.x); o.y = f2b(v.y); o.z = f2b(v.z); o.w = f2b(v.w);
  ((ushort4*)d)[i] = o;
}

// ---------- LayerNorm (unbiased std, scalar alpha/beta) -> bf16 ----------
__global__ __launch_bounds__(256) void ln_bf16(const float* __restrict__ X,
                                               unsigned short* __restrict__ out,
                                               const float* __restrict__ alpha,
                                               const float* __restrict__ beta) {
  int row = blockIdx.x;
  int tid = threadIdx.x;
  float4 v = ((const float4*)(X + (size_t)row * 1024))[tid];
  float s = v.x + v.y + v.z + v.w;
  float q = v.x * v.x + v.y * v.y + v.z * v.z + v.w * v.w;
#pragma unroll
  for (int m = 1; m < 64; m <<= 1) { s += __shfl_xor(s, m); q += __shfl_xor(q, m); }
  __shared__ float red[8];
  int wave = tid >> 6;
  if ((tid & 63) == 0) { red[wave] = s; red[4 + wave] = q; }
  __syncthreads();
  s = red[0] + red[1] + red[2] + red[3];
  q = red[4] + red[5] + red[6] + red[7];
  float mean = s * (1.0f / 1024.0f);
  float var = fmaxf((q - 1024.0f * mean * mean) * (1.0f / 1023.0f), 0.0f);
  float inv = alpha[0] / (sqrtf(var) + 1e-6f);
  float b = beta[0];
  ushort4 o;
  o.x = f2b((v.x - mean) * inv + b);
  o.y = f2b((v.y - mean) * inv + b);
  o.z = f2b((v.z - mean) * inv + b);
  o.w = f2b((v.w - mean) * inv + b);
  ((ushort4*)(out + (size_t)row * 1024))[tid] = o;
}

// ---------- GEMM: C[M,N] = act(A[M,K] @ W[N,K]^T + bias) variants ----------
// 128x128 tile, BK=32, 4 waves (2x2), 4x4 16x16x32 bf16 MFMA frags per wave.
// sA/sW: row strides (elements). RELU; RES: outF=resid+v; ACCUM: outF+=v (no bias);
// ROWBIAS: bias indexed by row; bias2/b2off: cols >= b2off use bias2[col-b2off].
template <int RELU, int RES, int ROWBIAS, int ACCUM>
__global__ __launch_bounds__(256) void gemm_bt(const unsigned short* __restrict__ A,
                                               const unsigned short* __restrict__ W,
                                               const float* __restrict__ bias,
                                               const float* __restrict__ bias2, int b2off,
                                               const float* __restrict__ resid,
                                               float* __restrict__ outF,
                                               unsigned short* __restrict__ outB,
                                               int M, int N, int K, int sA, int sW) {
  __shared__ unsigned short Al[128 * 32];
  __shared__ unsigned short Bl[128 * 32];
  int nbn = N >> 7;
  int nwg = gridDim.x;
  int bid = blockIdx.x;
  int wg = (bid & 7) * (nwg >> 3) + (bid >> 3);  // XCD swizzle (nwg % 8 == 0)
  int tm = wg / nbn, tn = wg % nbn;
  int tid = threadIdx.x;
  int wave = tid >> 6, lane = tid & 63;
  int wm = wave >> 1, wn = wave & 1;
  const unsigned short* Ab = A + (size_t)tm * 128 * sA;
  const unsigned short* Wb = W + (size_t)tn * 128 * sW;
  f32x4 acc[4][4] = {};
  int c0 = wave * 128 + lane;
  int r0 = c0 >> 2, cc0 = (c0 & 3) * 8;
  int c1 = c0 + 64;
  int r1 = c1 >> 2, cc1 = (c1 & 3) * 8;
  int arow = wm * 64 + (lane & 15);
  int brow = wn * 64 + (lane & 15);
  int kf = (lane >> 4) * 8;

  for (int k0 = 0; k0 < K; k0 += 32) {
    __syncthreads();
    gld16(Ab + (size_t)r0 * sA + k0 + cc0, &Al[(wave * 128) * 8]);
    gld16(Ab + (size_t)r1 * sA + k0 + cc1, &Al[(wave * 128 + 64) * 8]);
    gld16(Wb + (size_t)r0 * sW + k0 + cc0, &Bl[(wave * 128) * 8]);
    gld16(Wb + (size_t)r1 * sW + k0 + cc1, &Bl[(wave * 128 + 64) * 8]);
    __syncthreads();
    bf16x8 af[4], bfr[4];
#pragma unroll
    for (int i = 0; i < 4; ++i) af[i] = *(const bf16x8*)&Al[(arow + i * 16) * 32 + kf];
#pragma unroll
    for (int j = 0; j < 4; ++j) bfr[j] = *(const bf16x8*)&Bl[(brow + j * 16) * 32 + kf];
    __builtin_amdgcn_s_setprio(1);
#pragma unroll
    for (int i = 0; i < 4; ++i)
#pragma unroll
      for (int j = 0; j < 4; ++j)
        acc[i][j] = __builtin_amdgcn_mfma_f32_16x16x32_bf16(af[i], bfr[j], acc[i][j], 0, 0, 0);
    __builtin_amdgcn_s_setprio(0);
  }

  int row0 = tm * 128 + wm * 64 + (lane >> 4) * 4;
  int col0 = tn * 128 + wn * 64 + (lane & 15);
#pragma unroll
  for (int i = 0; i < 4; ++i) {
#pragma unroll
    for (int j = 0; j < 4; ++j) {
      int col = col0 + j * 16;
      float bb = 0.0f;
      if (!ROWBIAS && bias != nullptr)
        bb = (bias2 != nullptr && col >= b2off) ? bias2[col - b2off] : bias[col];
#pragma unroll
      for (int r = 0; r < 4; ++r) {
        int row = row0 + i * 16 + r;
        float v = acc[i][j][r] + (ROWBIAS ? bias[row] : bb);
        if (RELU) v = fmaxf(v, 0.0f);
        size_t idx = (size_t)row * N + col;
        if (ACCUM) outF[idx] += v;
        else if (RES) outF[idx] = resid[idx] + v;
        else outB[idx] = f2b(v);
      }
    }
  }
}

// ---------- flash attention v3: lane-local softmax+output, exp2 domain ----------
// QK [tok][2048] bf16 (Q cols 0-1023, K cols 1024-2047), Vt [h*64+d][tok] bf16.
// 1 block = (b,h,64-q-tile); 4 waves x 16 q-rows. KV tile = 64 keys.
// QK^T: S^T = mfma(A=K, B=Q) -> lane has q=l15, keys j*16+g*4+r.
// PV:   O^T-block = mfma(A=V^T, B=P) -> lane has q=l15, d=dt*16+g*4+r (lane-local!).
// LDS [64][64] linear, chunk-XOR-swizzled via pre-swizzled global source (rule #21).
__global__ __launch_bounds__(256) void attn_fwd3(const unsigned short* __restrict__ QK,
                                                 const unsigned short* __restrict__ Vt,
                                                 const int* __restrict__ mask,
                                                 unsigned short* __restrict__ O) {
  __shared__ unsigned short Kl[64 * 64];
  __shared__ unsigned short Vl[64 * 64];
  __shared__ float biasl[1024];
  int bid = blockIdx.x;
  int wg = (bid & 7) * 256 + (bid >> 3);  // XCD swizzle: a head's 16 q-tiles on one XCD
  int qt = wg & 15, bh = wg >> 4;
  int b = bh >> 4, h = bh & 15;
  int tid = threadIdx.x, wave = tid >> 6, lane = tid & 63;
  int l15 = lane & 15, g = lane >> 4;
  int q0 = qt * 64;

  // mask -> additive bias, pre-scaled to log2 domain
  for (int i = tid; i < 1024; i += 256)
    biasl[i] = (mask[b * 1024 + i] == 0) ? -1.4426950e9f : 0.0f;

  const unsigned short* Qrow = QK + ((size_t)(b * 1024 + q0 + wave * 16 + l15)) * 2048 + h * 64;
  bf16x8 qf0 = *(const bf16x8*)(Qrow + g * 8);
  bf16x8 qf1 = *(const bf16x8*)(Qrow + 32 + g * 8);

  float m_q = -3e38f, l_q = 0.0f;  // log2-domain running max; linear sum (per q=l15)
  f32x4 o[4] = {};                 // o[dt][r] = O[q=l15][d = dt*16 + g*4 + r]

  int srow = lane >> 3;
  int clog = (lane & 7) ^ srow;
  int h7 = l15 & 7;
  const float SC = 0.125f * 1.44269504f;  // 1/sqrt(64) * log2(e)

  for (int kt = 0; kt < 16; ++kt) {
    __syncthreads();
#pragma unroll
    for (int i = 0; i < 2; ++i) {
      int rk = wave * 16 + i * 8 + srow;  // rk & 7 == srow
      gld16(QK + ((size_t)(b * 1024 + kt * 64 + rk)) * 2048 + 1024 + h * 64 + clog * 8,
            &Kl[(wave * 16 + i * 8) * 64]);
      gld16(Vt + ((size_t)(h * 64 + rk)) * 8192 + b * 1024 + kt * 64 + clog * 8,
            &Vl[(wave * 16 + i * 8) * 64]);
    }
    __syncthreads();

    // S^T[key][q] = mfma(A=K, B=Q): lane holds q=l15, keys j*16+g*4+r
    f32x4 st[4];
    __builtin_amdgcn_s_setprio(1);
#pragma unroll
    for (int j = 0; j < 4; ++j) {
      int kr = j * 16 + l15;
      bf16x8 ka = *(const bf16x8*)&Kl[kr * 64 + ((g ^ h7) * 8)];
      bf16x8 kb = *(const bf16x8*)&Kl[kr * 64 + (((4 + g) ^ h7) * 8)];
      f32x4 z = {};
      st[j] = __builtin_amdgcn_mfma_f32_16x16x32_bf16(ka, qf0, z, 0, 0, 0);
      st[j] = __builtin_amdgcn_mfma_f32_16x16x32_bf16(kb, qf1, st[j], 0, 0, 0);
    }
    __builtin_amdgcn_s_setprio(0);

    // log2-domain scores + mask bias; in-lane max over 16 keys + 2 shuffles
    float p[4][4];
    float tmax = -3e38f;
#pragma unroll
    for (int j = 0; j < 4; ++j) {
      float4 b4 = *(const float4*)&biasl[kt * 64 + j * 16 + g * 4];
#pragma unroll
      for (int r = 0; r < 4; ++r) {
        float v = st[j][r] * SC + ((const float*)&b4)[r];
        p[j][r] = v;
        tmax = fmaxf(tmax, v);
      }
    }
    tmax = fmaxf(tmax, __shfl_xor(tmax, 16));
    tmax = fmaxf(tmax, __shfl_xor(tmax, 32));

    // defer-max (T13): only rescale when max grew by >8 (P bounded by 2^8)
    if (__any(tmax > m_q + 8.0f)) {
      float mnew = fmaxf(m_q, tmax);
      float scq = exp2_fast(m_q - mnew);
#pragma unroll
      for (int dt = 0; dt < 4; ++dt)
#pragma unroll
        for (int r = 0; r < 4; ++r) o[dt][r] *= scq;
      l_q *= scq;
      m_q = mnew;
    }

    float lsum = 0.0f;
#pragma unroll
    for (int j = 0; j < 4; ++j)
#pragma unroll
      for (int r = 0; r < 4; ++r) {
        float e = exp2_fast(p[j][r] - m_q);
        p[j][r] = e;
        lsum += e;
      }
    lsum += __shfl_xor(lsum, 16);
    lsum += __shfl_xor(lsum, 32);
    l_q += lsum;

    // pack P into B-frags via v_cvt_pk_bf16_f32:
    // pa[kk] element e = P[key = 32kk + 16*(e>>2) + 4g + (e&3)][q=l15]
    union U8 { uint32_t u[4]; bf16x8 v; } pa[2];
#pragma unroll
    for (int j = 0; j < 4; ++j) {
      pa[j >> 1].u[(j & 1) * 2 + 0] = cvtpk(p[j][0], p[j][1]);
      pa[j >> 1].u[(j & 1) * 2 + 1] = cvtpk(p[j][2], p[j][3]);
    }

    // PV: O^T = mfma(A=V^T, B=P). A element e = V^T[d-block row l15][key kappa'(g*8+e)]
    // (same permuted key order as pa; identical LDS addresses as v2)
#pragma unroll
    for (int kk = 0; kk < 2; ++kk) {
#pragma unroll
      for (int dt = 0; dt < 4; ++dt) {
        int vr = dt * 16 + l15;
        uint2 lo = *(const uint2*)&Vl[vr * 64 + (((4 * kk + (g >> 1)) ^ h7) * 8) + (g & 1) * 4];
        uint2 hi = *(const uint2*)&Vl[vr * 64 + (((4 * kk + 2 + (g >> 1)) ^ h7) * 8) + (g & 1) * 4];
        union U8 vbu;
        vbu.u[0] = lo.x; vbu.u[1] = lo.y; vbu.u[2] = hi.x; vbu.u[3] = hi.y;
        __builtin_amdgcn_s_setprio(1);
        o[dt] = __builtin_amdgcn_mfma_f32_16x16x32_bf16(vbu.v, pa[kk].v, o[dt], 0, 0, 0);
        __builtin_amdgcn_s_setprio(0);
      }
    }
  }

  // epilogue: lane-local 1/l, vectorized 8B stores (4 consecutive d per dt)
  float inv = 1.0f / l_q;
  size_t orow = ((size_t)(b * 1024 + q0 + wave * 16 + l15)) * 1024 + h * 64;
#pragma unroll
  for (int dt = 0; dt < 4; ++dt) {
    uint2 w;
    w.x = cvtpk(o[dt][0] * inv, o[dt][1] * inv);
    w.y = cvtpk(o[dt][2] * inv, o[dt][3] * inv);
    *(uint2*)&O[orow + dt * 16 + g * 4] = w;
  }
}

// ---------- launch ----------
extern "C" void kernel_launch(void* const* d_in, const int* in_sizes, int n_in,
                              void* d_out, int out_size, void* d_ws, size_t ws_size,
                              hipStream_t stream) {
  const float* X = (const float*)d_in[0];
  const int* mask = (const int*)d_in[1];
  const float* wq = (const float*)d_in[2];
  const float* bq = (const float*)d_in[3];
  const float* wk = (const float*)d_in[4];
  const float* bk = (const float*)d_in[5];
  const float* wv = (const float*)d_in[6];
  const float* bv = (const float*)d_in[7];
  const float* wo = (const float*)d_in[8];
  const float* bo = (const float*)d_in[9];
  const float* w1 = (const float*)d_in[10];
  const float* b1 = (const float*)d_in[11];
  const float* w2 = (const float*)d_in[12];
  const float* b2 = (const float*)d_in[13];
  const float* ln1a = (const float*)d_in[14];
  const float* ln1b = (const float*)d_in[15];
  const float* ln2a = (const float*)d_in[16];
  const float* ln2b = (const float*)d_in[17];
  float* out = (float*)d_out;
  char* ws = (char*)d_ws;
  const size_t MB = 1024 * 1024;

  // layout (88MB): [0,8) w1_b | [8,16) w2_b | [16,20) wqk_b | [20,22) wv_b |
  // [22,24) wo_b | [24,40) xn (LN1 out -> attn O -> LN2 out) | [40,72) QKb -> hb |
  // [72,88) Vtb
  unsigned short* w1_b = (unsigned short*)(ws + 0 * MB);
  unsigned short* w2_b = (unsigned short*)(ws + 8 * MB);
  unsigned short* wqk_b = (unsigned short*)(ws + 16 * MB);
  unsigned short* wv_b = (unsigned short*)(ws + 20 * MB);
  unsigned short* wo_b = (unsigned short*)(ws + 22 * MB);
  unsigned short* xn = (unsigned short*)(ws + 24 * MB);
  unsigned short* QKb = (unsigned short*)(ws + 40 * MB);
  unsigned short* Vtb = (unsigned short*)(ws + 72 * MB);
  unsigned short* hb = QKb;

  // all weights -> bf16 in one launch (wq,wk stacked into wqk_b)
  cast_all<<<12288, 256, 0, stream>>>(w1, w2, wq, wk, wv, wo, w1_b, w2_b, wqk_b, wv_b, wo_b);

  // LN1
  ln_bf16<<<8192, 256, 0, stream>>>(X, xn, ln1a, ln1b);
  // fused Q+K projection: QK[token][2048]
  gemm_bt<0, 0, 0, 0><<<1024, 256, 0, stream>>>(xn, wqk_b, bq, bk, 1024, nullptr, nullptr, QKb,
                                                8192, 2048, 1024, 1024, 1024);
  // V transposed: Vt[hd][token] = wv @ xn^T + bv (row bias)
  gemm_bt<0, 0, 1, 0><<<512, 256, 0, stream>>>(wv_b, xn, bv, nullptr, 0, nullptr, nullptr, Vtb,
                                               1024, 8192, 1024, 1024, 1024);
  // attention (writes O into xn buffer)
  attn_fwd3<<<2048, 256, 0, stream>>>(QKb, Vtb, mask, xn);
  // out = X + O @ wo^T + bo
  gemm_bt<0, 1, 0, 0><<<512, 256, 0, stream>>>(xn, wo_b, bo, nullptr, 0, X, out, nullptr,
                                               8192, 1024, 1024, 1024, 1024);
  // LN2 (reads out, writes into xn region)
  ln_bf16<<<8192, 256, 0, stream>>>(out, xn, ln2a, ln2b);
  // FFN chunked along hidden dim: h half = [8192][2048] in hb (QKb region)
  for (int hc = 0; hc < 2; ++hc) {
    // h = relu(xn @ w1[hc*2048:(hc+1)*2048]^T + b1[hc*2048:])
    gemm_bt<1, 0, 0, 0><<<1024, 256, 0, stream>>>(xn, w1_b + (size_t)hc * 2048 * 1024,
                                                  b1 + hc * 2048, nullptr, 0, nullptr, nullptr, hb,
                                                  8192, 2048, 1024, 1024, 1024);
    if (hc == 0)  // out = out + b2 + h_half @ w2[:, 0:2048]^T
      gemm_bt<0, 1, 0, 0><<<512, 256, 0, stream>>>(hb, w2_b, b2, nullptr, 0, out, out, nullptr,
                                                   8192, 1024, 2048, 2048, 4096);
    else          // out += h_half @ w2[:, 2048:4096]^T
      gemm_bt<0, 0, 0, 1><<<512, 256, 0, stream>>>(hb, w2_b + 2048, nullptr, nullptr, 0, nullptr,
                                                   out, nullptr, 8192, 1024, 2048, 2048, 4096);
  }
}

// Round 6
// 452.563 us; speedup vs baseline: 1.2883x; 1.0136x over previous
//
#include <hip/hip_runtime.h>
#include <cstdint>
#include <cstddef>

// ---------- types ----------
typedef float f32x4 __attribute__((ext_vector_type(4)));
typedef short bf16x8 __attribute__((ext_vector_type(8)));
typedef short bf16x4 __attribute__((ext_vector_type(4)));

typedef __attribute__((address_space(1))) void void_g;
typedef __attribute__((address_space(3))) void void_l;

__device__ __forceinline__ void gld16(const void* g, void* l) {
  // async global->LDS, 16B per lane; LDS dest = wave-uniform base + lane*16
  __builtin_amdgcn_global_load_lds((void_g*)g, (void_l*)l, 16, 0, 0);
}

__device__ __forceinline__ unsigned short f2b(float f) {
  union { float f; uint32_t u; } c; c.f = f;
  uint32_t u = c.u;
  return (unsigned short)((u + 0x7fffu + ((u >> 16) & 1u)) >> 16);  // RNE
}

__device__ __forceinline__ uint32_t cvtpk(float lo, float hi) {
  uint32_t r;
  asm("v_cvt_pk_bf16_f32 %0, %1, %2" : "=v"(r) : "v"(lo), "v"(hi));
  return r;  // low16 = bf16(lo), high16 = bf16(hi)
}

__device__ __forceinline__ float exp2_fast(float x) {
  return __builtin_exp2f(x);  // lowers to v_exp_f32 (2^x) on gfx950
}

// ---------- all weight casts fp32 -> bf16 in one launch ----------
__global__ __launch_bounds__(256) void cast_all(const float* __restrict__ w1,
                                                const float* __restrict__ w2,
                                                const float* __restrict__ wq,
                                                const float* __restrict__ wk,
                                                const float* __restrict__ wv,
                                                const float* __restrict__ wo,
                                                unsigned short* __restrict__ d1,
                                                unsigned short* __restrict__ d2,
                                                unsigned short* __restrict__ dqk,
                                                unsigned short* __restrict__ dv,
                                                unsigned short* __restrict__ dod) {
  int blk = blockIdx.x;
  const float* s;
  unsigned short* d;
  int off;
  if (blk < 4096) { s = w1; d = d1; off = blk; }
  else if (blk < 8192) { s = w2; d = d2; off = blk - 4096; }
  else if (blk < 9216) { s = wq; d = dqk; off = blk - 8192; }
  else if (blk < 10240) { s = wk; d = dqk + (1 << 20); off = blk - 9216; }
  else if (blk < 11264) { s = wv; d = dv; off = blk - 10240; }
  else { s = wo; d = dod; off = blk - 11264; }
  int i = off * 256 + threadIdx.x;
  float4 v = ((const float4*)s)[i];
  ushort4 o;
  o.x = f2b(v.x); o.y = f2b(v.y); o.z = f2b(v.z); o.w = f2b(v.w);
  ((ushort4*)d)[i] = o;
}

// ---------- LayerNorm (unbiased std, scalar alpha/beta) -> bf16 ----------
__global__ __launch_bounds__(256) void ln_bf16(const float* __restrict__ X,
                                               unsigned short* __restrict__ out,
                                               const float* __restrict__ alpha,
                                               const float* __restrict__ beta) {
  int row = blockIdx.x;
  int tid = threadIdx.x;
  float4 v = ((const float4*)(X + (size_t)row * 1024))[tid];
  float s = v.x + v.y + v.z + v.w;
  float q = v.x * v.x + v.y * v.y + v.z * v.z + v.w * v.w;
#pragma unroll
  for (int m = 1; m < 64; m <<= 1) { s += __shfl_xor(s, m); q += __shfl_xor(q, m); }
  __shared__ float red[8];
  int wave = tid >> 6;
  if ((tid & 63) == 0) { red[wave] = s; red[4 + wave] = q; }
  __syncthreads();
  s = red[0] + red[1] + red[2] + red[3];
  q = red[4] + red[5] + red[6] + red[7];
  float mean = s * (1.0f / 1024.0f);
  float var = fmaxf((q - 1024.0f * mean * mean) * (1.0f / 1023.0f), 0.0f);
  float inv = alpha[0] / (sqrtf(var) + 1e-6f);
  float b = beta[0];
  ushort4 o;
  o.x = f2b((v.x - mean) * inv + b);
  o.y = f2b((v.y - mean) * inv + b);
  o.z = f2b((v.z - mean) * inv + b);
  o.w = f2b((v.w - mean) * inv + b);
  ((ushort4*)(out + (size_t)row * 1024))[tid] = o;
}

// ---------- GEMM: C[M,N] = act(A[M,K] @ W[N,K]^T + bias) variants ----------
// 128x128 tile, BK=32, 4 waves (2x2), 4x4 16x16x32 bf16 MFMA frags per wave.
// 2-phase pipeline (T3-minimum): double-buffered LDS, stage(t+1) before
// compute(t), ONE barrier per K-step (load latency hides under MFMA).
// sA/sW: row strides (elements). RELU; RES: outF=resid+v; ACCUM: outF+=v (no bias);
// ROWBIAS: bias indexed by row; bias2/b2off: cols >= b2off use bias2[col-b2off].
template <int RELU, int RES, int ROWBIAS, int ACCUM>
__global__ __launch_bounds__(256) void gemm_bt(const unsigned short* __restrict__ A,
                                               const unsigned short* __restrict__ W,
                                               const float* __restrict__ bias,
                                               const float* __restrict__ bias2, int b2off,
                                               const float* __restrict__ resid,
                                               float* __restrict__ outF,
                                               unsigned short* __restrict__ outB,
                                               int M, int N, int K, int sA, int sW) {
  __shared__ unsigned short Al[2][128 * 32];
  __shared__ unsigned short Bl[2][128 * 32];
  int nbn = N >> 7;
  int nwg = gridDim.x;
  int bid = blockIdx.x;
  int wg = (bid & 7) * (nwg >> 3) + (bid >> 3);  // XCD swizzle (nwg % 8 == 0)
  int tm = wg / nbn, tn = wg % nbn;
  int tid = threadIdx.x;
  int wave = tid >> 6, lane = tid & 63;
  int wm = wave >> 1, wn = wave & 1;
  const unsigned short* Ab = A + (size_t)tm * 128 * sA;
  const unsigned short* Wb = W + (size_t)tn * 128 * sW;
  f32x4 acc[4][4] = {};
  int c0 = wave * 128 + lane;
  int r0 = c0 >> 2, cc0 = (c0 & 3) * 8;
  int c1 = c0 + 64;
  int r1 = c1 >> 2, cc1 = (c1 & 3) * 8;
  int arow = wm * 64 + (lane & 15);
  int brow = wn * 64 + (lane & 15);
  int kf = (lane >> 4) * 8;

  auto stage = [&](int buf, int k0) {
    gld16(Ab + (size_t)r0 * sA + k0 + cc0, &Al[buf][(wave * 128) * 8]);
    gld16(Ab + (size_t)r1 * sA + k0 + cc1, &Al[buf][(wave * 128 + 64) * 8]);
    gld16(Wb + (size_t)r0 * sW + k0 + cc0, &Bl[buf][(wave * 128) * 8]);
    gld16(Wb + (size_t)r1 * sW + k0 + cc1, &Bl[buf][(wave * 128 + 64) * 8]);
  };

  stage(0, 0);
  __syncthreads();  // drains prologue loads (vmcnt(0) before s_barrier)
  int cur = 0;
  for (int k0 = 0; k0 < K; k0 += 32) {
    if (k0 + 32 < K) stage(cur ^ 1, k0 + 32);  // prefetch next tile into other buffer
    bf16x8 af[4], bfr[4];
#pragma unroll
    for (int i = 0; i < 4; ++i) af[i] = *(const bf16x8*)&Al[cur][(arow + i * 16) * 32 + kf];
#pragma unroll
    for (int j = 0; j < 4; ++j) bfr[j] = *(const bf16x8*)&Bl[cur][(brow + j * 16) * 32 + kf];
    __builtin_amdgcn_s_setprio(1);
#pragma unroll
    for (int i = 0; i < 4; ++i)
#pragma unroll
      for (int j = 0; j < 4; ++j)
        acc[i][j] = __builtin_amdgcn_mfma_f32_16x16x32_bf16(af[i], bfr[j], acc[i][j], 0, 0, 0);
    __builtin_amdgcn_s_setprio(0);
    __syncthreads();  // one barrier per K-step: reads done + next-tile loads landed
    cur ^= 1;
  }

  int row0 = tm * 128 + wm * 64 + (lane >> 4) * 4;
  int col0 = tn * 128 + wn * 64 + (lane & 15);
#pragma unroll
  for (int i = 0; i < 4; ++i) {
#pragma unroll
    for (int j = 0; j < 4; ++j) {
      int col = col0 + j * 16;
      float bb = 0.0f;
      if (!ROWBIAS && bias != nullptr)
        bb = (bias2 != nullptr && col >= b2off) ? bias2[col - b2off] : bias[col];
#pragma unroll
      for (int r = 0; r < 4; ++r) {
        int row = row0 + i * 16 + r;
        float v = acc[i][j][r] + (ROWBIAS ? bias[row] : bb);
        if (RELU) v = fmaxf(v, 0.0f);
        size_t idx = (size_t)row * N + col;
        if (ACCUM) outF[idx] += v;
        else if (RES) outF[idx] = resid[idx] + v;
        else outB[idx] = f2b(v);
      }
    }
  }
}

// ---------- flash attention v4: v3 + double-buffered KV staging (2-phase) ----------
// QK [tok][2048] bf16 (Q cols 0-1023, K cols 1024-2047), Vt [h*64+d][tok] bf16.
// 1 block = (b,h,64-q-tile); 4 waves x 16 q-rows. KV tile = 64 keys.
// QK^T: S^T = mfma(A=K, B=Q) -> lane has q=l15, keys j*16+g*4+r.
// PV:   O^T-block = mfma(A=V^T, B=P) -> lane has q=l15, d=dt*16+g*4+r (lane-local).
// LDS [64][64] linear, chunk-XOR-swizzled via pre-swizzled global source (rule #21).
// Stage(kt+1) issued before compute(kt); ONE barrier per kt.
__global__ __launch_bounds__(256) void attn_fwd4(const unsigned short* __restrict__ QK,
                                                 const unsigned short* __restrict__ Vt,
                                                 const int* __restrict__ mask,
                                                 unsigned short* __restrict__ O) {
  __shared__ unsigned short Kl[2][64 * 64];
  __shared__ unsigned short Vl[2][64 * 64];
  __shared__ float biasl[1024];
  int bid = blockIdx.x;
  int wg = (bid & 7) * 256 + (bid >> 3);  // XCD swizzle: a head's 16 q-tiles on one XCD
  int qt = wg & 15, bh = wg >> 4;
  int b = bh >> 4, h = bh & 15;
  int tid = threadIdx.x, wave = tid >> 6, lane = tid & 63;
  int l15 = lane & 15, g = lane >> 4;
  int q0 = qt * 64;

  // mask -> additive bias, pre-scaled to log2 domain
  for (int i = tid; i < 1024; i += 256)
    biasl[i] = (mask[b * 1024 + i] == 0) ? -1.4426950e9f : 0.0f;

  const unsigned short* Qrow = QK + ((size_t)(b * 1024 + q0 + wave * 16 + l15)) * 2048 + h * 64;
  bf16x8 qf0 = *(const bf16x8*)(Qrow + g * 8);
  bf16x8 qf1 = *(const bf16x8*)(Qrow + 32 + g * 8);

  float m_q = -3e38f, l_q = 0.0f;  // log2-domain running max; linear sum (per q=l15)
  f32x4 o[4] = {};                 // o[dt][r] = O[q=l15][d = dt*16 + g*4 + r]

  int srow = lane >> 3;
  int clog = (lane & 7) ^ srow;
  int h7 = l15 & 7;
  const float SC = 0.125f * 1.44269504f;  // 1/sqrt(64) * log2(e)

  auto stageKV = [&](int buf, int kt) {
#pragma unroll
    for (int i = 0; i < 2; ++i) {
      int rk = wave * 16 + i * 8 + srow;  // rk & 7 == srow
      gld16(QK + ((size_t)(b * 1024 + kt * 64 + rk)) * 2048 + 1024 + h * 64 + clog * 8,
            &Kl[buf][(wave * 16 + i * 8) * 64]);
      gld16(Vt + ((size_t)(h * 64 + rk)) * 8192 + b * 1024 + kt * 64 + clog * 8,
            &Vl[buf][(wave * 16 + i * 8) * 64]);
    }
  };

  stageKV(0, 0);
  __syncthreads();  // drains prologue loads + biasl writes
  int cur = 0;

  for (int kt = 0; kt < 16; ++kt) {
    if (kt < 15) stageKV(cur ^ 1, kt + 1);  // prefetch next KV tile

    // S^T[key][q] = mfma(A=K, B=Q): lane holds q=l15, keys j*16+g*4+r
    f32x4 st[4];
    __builtin_amdgcn_s_setprio(1);
#pragma unroll
    for (int j = 0; j < 4; ++j) {
      int kr = j * 16 + l15;
      bf16x8 ka = *(const bf16x8*)&Kl[cur][kr * 64 + ((g ^ h7) * 8)];
      bf16x8 kb = *(const bf16x8*)&Kl[cur][kr * 64 + (((4 + g) ^ h7) * 8)];
      f32x4 z = {};
      st[j] = __builtin_amdgcn_mfma_f32_16x16x32_bf16(ka, qf0, z, 0, 0, 0);
      st[j] = __builtin_amdgcn_mfma_f32_16x16x32_bf16(kb, qf1, st[j], 0, 0, 0);
    }
    __builtin_amdgcn_s_setprio(0);

    // log2-domain scores + mask bias; in-lane max over 16 keys + 2 shuffles
    float p[4][4];
    float tmax = -3e38f;
#pragma unroll
    for (int j = 0; j < 4; ++j) {
      float4 b4 = *(const float4*)&biasl[kt * 64 + j * 16 + g * 4];
#pragma unroll
      for (int r = 0; r < 4; ++r) {
        float v = st[j][r] * SC + ((const float*)&b4)[r];
        p[j][r] = v;
        tmax = fmaxf(tmax, v);
      }
    }
    tmax = fmaxf(tmax, __shfl_xor(tmax, 16));
    tmax = fmaxf(tmax, __shfl_xor(tmax, 32));

    // defer-max (T13): only rescale when max grew by >8 (P bounded by 2^8)
    if (__any(tmax > m_q + 8.0f)) {
      float mnew = fmaxf(m_q, tmax);
      float scq = exp2_fast(m_q - mnew);
#pragma unroll
      for (int dt = 0; dt < 4; ++dt)
#pragma unroll
        for (int r = 0; r < 4; ++r) o[dt][r] *= scq;
      l_q *= scq;
      m_q = mnew;
    }

    float lsum = 0.0f;
#pragma unroll
    for (int j = 0; j < 4; ++j)
#pragma unroll
      for (int r = 0; r < 4; ++r) {
        float e = exp2_fast(p[j][r] - m_q);
        p[j][r] = e;
        lsum += e;
      }
    lsum += __shfl_xor(lsum, 16);
    lsum += __shfl_xor(lsum, 32);
    l_q += lsum;

    // pack P into B-frags via v_cvt_pk_bf16_f32:
    // pa[kk] element e = P[key = 32kk + 16*(e>>2) + 4g + (e&3)][q=l15]
    union U8 { uint32_t u[4]; bf16x8 v; } pa[2];
#pragma unroll
    for (int j = 0; j < 4; ++j) {
      pa[j >> 1].u[(j & 1) * 2 + 0] = cvtpk(p[j][0], p[j][1]);
      pa[j >> 1].u[(j & 1) * 2 + 1] = cvtpk(p[j][2], p[j][3]);
    }

    // PV: O^T = mfma(A=V^T, B=P). A element e = V^T[d-block row l15][key kappa'(g*8+e)]
#pragma unroll
    for (int kk = 0; kk < 2; ++kk) {
#pragma unroll
      for (int dt = 0; dt < 4; ++dt) {
        int vr = dt * 16 + l15;
        uint2 lo = *(const uint2*)&Vl[cur][vr * 64 + (((4 * kk + (g >> 1)) ^ h7) * 8) + (g & 1) * 4];
        uint2 hi = *(const uint2*)&Vl[cur][vr * 64 + (((4 * kk + 2 + (g >> 1)) ^ h7) * 8) + (g & 1) * 4];
        union U8 vbu;
        vbu.u[0] = lo.x; vbu.u[1] = lo.y; vbu.u[2] = hi.x; vbu.u[3] = hi.y;
        __builtin_amdgcn_s_setprio(1);
        o[dt] = __builtin_amdgcn_mfma_f32_16x16x32_bf16(vbu.v, pa[kk].v, o[dt], 0, 0, 0);
        __builtin_amdgcn_s_setprio(0);
      }
    }

    __syncthreads();  // one barrier per kt: reads of cur done + next-tile loads landed
    cur ^= 1;
  }

  // epilogue: lane-local 1/l, vectorized 8B stores (4 consecutive d per dt)
  float inv = 1.0f / l_q;
  size_t orow = ((size_t)(b * 1024 + q0 + wave * 16 + l15)) * 1024 + h * 64;
#pragma unroll
  for (int dt = 0; dt < 4; ++dt) {
    uint2 w;
    w.x = cvtpk(o[dt][0] * inv, o[dt][1] * inv);
    w.y = cvtpk(o[dt][2] * inv, o[dt][3] * inv);
    *(uint2*)&O[orow + dt * 16 + g * 4] = w;
  }
}

// ---------- launch ----------
extern "C" void kernel_launch(void* const* d_in, const int* in_sizes, int n_in,
                              void* d_out, int out_size, void* d_ws, size_t ws_size,
                              hipStream_t stream) {
  const float* X = (const float*)d_in[0];
  const int* mask = (const int*)d_in[1];
  const float* wq = (const float*)d_in[2];
  const float* bq = (const float*)d_in[3];
  const float* wk = (const float*)d_in[4];
  const float* bk = (const float*)d_in[5];
  const float* wv = (const float*)d_in[6];
  const float* bv = (const float*)d_in[7];
  const float* wo = (const float*)d_in[8];
  const float* bo = (const float*)d_in[9];
  const float* w1 = (const float*)d_in[10];
  const float* b1 = (const float*)d_in[11];
  const float* w2 = (const float*)d_in[12];
  const float* b2 = (const float*)d_in[13];
  const float* ln1a = (const float*)d_in[14];
  const float* ln1b = (const float*)d_in[15];
  const float* ln2a = (const float*)d_in[16];
  const float* ln2b = (const float*)d_in[17];
  float* out = (float*)d_out;
  char* ws = (char*)d_ws;
  const size_t MB = 1024 * 1024;

  // layout (88MB): [0,8) w1_b | [8,16) w2_b | [16,20) wqk_b | [20,22) wv_b |
  // [22,24) wo_b | [24,40) xn (LN1 out -> attn O -> LN2 out) | [40,72) QKb -> hb |
  // [72,88) Vtb
  unsigned short* w1_b = (unsigned short*)(ws + 0 * MB);
  unsigned short* w2_b = (unsigned short*)(ws + 8 * MB);
  unsigned short* wqk_b = (unsigned short*)(ws + 16 * MB);
  unsigned short* wv_b = (unsigned short*)(ws + 20 * MB);
  unsigned short* wo_b = (unsigned short*)(ws + 22 * MB);
  unsigned short* xn = (unsigned short*)(ws + 24 * MB);
  unsigned short* QKb = (unsigned short*)(ws + 40 * MB);
  unsigned short* Vtb = (unsigned short*)(ws + 72 * MB);
  unsigned short* hb = QKb;

  // all weights -> bf16 in one launch (wq,wk stacked into wqk_b)
  cast_all<<<12288, 256, 0, stream>>>(w1, w2, wq, wk, wv, wo, w1_b, w2_b, wqk_b, wv_b, wo_b);

  // LN1
  ln_bf16<<<8192, 256, 0, stream>>>(X, xn, ln1a, ln1b);
  // fused Q+K projection: QK[token][2048]
  gemm_bt<0, 0, 0, 0><<<1024, 256, 0, stream>>>(xn, wqk_b, bq, bk, 1024, nullptr, nullptr, QKb,
                                                8192, 2048, 1024, 1024, 1024);
  // V transposed: Vt[hd][token] = wv @ xn^T + bv (row bias)
  gemm_bt<0, 0, 1, 0><<<512, 256, 0, stream>>>(wv_b, xn, bv, nullptr, 0, nullptr, nullptr, Vtb,
                                               1024, 8192, 1024, 1024, 1024);
  // attention (writes O into xn buffer)
  attn_fwd4<<<2048, 256, 0, stream>>>(QKb, Vtb, mask, xn);
  // out = X + O @ wo^T + bo
  gemm_bt<0, 1, 0, 0><<<512, 256, 0, stream>>>(xn, wo_b, bo, nullptr, 0, X, out, nullptr,
                                               8192, 1024, 1024, 1024, 1024);
  // LN2 (reads out, writes into xn region)
  ln_bf16<<<8192, 256, 0, stream>>>(out, xn, ln2a, ln2b);
  // FFN chunked along hidden dim: h half = [8192][2048] in hb (QKb region)
  for (int hc = 0; hc < 2; ++hc) {
    // h = relu(xn @ w1[hc*2048:(hc+1)*2048]^T + b1[hc*2048:])
    gemm_bt<1, 0, 0, 0><<<1024, 256, 0, stream>>>(xn, w1_b + (size_t)hc * 2048 * 1024,
                                                  b1 + hc * 2048, nullptr, 0, nullptr, nullptr, hb,
                                                  8192, 2048, 1024, 1024, 1024);
    if (hc == 0)  // out = out + b2 + h_half @ w2[:, 0:2048]^T
      gemm_bt<0, 1, 0, 0><<<512, 256, 0, stream>>>(hb, w2_b, b2, nullptr, 0, out, out, nullptr,
                                                   8192, 1024, 2048, 2048, 4096);
    else          // out += h_half @ w2[:, 2048:4096]^T
      gemm_bt<0, 0, 0, 1><<<512, 256, 0, stream>>>(hb, w2_b + 2048, nullptr, nullptr, 0, nullptr,
                                                   out, nullptr, 8192, 1024, 2048, 2048, 4096);
  }
}

// Round 7
// 408.364 us; speedup vs baseline: 1.4277x; 1.1082x over previous
//
#include <hip/hip_runtime.h>
#include <cstdint>
#include <cstddef>

// ---------- types ----------
typedef float f32x4 __attribute__((ext_vector_type(4)));
typedef short bf16x8 __attribute__((ext_vector_type(8)));
typedef short bf16x4 __attribute__((ext_vector_type(4)));

typedef __attribute__((address_space(1))) void void_g;
typedef __attribute__((address_space(3))) void void_l;

__device__ __forceinline__ void gld16(const void* g, void* l) {
  // async global->LDS, 16B per lane; LDS dest = wave-uniform base + lane*16
  __builtin_amdgcn_global_load_lds((void_g*)g, (void_l*)l, 16, 0, 0);
}

__device__ __forceinline__ unsigned short f2b(float f) {
  union { float f; uint32_t u; } c; c.f = f;
  uint32_t u = c.u;
  return (unsigned short)((u + 0x7fffu + ((u >> 16) & 1u)) >> 16);  // RNE
}

__device__ __forceinline__ uint32_t cvtpk(float lo, float hi) {
  uint32_t r;
  asm("v_cvt_pk_bf16_f32 %0, %1, %2" : "=v"(r) : "v"(lo), "v"(hi));
  return r;  // low16 = bf16(lo), high16 = bf16(hi)
}

__device__ __forceinline__ float exp2_fast(float x) {
  return __builtin_exp2f(x);  // lowers to v_exp_f32 (2^x) on gfx950
}

// ---------- all weight casts fp32 -> bf16 in one launch ----------
__global__ __launch_bounds__(256) void cast_all(const float* __restrict__ w1,
                                                const float* __restrict__ w2,
                                                const float* __restrict__ wq,
                                                const float* __restrict__ wk,
                                                const float* __restrict__ wv,
                                                const float* __restrict__ wo,
                                                unsigned short* __restrict__ d1,
                                                unsigned short* __restrict__ d2,
                                                unsigned short* __restrict__ dqk,
                                                unsigned short* __restrict__ dv,
                                                unsigned short* __restrict__ dod) {
  int blk = blockIdx.x;
  const float* s;
  unsigned short* d;
  int off;
  if (blk < 4096) { s = w1; d = d1; off = blk; }
  else if (blk < 8192) { s = w2; d = d2; off = blk - 4096; }
  else if (blk < 9216) { s = wq; d = dqk; off = blk - 8192; }
  else if (blk < 10240) { s = wk; d = dqk + (1 << 20); off = blk - 9216; }
  else if (blk < 11264) { s = wv; d = dv; off = blk - 10240; }
  else { s = wo; d = dod; off = blk - 11264; }
  int i = off * 256 + threadIdx.x;
  float4 v = ((const float4*)s)[i];
  ushort4 o;
  o.x = f2b(v.x); o.y = f2b(v.y); o.z = f2b(v.z); o.w = f2b(v.w);
  ((ushort4*)d)[i] = o;
}

// ---------- LayerNorm (unbiased std, scalar alpha/beta) -> bf16 ----------
__global__ __launch_bounds__(256) void ln_bf16(const float* __restrict__ X,
                                               unsigned short* __restrict__ out,
                                               const float* __restrict__ alpha,
                                               const float* __restrict__ beta) {
  int row = blockIdx.x;
  int tid = threadIdx.x;
  float4 v = ((const float4*)(X + (size_t)row * 1024))[tid];
  float s = v.x + v.y + v.z + v.w;
  float q = v.x * v.x + v.y * v.y + v.z * v.z + v.w * v.w;
#pragma unroll
  for (int m = 1; m < 64; m <<= 1) { s += __shfl_xor(s, m); q += __shfl_xor(q, m); }
  __shared__ float red[8];
  int wave = tid >> 6;
  if ((tid & 63) == 0) { red[wave] = s; red[4 + wave] = q; }
  __syncthreads();
  s = red[0] + red[1] + red[2] + red[3];
  q = red[4] + red[5] + red[6] + red[7];
  float mean = s * (1.0f / 1024.0f);
  float var = fmaxf((q - 1024.0f * mean * mean) * (1.0f / 1023.0f), 0.0f);
  float inv = alpha[0] / (sqrtf(var) + 1e-6f);
  float b = beta[0];
  ushort4 o;
  o.x = f2b((v.x - mean) * inv + b);
  o.y = f2b((v.y - mean) * inv + b);
  o.z = f2b((v.z - mean) * inv + b);
  o.w = f2b((v.w - mean) * inv + b);
  ((ushort4*)(out + (size_t)row * 1024))[tid] = o;
}

// ---------- GEMM 128x128 (2-phase): for N=1024 shapes (grid 128-512) ----------
template <int RELU, int RES, int ROWBIAS, int ACCUM>
__global__ __launch_bounds__(256) void gemm_bt(const unsigned short* __restrict__ A,
                                               const unsigned short* __restrict__ W,
                                               const float* __restrict__ bias,
                                               const float* __restrict__ bias2, int b2off,
                                               const float* __restrict__ resid,
                                               float* __restrict__ outF,
                                               unsigned short* __restrict__ outB,
                                               int M, int N, int K, int sA, int sW) {
  __shared__ unsigned short Al[2][128 * 32];
  __shared__ unsigned short Bl[2][128 * 32];
  int nbn = N >> 7;
  int nwg = gridDim.x;
  int bid = blockIdx.x;
  int wg = (bid & 7) * (nwg >> 3) + (bid >> 3);  // XCD swizzle (nwg % 8 == 0)
  int tm = wg / nbn, tn = wg % nbn;
  int tid = threadIdx.x;
  int wave = tid >> 6, lane = tid & 63;
  int wm = wave >> 1, wn = wave & 1;
  const unsigned short* Ab = A + (size_t)tm * 128 * sA;
  const unsigned short* Wb = W + (size_t)tn * 128 * sW;
  f32x4 acc[4][4] = {};
  int c0 = wave * 128 + lane;
  int r0 = c0 >> 2, cc0 = (c0 & 3) * 8;
  int c1 = c0 + 64;
  int r1 = c1 >> 2, cc1 = (c1 & 3) * 8;
  int arow = wm * 64 + (lane & 15);
  int brow = wn * 64 + (lane & 15);
  int kf = (lane >> 4) * 8;

  auto stage = [&](int buf, int k0) {
    gld16(Ab + (size_t)r0 * sA + k0 + cc0, &Al[buf][(wave * 128) * 8]);
    gld16(Ab + (size_t)r1 * sA + k0 + cc1, &Al[buf][(wave * 128 + 64) * 8]);
    gld16(Wb + (size_t)r0 * sW + k0 + cc0, &Bl[buf][(wave * 128) * 8]);
    gld16(Wb + (size_t)r1 * sW + k0 + cc1, &Bl[buf][(wave * 128 + 64) * 8]);
  };

  stage(0, 0);
  __syncthreads();
  int cur = 0;
  for (int k0 = 0; k0 < K; k0 += 32) {
    if (k0 + 32 < K) stage(cur ^ 1, k0 + 32);
    bf16x8 af[4], bfr[4];
#pragma unroll
    for (int i = 0; i < 4; ++i) af[i] = *(const bf16x8*)&Al[cur][(arow + i * 16) * 32 + kf];
#pragma unroll
    for (int j = 0; j < 4; ++j) bfr[j] = *(const bf16x8*)&Bl[cur][(brow + j * 16) * 32 + kf];
    __builtin_amdgcn_s_setprio(1);
#pragma unroll
    for (int i = 0; i < 4; ++i)
#pragma unroll
      for (int j = 0; j < 4; ++j)
        acc[i][j] = __builtin_amdgcn_mfma_f32_16x16x32_bf16(af[i], bfr[j], acc[i][j], 0, 0, 0);
    __builtin_amdgcn_s_setprio(0);
    __syncthreads();
    cur ^= 1;
  }

  int row0 = tm * 128 + wm * 64 + (lane >> 4) * 4;
  int col0 = tn * 128 + wn * 64 + (lane & 15);
#pragma unroll
  for (int i = 0; i < 4; ++i) {
#pragma unroll
    for (int j = 0; j < 4; ++j) {
      int col = col0 + j * 16;
      float bb = 0.0f;
      if (!ROWBIAS && bias != nullptr)
        bb = (bias2 != nullptr && col >= b2off) ? bias2[col - b2off] : bias[col];
#pragma unroll
      for (int r = 0; r < 4; ++r) {
        int row = row0 + i * 16 + r;
        float v = acc[i][j][r] + (ROWBIAS ? bias[row] : bb);
        if (RELU) v = fmaxf(v, 0.0f);
        size_t idx = (size_t)row * N + col;
        if (ACCUM) outF[idx] += v;
        else if (RES) outF[idx] = resid[idx] + v;
        else outB[idx] = f2b(v);
      }
    }
  }
}

// ---------- GEMM 256x256 8-wave, BK=64, counted-vmcnt pipeline (T3+T4) ----------
// C[M,N] = act(A[M,K] @ W[N,K]^T + bias), bf16 out. Requires M%256==0, N%256==0,
// K%64==0, K>=192, grid=(M/256)*(N/256)%8==0.
// LDS: 2 buf x 4 slots (A0,A1,B0,B1), each [128][64] bf16, chunk-XOR swizzled
// (phys chunk = logical ^ (row&7)) via pre-swizzled global source. Per K-tile t,
// 4 phases (output quadrants); phase stages one half-tile 3-4 phases ahead;
// ONE counted s_waitcnt vmcnt(4) per tile (never 0 mid-loop); raw s_barrier.
template <int RELU, int BIAS2>
__global__ __launch_bounds__(512, 1) void gemm256(const unsigned short* __restrict__ A,
                                                  const unsigned short* __restrict__ W,
                                                  const float* __restrict__ bias,
                                                  const float* __restrict__ bias2, int b2off,
                                                  unsigned short* __restrict__ outB,
                                                  int M, int N, int K, int sA, int sW) {
  __shared__ unsigned short lds[2][4][128 * 64];  // 128 KB
  int nbn = N >> 8;
  int nwg = gridDim.x;
  int bid = blockIdx.x;
  int wg = (bid & 7) * (nwg >> 3) + (bid >> 3);  // XCD swizzle (nwg % 8 == 0)
  int tm = wg / nbn, tn = wg % nbn;
  int tid = threadIdx.x;
  int wave = tid >> 6, lane = tid & 63;
  int wr = wave >> 2, wc = wave & 3;  // 2 x 4 wave grid; per-wave C = 128 x 64
  int l15 = lane & 15, g = lane >> 4;
  int nt = K >> 6;

  const unsigned short* Abase = A + (size_t)(tm * 256) * sA;
  const unsigned short* Wbase = W + (size_t)(tn * 256) * sW;
  int srow = tid >> 3;                    // staged row (issue 0), +64 for issue 1
  int schunk = (tid & 7) ^ (srow & 7);    // inverse-swizzled logical chunk to fetch

  f32x4 acc[8][4] = {};
  bf16x8 afr[2][2], bfr[2][4];

  // stage half-tile: slot s (0,1 = A rows s*128..; 2,3 = W rows (s-2)*128..), tile kt
  auto stage = [&](int buf, int s, int kt) {
    const unsigned short* base = (s < 2) ? Abase : Wbase;
    int str = (s < 2) ? sA : sW;
    int rbase = (s & 1) * 128;
#pragma unroll
    for (int e = 0; e < 2; ++e) {
      gld16(base + (size_t)(rbase + srow + e * 64) * str + kt * 64 + schunk * 8,
            &lds[buf][s][wave * 512 + e * 4096]);  // wave-uniform dest
    }
  };

  // prologue: B0(0),B1(0),A0(0),A1(0) -> buf0; B0(1),B1(1) -> buf1
  stage(0, 2, 0); stage(0, 3, 0); stage(0, 0, 0); stage(0, 1, 0);
  stage(1, 2, 1); stage(1, 3, 1);
  asm volatile("s_waitcnt vmcnt(4)" ::: "memory");  // tile 0 fully landed
  __builtin_amdgcn_s_barrier();

#define PHASE(q)                                                                     \
  {                                                                                  \
    __builtin_amdgcn_sched_barrier(0);                                               \
    if ((q) == 0 && t + 1 < nt) stage(buf ^ 1, 0, t + 1);                            \
    if ((q) == 1 && t + 1 < nt) stage(buf ^ 1, 1, t + 1);                            \
    if ((q) == 2 && t + 2 < nt) stage(buf, 2, t + 2);                                \
    if ((q) == 3 && t + 2 < nt) stage(buf, 3, t + 2);                                \
    if ((q) == 0) {                                                                  \
      const unsigned short* Bh = &lds[buf][2 + (wc >> 1)][0];                        \
      _Pragma("unroll") for (int kk = 0; kk < 2; ++kk)                               \
          _Pragma("unroll") for (int j = 0; j < 4; ++j) {                            \
        int br = (wc & 1) * 64 + j * 16 + l15;                                       \
        bfr[kk][j] = *(const bf16x8*)&Bh[br * 64 + (((kk * 4 + g) ^ (br & 7)) * 8)]; \
      }                                                                              \
    }                                                                                \
    {                                                                                \
      const unsigned short* Ah = &lds[buf][wr][0];                                   \
      _Pragma("unroll") for (int kk = 0; kk < 2; ++kk)                               \
          _Pragma("unroll") for (int ri = 0; ri < 2; ++ri) {                         \
        int ar = (q) * 32 + ri * 16 + l15;                                           \
        afr[kk][ri] = *(const bf16x8*)&Ah[ar * 64 + (((kk * 4 + g) ^ (ar & 7)) * 8)];\
      }                                                                              \
    }                                                                                \
    __builtin_amdgcn_s_setprio(1);                                                   \
    _Pragma("unroll") for (int kk = 0; kk < 2; ++kk)                                 \
        _Pragma("unroll") for (int ri = 0; ri < 2; ++ri)                             \
            _Pragma("unroll") for (int j = 0; j < 4; ++j)                            \
      acc[(q) * 2 + ri][j] = __builtin_amdgcn_mfma_f32_16x16x32_bf16(                \
          afr[kk][ri], bfr[kk][j], acc[(q) * 2 + ri][j], 0, 0, 0);                   \
    __builtin_amdgcn_s_setprio(0);                                                   \
    if ((q) == 3) {                                                                  \
      if (t + 2 < nt) asm volatile("s_waitcnt vmcnt(4)" ::: "memory");               \
      else asm volatile("s_waitcnt vmcnt(0)" ::: "memory");                          \
    }                                                                                \
    __builtin_amdgcn_s_barrier();                                                    \
  }

  for (int t = 0; t < nt; ++t) {
    int buf = t & 1;
    PHASE(0)
    PHASE(1)
    PHASE(2)
    PHASE(3)
  }
#undef PHASE

  // epilogue
  int row0 = tm * 256 + wr * 128 + g * 4;
  int col0 = tn * 256 + wc * 64 + l15;
#pragma unroll
  for (int i = 0; i < 8; ++i) {
#pragma unroll
    for (int j = 0; j < 4; ++j) {
      int col = col0 + j * 16;
      float bb = (BIAS2 && col >= b2off) ? bias2[col - b2off] : bias[col];
#pragma unroll
      for (int r = 0; r < 4; ++r) {
        int row = row0 + i * 16 + r;
        float v = acc[i][j][r] + bb;
        if (RELU) v = fmaxf(v, 0.0f);
        outB[(size_t)row * N + col] = f2b(v);
      }
    }
  }
}

// ---------- flash attention v4 (unchanged from R6) ----------
__global__ __launch_bounds__(256) void attn_fwd4(const unsigned short* __restrict__ QK,
                                                 const unsigned short* __restrict__ Vt,
                                                 const int* __restrict__ mask,
                                                 unsigned short* __restrict__ O) {
  __shared__ unsigned short Kl[2][64 * 64];
  __shared__ unsigned short Vl[2][64 * 64];
  __shared__ float biasl[1024];
  int bid = blockIdx.x;
  int wg = (bid & 7) * 256 + (bid >> 3);
  int qt = wg & 15, bh = wg >> 4;
  int b = bh >> 4, h = bh & 15;
  int tid = threadIdx.x, wave = tid >> 6, lane = tid & 63;
  int l15 = lane & 15, g = lane >> 4;
  int q0 = qt * 64;

  for (int i = tid; i < 1024; i += 256)
    biasl[i] = (mask[b * 1024 + i] == 0) ? -1.4426950e9f : 0.0f;

  const unsigned short* Qrow = QK + ((size_t)(b * 1024 + q0 + wave * 16 + l15)) * 2048 + h * 64;
  bf16x8 qf0 = *(const bf16x8*)(Qrow + g * 8);
  bf16x8 qf1 = *(const bf16x8*)(Qrow + 32 + g * 8);

  float m_q = -3e38f, l_q = 0.0f;
  f32x4 o[4] = {};

  int srow = lane >> 3;
  int clog = (lane & 7) ^ srow;
  int h7 = l15 & 7;
  const float SC = 0.125f * 1.44269504f;

  auto stageKV = [&](int buf, int kt) {
#pragma unroll
    for (int i = 0; i < 2; ++i) {
      int rk = wave * 16 + i * 8 + srow;
      gld16(QK + ((size_t)(b * 1024 + kt * 64 + rk)) * 2048 + 1024 + h * 64 + clog * 8,
            &Kl[buf][(wave * 16 + i * 8) * 64]);
      gld16(Vt + ((size_t)(h * 64 + rk)) * 8192 + b * 1024 + kt * 64 + clog * 8,
            &Vl[buf][(wave * 16 + i * 8) * 64]);
    }
  };

  stageKV(0, 0);
  __syncthreads();
  int cur = 0;

  for (int kt = 0; kt < 16; ++kt) {
    if (kt < 15) stageKV(cur ^ 1, kt + 1);

    f32x4 st[4];
    __builtin_amdgcn_s_setprio(1);
#pragma unroll
    for (int j = 0; j < 4; ++j) {
      int kr = j * 16 + l15;
      bf16x8 ka = *(const bf16x8*)&Kl[cur][kr * 64 + ((g ^ h7) * 8)];
      bf16x8 kb = *(const bf16x8*)&Kl[cur][kr * 64 + (((4 + g) ^ h7) * 8)];
      f32x4 z = {};
      st[j] = __builtin_amdgcn_mfma_f32_16x16x32_bf16(ka, qf0, z, 0, 0, 0);
      st[j] = __builtin_amdgcn_mfma_f32_16x16x32_bf16(kb, qf1, st[j], 0, 0, 0);
    }
    __builtin_amdgcn_s_setprio(0);

    float p[4][4];
    float tmax = -3e38f;
#pragma unroll
    for (int j = 0; j < 4; ++j) {
      float4 b4 = *(const float4*)&biasl[kt * 64 + j * 16 + g * 4];
#pragma unroll
      for (int r = 0; r < 4; ++r) {
        float v = st[j][r] * SC + ((const float*)&b4)[r];
        p[j][r] = v;
        tmax = fmaxf(tmax, v);
      }
    }
    tmax = fmaxf(tmax, __shfl_xor(tmax, 16));
    tmax = fmaxf(tmax, __shfl_xor(tmax, 32));

    if (__any(tmax > m_q + 8.0f)) {
      float mnew = fmaxf(m_q, tmax);
      float scq = exp2_fast(m_q - mnew);
#pragma unroll
      for (int dt = 0; dt < 4; ++dt)
#pragma unroll
        for (int r = 0; r < 4; ++r) o[dt][r] *= scq;
      l_q *= scq;
      m_q = mnew;
    }

    float lsum = 0.0f;
#pragma unroll
    for (int j = 0; j < 4; ++j)
#pragma unroll
      for (int r = 0; r < 4; ++r) {
        float e = exp2_fast(p[j][r] - m_q);
        p[j][r] = e;
        lsum += e;
      }
    lsum += __shfl_xor(lsum, 16);
    lsum += __shfl_xor(lsum, 32);
    l_q += lsum;

    union U8 { uint32_t u[4]; bf16x8 v; } pa[2];
#pragma unroll
    for (int j = 0; j < 4; ++j) {
      pa[j >> 1].u[(j & 1) * 2 + 0] = cvtpk(p[j][0], p[j][1]);
      pa[j >> 1].u[(j & 1) * 2 + 1] = cvtpk(p[j][2], p[j][3]);
    }

#pragma unroll
    for (int kk = 0; kk < 2; ++kk) {
#pragma unroll
      for (int dt = 0; dt < 4; ++dt) {
        int vr = dt * 16 + l15;
        uint2 lo = *(const uint2*)&Vl[cur][vr * 64 + (((4 * kk + (g >> 1)) ^ h7) * 8) + (g & 1) * 4];
        uint2 hi = *(const uint2*)&Vl[cur][vr * 64 + (((4 * kk + 2 + (g >> 1)) ^ h7) * 8) + (g & 1) * 4];
        union U8 vbu;
        vbu.u[0] = lo.x; vbu.u[1] = lo.y; vbu.u[2] = hi.x; vbu.u[3] = hi.y;
        __builtin_amdgcn_s_setprio(1);
        o[dt] = __builtin_amdgcn_mfma_f32_16x16x32_bf16(vbu.v, pa[kk].v, o[dt], 0, 0, 0);
        __builtin_amdgcn_s_setprio(0);
      }
    }

    __syncthreads();
    cur ^= 1;
  }

  float inv = 1.0f / l_q;
  size_t orow = ((size_t)(b * 1024 + q0 + wave * 16 + l15)) * 1024 + h * 64;
#pragma unroll
  for (int dt = 0; dt < 4; ++dt) {
    uint2 w;
    w.x = cvtpk(o[dt][0] * inv, o[dt][1] * inv);
    w.y = cvtpk(o[dt][2] * inv, o[dt][3] * inv);
    *(uint2*)&O[orow + dt * 16 + g * 4] = w;
  }
}

// ---------- launch ----------
extern "C" void kernel_launch(void* const* d_in, const int* in_sizes, int n_in,
                              void* d_out, int out_size, void* d_ws, size_t ws_size,
                              hipStream_t stream) {
  const float* X = (const float*)d_in[0];
  const int* mask = (const int*)d_in[1];
  const float* wq = (const float*)d_in[2];
  const float* bq = (const float*)d_in[3];
  const float* wk = (const float*)d_in[4];
  const float* bk = (const float*)d_in[5];
  const float* wv = (const float*)d_in[6];
  const float* bv = (const float*)d_in[7];
  const float* wo = (const float*)d_in[8];
  const float* bo = (const float*)d_in[9];
  const float* w1 = (const float*)d_in[10];
  const float* b1 = (const float*)d_in[11];
  const float* w2 = (const float*)d_in[12];
  const float* b2 = (const float*)d_in[13];
  const float* ln1a = (const float*)d_in[14];
  const float* ln1b = (const float*)d_in[15];
  const float* ln2a = (const float*)d_in[16];
  const float* ln2b = (const float*)d_in[17];
  float* out = (float*)d_out;
  char* ws = (char*)d_ws;
  const size_t MB = 1024 * 1024;

  // layout (88MB): [0,8) w1_b | [8,16) w2_b | [16,20) wqk_b | [20,22) wv_b |
  // [22,24) wo_b | [24,40) xn (LN1 out -> attn O -> LN2 out) | [40,72) QKb -> hb |
  // [72,88) Vtb
  unsigned short* w1_b = (unsigned short*)(ws + 0 * MB);
  unsigned short* w2_b = (unsigned short*)(ws + 8 * MB);
  unsigned short* wqk_b = (unsigned short*)(ws + 16 * MB);
  unsigned short* wv_b = (unsigned short*)(ws + 20 * MB);
  unsigned short* wo_b = (unsigned short*)(ws + 22 * MB);
  unsigned short* xn = (unsigned short*)(ws + 24 * MB);
  unsigned short* QKb = (unsigned short*)(ws + 40 * MB);
  unsigned short* Vtb = (unsigned short*)(ws + 72 * MB);
  unsigned short* hb = QKb;

  // all weights -> bf16 in one launch (wq,wk stacked into wqk_b)
  cast_all<<<12288, 256, 0, stream>>>(w1, w2, wq, wk, wv, wo, w1_b, w2_b, wqk_b, wv_b, wo_b);

  // LN1
  ln_bf16<<<8192, 256, 0, stream>>>(X, xn, ln1a, ln1b);
  // fused Q+K projection: QK[token][2048]  (8-phase 256^2, grid 256 = 1/CU)
  gemm256<0, 1><<<256, 512, 0, stream>>>(xn, wqk_b, bq, bk, 1024, QKb,
                                         8192, 2048, 1024, 1024, 1024);
  // V transposed: Vt[hd][token] = wv @ xn^T + bv (row bias)
  gemm_bt<0, 0, 1, 0><<<512, 256, 0, stream>>>(wv_b, xn, bv, nullptr, 0, nullptr, nullptr, Vtb,
                                               1024, 8192, 1024, 1024, 1024);
  // attention (writes O into xn buffer)
  attn_fwd4<<<2048, 256, 0, stream>>>(QKb, Vtb, mask, xn);
  // out = X + O @ wo^T + bo
  gemm_bt<0, 1, 0, 0><<<512, 256, 0, stream>>>(xn, wo_b, bo, nullptr, 0, X, out, nullptr,
                                               8192, 1024, 1024, 1024, 1024);
  // LN2 (reads out, writes into xn region)
  ln_bf16<<<8192, 256, 0, stream>>>(out, xn, ln2a, ln2b);
  // FFN chunked along hidden dim: h half = [8192][2048] in hb (QKb region)
  for (int hc = 0; hc < 2; ++hc) {
    // h = relu(xn @ w1[hc*2048:(hc+1)*2048]^T + b1[hc*2048:])  (8-phase 256^2)
    gemm256<1, 0><<<256, 512, 0, stream>>>(xn, w1_b + (size_t)hc * 2048 * 1024,
                                           b1 + hc * 2048, nullptr, 0, hb,
                                           8192, 2048, 1024, 1024, 1024);
    if (hc == 0)  // out = out + b2 + h_half @ w2[:, 0:2048]^T
      gemm_bt<0, 1, 0, 0><<<512, 256, 0, stream>>>(hb, w2_b, b2, nullptr, 0, out, out, nullptr,
                                                   8192, 1024, 2048, 2048, 4096);
    else          // out += h_half @ w2[:, 2048:4096]^T
      gemm_bt<0, 0, 0, 1><<<512, 256, 0, stream>>>(hb, w2_b + 2048, nullptr, nullptr, 0, nullptr,
                                                   out, nullptr, 8192, 1024, 2048, 2048, 4096);
  }
}

// Round 8
// 367.521 us; speedup vs baseline: 1.5864x; 1.1111x over previous
//
#include <hip/hip_runtime.h>
#include <cstdint>
#include <cstddef>

// ---------- types ----------
typedef float f32x4 __attribute__((ext_vector_type(4)));
typedef short bf16x8 __attribute__((ext_vector_type(8)));

typedef __attribute__((address_space(1))) void void_g;
typedef __attribute__((address_space(3))) void void_l;

__device__ __forceinline__ void gld16(const void* g, void* l) {
  // async global->LDS, 16B per lane; LDS dest = wave-uniform base + lane*16
  __builtin_amdgcn_global_load_lds((void_g*)g, (void_l*)l, 16, 0, 0);
}

__device__ __forceinline__ unsigned short f2b(float f) {
  union { float f; uint32_t u; } c; c.f = f;
  uint32_t u = c.u;
  return (unsigned short)((u + 0x7fffu + ((u >> 16) & 1u)) >> 16);  // RNE
}

__device__ __forceinline__ uint32_t cvtpk(float lo, float hi) {
  uint32_t r;
  asm("v_cvt_pk_bf16_f32 %0, %1, %2" : "=v"(r) : "v"(lo), "v"(hi));
  return r;  // low16 = bf16(lo), high16 = bf16(hi)
}

__device__ __forceinline__ float exp2_fast(float x) {
  return __builtin_exp2f(x);  // lowers to v_exp_f32 (2^x) on gfx950
}

// ---------- all weight casts fp32 -> bf16 in one launch ----------
__global__ __launch_bounds__(256) void cast_all(const float* __restrict__ w1,
                                                const float* __restrict__ w2,
                                                const float* __restrict__ wq,
                                                const float* __restrict__ wk,
                                                const float* __restrict__ wv,
                                                const float* __restrict__ wo,
                                                unsigned short* __restrict__ d1,
                                                unsigned short* __restrict__ d2,
                                                unsigned short* __restrict__ dqk,
                                                unsigned short* __restrict__ dv,
                                                unsigned short* __restrict__ dod) {
  int blk = blockIdx.x;
  const float* s;
  unsigned short* d;
  int off;
  if (blk < 4096) { s = w1; d = d1; off = blk; }
  else if (blk < 8192) { s = w2; d = d2; off = blk - 4096; }
  else if (blk < 9216) { s = wq; d = dqk; off = blk - 8192; }
  else if (blk < 10240) { s = wk; d = dqk + (1 << 20); off = blk - 9216; }
  else if (blk < 11264) { s = wv; d = dv; off = blk - 10240; }
  else { s = wo; d = dod; off = blk - 11264; }
  int i = off * 256 + threadIdx.x;
  float4 v = ((const float4*)s)[i];
  ushort4 o;
  o.x = f2b(v.x); o.y = f2b(v.y); o.z = f2b(v.z); o.w = f2b(v.w);
  ((ushort4*)d)[i] = o;
}

// ---------- LayerNorm (unbiased std, scalar alpha/beta) -> bf16 ----------
__global__ __launch_bounds__(256) void ln_bf16(const float* __restrict__ X,
                                               unsigned short* __restrict__ out,
                                               const float* __restrict__ alpha,
                                               const float* __restrict__ beta) {
  int row = blockIdx.x;
  int tid = threadIdx.x;
  float4 v = ((const float4*)(X + (size_t)row * 1024))[tid];
  float s = v.x + v.y + v.z + v.w;
  float q = v.x * v.x + v.y * v.y + v.z * v.z + v.w * v.w;
#pragma unroll
  for (int m = 1; m < 64; m <<= 1) { s += __shfl_xor(s, m); q += __shfl_xor(q, m); }
  __shared__ float red[8];
  int wave = tid >> 6;
  if ((tid & 63) == 0) { red[wave] = s; red[4 + wave] = q; }
  __syncthreads();
  s = red[0] + red[1] + red[2] + red[3];
  q = red[4] + red[5] + red[6] + red[7];
  float mean = s * (1.0f / 1024.0f);
  float var = fmaxf((q - 1024.0f * mean * mean) * (1.0f / 1023.0f), 0.0f);
  float inv = alpha[0] / (sqrtf(var) + 1e-6f);
  float b = beta[0];
  ushort4 o;
  o.x = f2b((v.x - mean) * inv + b);
  o.y = f2b((v.y - mean) * inv + b);
  o.z = f2b((v.z - mean) * inv + b);
  o.w = f2b((v.w - mean) * inv + b);
  ((ushort4*)(out + (size_t)row * 1024))[tid] = o;
}

// ---------- GEMM 256x256 8-wave, BK=64, counted-vmcnt pipeline (T3+T4) ----------
// (unchanged from R7 — QK-fused and w1 dispatches, grid=(M/256)*(N/256)%8==0)
template <int RELU, int BIAS2>
__global__ __launch_bounds__(512, 1) void gemm256(const unsigned short* __restrict__ A,
                                                  const unsigned short* __restrict__ W,
                                                  const float* __restrict__ bias,
                                                  const float* __restrict__ bias2, int b2off,
                                                  unsigned short* __restrict__ outB,
                                                  int M, int N, int K, int sA, int sW) {
  __shared__ unsigned short lds[2][4][128 * 64];  // 128 KB
  int nbn = N >> 8;
  int nwg = gridDim.x;
  int bid = blockIdx.x;
  int wg = (bid & 7) * (nwg >> 3) + (bid >> 3);  // XCD swizzle (nwg % 8 == 0)
  int tm = wg / nbn, tn = wg % nbn;
  int tid = threadIdx.x;
  int wave = tid >> 6, lane = tid & 63;
  int wr = wave >> 2, wc = wave & 3;  // 2 x 4 wave grid; per-wave C = 128 x 64
  int l15 = lane & 15, g = lane >> 4;
  int nt = K >> 6;

  const unsigned short* Abase = A + (size_t)(tm * 256) * sA;
  const unsigned short* Wbase = W + (size_t)(tn * 256) * sW;
  int srow = tid >> 3;
  int schunk = (tid & 7) ^ (srow & 7);

  f32x4 acc[8][4] = {};
  bf16x8 afr[2][2], bfr[2][4];

  auto stage = [&](int buf, int s, int kt) {
    const unsigned short* base = (s < 2) ? Abase : Wbase;
    int str = (s < 2) ? sA : sW;
    int rbase = (s & 1) * 128;
#pragma unroll
    for (int e = 0; e < 2; ++e) {
      gld16(base + (size_t)(rbase + srow + e * 64) * str + kt * 64 + schunk * 8,
            &lds[buf][s][wave * 512 + e * 4096]);
    }
  };

  stage(0, 2, 0); stage(0, 3, 0); stage(0, 0, 0); stage(0, 1, 0);
  stage(1, 2, 1); stage(1, 3, 1);
  asm volatile("s_waitcnt vmcnt(4)" ::: "memory");
  __builtin_amdgcn_s_barrier();

#define PHASE(q)                                                                     \
  {                                                                                  \
    __builtin_amdgcn_sched_barrier(0);                                               \
    if ((q) == 0 && t + 1 < nt) stage(buf ^ 1, 0, t + 1);                            \
    if ((q) == 1 && t + 1 < nt) stage(buf ^ 1, 1, t + 1);                            \
    if ((q) == 2 && t + 2 < nt) stage(buf, 2, t + 2);                                \
    if ((q) == 3 && t + 2 < nt) stage(buf, 3, t + 2);                                \
    if ((q) == 0) {                                                                  \
      const unsigned short* Bh = &lds[buf][2 + (wc >> 1)][0];                        \
      _Pragma("unroll") for (int kk = 0; kk < 2; ++kk)                               \
          _Pragma("unroll") for (int j = 0; j < 4; ++j) {                            \
        int br = (wc & 1) * 64 + j * 16 + l15;                                       \
        bfr[kk][j] = *(const bf16x8*)&Bh[br * 64 + (((kk * 4 + g) ^ (br & 7)) * 8)]; \
      }                                                                              \
    }                                                                                \
    {                                                                                \
      const unsigned short* Ah = &lds[buf][wr][0];                                   \
      _Pragma("unroll") for (int kk = 0; kk < 2; ++kk)                               \
          _Pragma("unroll") for (int ri = 0; ri < 2; ++ri) {                         \
        int ar = (q) * 32 + ri * 16 + l15;                                           \
        afr[kk][ri] = *(const bf16x8*)&Ah[ar * 64 + (((kk * 4 + g) ^ (ar & 7)) * 8)];\
      }                                                                              \
    }                                                                                \
    __builtin_amdgcn_s_setprio(1);                                                   \
    _Pragma("unroll") for (int kk = 0; kk < 2; ++kk)                                 \
        _Pragma("unroll") for (int ri = 0; ri < 2; ++ri)                             \
            _Pragma("unroll") for (int j = 0; j < 4; ++j)                            \
      acc[(q) * 2 + ri][j] = __builtin_amdgcn_mfma_f32_16x16x32_bf16(                \
          afr[kk][ri], bfr[kk][j], acc[(q) * 2 + ri][j], 0, 0, 0);                   \
    __builtin_amdgcn_s_setprio(0);                                                   \
    if ((q) == 3) {                                                                  \
      if (t + 2 < nt) asm volatile("s_waitcnt vmcnt(4)" ::: "memory");               \
      else asm volatile("s_waitcnt vmcnt(0)" ::: "memory");                          \
    }                                                                                \
    __builtin_amdgcn_s_barrier();                                                    \
  }

  for (int t = 0; t < nt; ++t) {
    int buf = t & 1;
    PHASE(0)
    PHASE(1)
    PHASE(2)
    PHASE(3)
  }
#undef PHASE

  int row0 = tm * 256 + wr * 128 + g * 4;
  int col0 = tn * 256 + wc * 64 + l15;
#pragma unroll
  for (int i = 0; i < 8; ++i) {
#pragma unroll
    for (int j = 0; j < 4; ++j) {
      int col = col0 + j * 16;
      float bb = (BIAS2 && col >= b2off) ? bias2[col - b2off] : bias[col];
#pragma unroll
      for (int r = 0; r < 4; ++r) {
        int row = row0 + i * 16 + r;
        float v = acc[i][j][r] + bb;
        if (RELU) v = fmaxf(v, 0.0f);
        outB[(size_t)row * N + col] = f2b(v);
      }
    }
  }
}

// ---------- GEMM 256x128 8-wave, BK=64, counted-vmcnt (for N%128 shapes) ----------
// grid = (M/256)*(N/128), must be %8==0. LDS 96KB: slots {A0,A1,B} x 2 buf.
// vmcnt ledger (2 loads/half-tile): phase0 stages A0(t+1), phase1 A1(t+1),
// phase2 B(t+2); at phase3 outstanding = {B(t+1),A0(t+1),A1(t+1),B(t+2)} = 8
// -> vmcnt(2) retires tile t+1 exactly, keeps B(t+2) in flight.
// MODE: 1 = bf16 out + row bias; 2 = fp32 out = resid + v + col bias; 3 = fp32 out += v.
template <int MODE>
__global__ __launch_bounds__(512, 1) void gemm256x128(const unsigned short* __restrict__ A,
                                                      const unsigned short* __restrict__ W,
                                                      const float* __restrict__ bias,
                                                      const float* __restrict__ resid,
                                                      float* __restrict__ outF,
                                                      unsigned short* __restrict__ outB,
                                                      int M, int N, int K, int sA, int sW) {
  __shared__ unsigned short lds[2][3][128 * 64];  // 96 KB
  int nbn = N >> 7;
  int nwg = gridDim.x;
  int bid = blockIdx.x;
  int wg = (bid & 7) * (nwg >> 3) + (bid >> 3);  // XCD swizzle (nwg % 8 == 0)
  int tm = wg / nbn, tn = wg % nbn;
  int tid = threadIdx.x;
  int wave = tid >> 6, lane = tid & 63;
  int wr = wave >> 2, wc = wave & 3;  // per-wave C = 128 rows x 32 cols
  int l15 = lane & 15, g = lane >> 4;
  int nt = K >> 6;

  const unsigned short* Abase = A + (size_t)(tm * 256) * sA;
  const unsigned short* Wbase = W + (size_t)(tn * 128) * sW;
  int srow = tid >> 3;
  int schunk = (tid & 7) ^ (srow & 7);

  f32x4 acc[8][2] = {};
  bf16x8 afr[2][2], bfr[2][2];

  auto stage = [&](int buf, int s, int kt) {
    const unsigned short* base = (s < 2) ? Abase : Wbase;
    int str = (s < 2) ? sA : sW;
    int rbase = (s & 1) * 128;  // s=2 -> 0
#pragma unroll
    for (int e = 0; e < 2; ++e) {
      gld16(base + (size_t)(rbase + srow + e * 64) * str + kt * 64 + schunk * 8,
            &lds[buf][s][wave * 512 + e * 4096]);
    }
  };

  // prologue: B(0),A0(0),A1(0) -> buf0 (6 loads); B(1) -> buf1 (2 loads)
  stage(0, 2, 0); stage(0, 0, 0); stage(0, 1, 0);
  stage(1, 2, 1);
  asm volatile("s_waitcnt vmcnt(2)" ::: "memory");
  __builtin_amdgcn_s_barrier();

#define PHASE(q)                                                                     \
  {                                                                                  \
    __builtin_amdgcn_sched_barrier(0);                                               \
    if ((q) == 0 && t + 1 < nt) stage(buf ^ 1, 0, t + 1);                            \
    if ((q) == 1 && t + 1 < nt) stage(buf ^ 1, 1, t + 1);                            \
    if ((q) == 2 && t + 2 < nt) stage(buf, 2, t + 2);                                \
    if ((q) == 0) {                                                                  \
      const unsigned short* Bh = &lds[buf][2][0];                                    \
      _Pragma("unroll") for (int kk = 0; kk < 2; ++kk)                               \
          _Pragma("unroll") for (int j = 0; j < 2; ++j) {                            \
        int br = wc * 32 + j * 16 + l15;                                             \
        bfr[kk][j] = *(const bf16x8*)&Bh[br * 64 + (((kk * 4 + g) ^ (br & 7)) * 8)]; \
      }                                                                              \
    }                                                                                \
    {                                                                                \
      const unsigned short* Ah = &lds[buf][wr][0];                                   \
      _Pragma("unroll") for (int kk = 0; kk < 2; ++kk)                               \
          _Pragma("unroll") for (int ri = 0; ri < 2; ++ri) {                         \
        int ar = (q) * 32 + ri * 16 + l15;                                           \
        afr[kk][ri] = *(const bf16x8*)&Ah[ar * 64 + (((kk * 4 + g) ^ (ar & 7)) * 8)];\
      }                                                                              \
    }                                                                                \
    __builtin_amdgcn_s_setprio(1);                                                   \
    _Pragma("unroll") for (int kk = 0; kk < 2; ++kk)                                 \
        _Pragma("unroll") for (int ri = 0; ri < 2; ++ri)                             \
            _Pragma("unroll") for (int j = 0; j < 2; ++j)                            \
      acc[(q) * 2 + ri][j] = __builtin_amdgcn_mfma_f32_16x16x32_bf16(                \
          afr[kk][ri], bfr[kk][j], acc[(q) * 2 + ri][j], 0, 0, 0);                   \
    __builtin_amdgcn_s_setprio(0);                                                   \
    if ((q) == 3) {                                                                  \
      if (t + 2 < nt) asm volatile("s_waitcnt vmcnt(2)" ::: "memory");               \
      else asm volatile("s_waitcnt vmcnt(0)" ::: "memory");                          \
    }                                                                                \
    __builtin_amdgcn_s_barrier();                                                    \
  }

  for (int t = 0; t < nt; ++t) {
    int buf = t & 1;
    PHASE(0)
    PHASE(1)
    PHASE(2)
    PHASE(3)
  }
#undef PHASE

  int row0 = tm * 256 + wr * 128 + g * 4;
  int col0 = tn * 128 + wc * 32 + l15;
#pragma unroll
  for (int i = 0; i < 8; ++i) {
#pragma unroll
    for (int j = 0; j < 2; ++j) {
      int col = col0 + j * 16;
      float cb = (MODE == 2) ? bias[col] : 0.0f;
#pragma unroll
      for (int r = 0; r < 4; ++r) {
        int row = row0 + i * 16 + r;
        size_t idx = (size_t)row * N + col;
        float v = acc[i][j][r];
        if (MODE == 1) outB[idx] = f2b(v + bias[row]);
        else if (MODE == 2) outF[idx] = resid[idx] + v + cb;
        else outF[idx] += v;
      }
    }
  }
}

// ---------- flash attention v5: no-max softmax (bounded scores), deferred l-reduce ----------
// QK [tok][2048] bf16 (Q cols 0-1023, K cols 1024-2047), Vt [h*64+d][tok] bf16.
// 1 block = (b,h,64-q-tile); 4 waves x 16 q-rows. KV tile = 64 keys.
// Scores bounded (|q.k|*SC <~ 5 in log2 domain) -> fixed m=0: P = exp2(s),
// mathematically exact softmax; l summed lane-partial, reduced once at end.
__global__ __launch_bounds__(256) void attn_fwd5(const unsigned short* __restrict__ QK,
                                                 const unsigned short* __restrict__ Vt,
                                                 const int* __restrict__ mask,
                                                 unsigned short* __restrict__ O) {
  __shared__ unsigned short Kl[2][64 * 64];
  __shared__ unsigned short Vl[2][64 * 64];
  __shared__ float biasl[1024];
  int bid = blockIdx.x;
  int wg = (bid & 7) * 256 + (bid >> 3);  // XCD swizzle: a head's 16 q-tiles on one XCD
  int qt = wg & 15, bh = wg >> 4;
  int b = bh >> 4, h = bh & 15;
  int tid = threadIdx.x, wave = tid >> 6, lane = tid & 63;
  int l15 = lane & 15, g = lane >> 4;
  int q0 = qt * 64;

  for (int i = tid; i < 1024; i += 256)
    biasl[i] = (mask[b * 1024 + i] == 0) ? -1.4426950e9f : 0.0f;

  const unsigned short* Qrow = QK + ((size_t)(b * 1024 + q0 + wave * 16 + l15)) * 2048 + h * 64;
  bf16x8 qf0 = *(const bf16x8*)(Qrow + g * 8);
  bf16x8 qf1 = *(const bf16x8*)(Qrow + 32 + g * 8);

  float l_q = 0.0f;   // lane-partial softmax denominator (q = l15)
  f32x4 o[4] = {};    // o[dt][r] = O[q=l15][d = dt*16 + g*4 + r]

  int srow = lane >> 3;
  int clog = (lane & 7) ^ srow;
  int h7 = l15 & 7;
  const float SC = 0.125f * 1.44269504f;  // 1/sqrt(64) * log2(e)

  auto stageKV = [&](int buf, int kt) {
#pragma unroll
    for (int i = 0; i < 2; ++i) {
      int rk = wave * 16 + i * 8 + srow;
      gld16(QK + ((size_t)(b * 1024 + kt * 64 + rk)) * 2048 + 1024 + h * 64 + clog * 8,
            &Kl[buf][(wave * 16 + i * 8) * 64]);
      gld16(Vt + ((size_t)(h * 64 + rk)) * 8192 + b * 1024 + kt * 64 + clog * 8,
            &Vl[buf][(wave * 16 + i * 8) * 64]);
    }
  };

  stageKV(0, 0);
  __syncthreads();
  int cur = 0;

  for (int kt = 0; kt < 16; ++kt) {
    if (kt < 15) stageKV(cur ^ 1, kt + 1);

    // S^T[key][q] = mfma(A=K, B=Q): lane holds q=l15, keys j*16+g*4+r
    f32x4 st[4];
    __builtin_amdgcn_s_setprio(1);
#pragma unroll
    for (int j = 0; j < 4; ++j) {
      int kr = j * 16 + l15;
      bf16x8 ka = *(const bf16x8*)&Kl[cur][kr * 64 + ((g ^ h7) * 8)];
      bf16x8 kb = *(const bf16x8*)&Kl[cur][kr * 64 + (((4 + g) ^ h7) * 8)];
      f32x4 z = {};
      st[j] = __builtin_amdgcn_mfma_f32_16x16x32_bf16(ka, qf0, z, 0, 0, 0);
      st[j] = __builtin_amdgcn_mfma_f32_16x16x32_bf16(kb, qf1, st[j], 0, 0, 0);
    }
    __builtin_amdgcn_s_setprio(0);

    // P = exp2(score*SC + maskbias); accumulate lane-partial l
    float p[4][4];
#pragma unroll
    for (int j = 0; j < 4; ++j) {
      float4 b4 = *(const float4*)&biasl[kt * 64 + j * 16 + g * 4];
#pragma unroll
      for (int r = 0; r < 4; ++r) {
        float e = exp2_fast(st[j][r] * SC + ((const float*)&b4)[r]);
        p[j][r] = e;
        l_q += e;
      }
    }

    // pack P into B-frags: pa[kk] element e = P[key = 32kk+16(e>>2)+4g+(e&3)][q=l15]
    union U8 { uint32_t u[4]; bf16x8 v; } pa[2];
#pragma unroll
    for (int j = 0; j < 4; ++j) {
      pa[j >> 1].u[(j & 1) * 2 + 0] = cvtpk(p[j][0], p[j][1]);
      pa[j >> 1].u[(j & 1) * 2 + 1] = cvtpk(p[j][2], p[j][3]);
    }

    // PV: O^T = mfma(A=V^T, B=P), same permuted key order on both operands
#pragma unroll
    for (int kk = 0; kk < 2; ++kk) {
#pragma unroll
      for (int dt = 0; dt < 4; ++dt) {
        int vr = dt * 16 + l15;
        uint2 lo = *(const uint2*)&Vl[cur][vr * 64 + (((4 * kk + (g >> 1)) ^ h7) * 8) + (g & 1) * 4];
        uint2 hi = *(const uint2*)&Vl[cur][vr * 64 + (((4 * kk + 2 + (g >> 1)) ^ h7) * 8) + (g & 1) * 4];
        union U8 vbu;
        vbu.u[0] = lo.x; vbu.u[1] = lo.y; vbu.u[2] = hi.x; vbu.u[3] = hi.y;
        __builtin_amdgcn_s_setprio(1);
        o[dt] = __builtin_amdgcn_mfma_f32_16x16x32_bf16(vbu.v, pa[kk].v, o[dt], 0, 0, 0);
        __builtin_amdgcn_s_setprio(0);
      }
    }

    __syncthreads();
    cur ^= 1;
  }

  // final l reduce across the 4 lane-copies of q=l15, then lane-local epilogue
  l_q += __shfl_xor(l_q, 16);
  l_q += __shfl_xor(l_q, 32);
  float inv = 1.0f / l_q;
  size_t orow = ((size_t)(b * 1024 + q0 + wave * 16 + l15)) * 1024 + h * 64;
#pragma unroll
  for (int dt = 0; dt < 4; ++dt) {
    uint2 w;
    w.x = cvtpk(o[dt][0] * inv, o[dt][1] * inv);
    w.y = cvtpk(o[dt][2] * inv, o[dt][3] * inv);
    *(uint2*)&O[orow + dt * 16 + g * 4] = w;
  }
}

// ---------- launch ----------
extern "C" void kernel_launch(void* const* d_in, const int* in_sizes, int n_in,
                              void* d_out, int out_size, void* d_ws, size_t ws_size,
                              hipStream_t stream) {
  const float* X = (const float*)d_in[0];
  const int* mask = (const int*)d_in[1];
  const float* wq = (const float*)d_in[2];
  const float* bq = (const float*)d_in[3];
  const float* wk = (const float*)d_in[4];
  const float* bk = (const float*)d_in[5];
  const float* wv = (const float*)d_in[6];
  const float* bv = (const float*)d_in[7];
  const float* wo = (const float*)d_in[8];
  const float* bo = (const float*)d_in[9];
  const float* w1 = (const float*)d_in[10];
  const float* b1 = (const float*)d_in[11];
  const float* w2 = (const float*)d_in[12];
  const float* b2 = (const float*)d_in[13];
  const float* ln1a = (const float*)d_in[14];
  const float* ln1b = (const float*)d_in[15];
  const float* ln2a = (const float*)d_in[16];
  const float* ln2b = (const float*)d_in[17];
  float* out = (float*)d_out;
  char* ws = (char*)d_ws;
  const size_t MB = 1024 * 1024;

  // layout (88MB): [0,8) w1_b | [8,16) w2_b | [16,20) wqk_b | [20,22) wv_b |
  // [22,24) wo_b | [24,40) xn (LN1 out -> attn O -> LN2 out) | [40,72) QKb -> hb |
  // [72,88) Vtb
  unsigned short* w1_b = (unsigned short*)(ws + 0 * MB);
  unsigned short* w2_b = (unsigned short*)(ws + 8 * MB);
  unsigned short* wqk_b = (unsigned short*)(ws + 16 * MB);
  unsigned short* wv_b = (unsigned short*)(ws + 20 * MB);
  unsigned short* wo_b = (unsigned short*)(ws + 22 * MB);
  unsigned short* xn = (unsigned short*)(ws + 24 * MB);
  unsigned short* QKb = (unsigned short*)(ws + 40 * MB);
  unsigned short* Vtb = (unsigned short*)(ws + 72 * MB);
  unsigned short* hb = QKb;

  // all weights -> bf16 in one launch (wq,wk stacked into wqk_b)
  cast_all<<<12288, 256, 0, stream>>>(w1, w2, wq, wk, wv, wo, w1_b, w2_b, wqk_b, wv_b, wo_b);

  // LN1
  ln_bf16<<<8192, 256, 0, stream>>>(X, xn, ln1a, ln1b);
  // fused Q+K projection: QK[token][2048]  (256^2 tile, grid 256 = 1/CU)
  gemm256<0, 1><<<256, 512, 0, stream>>>(xn, wqk_b, bq, bk, 1024, QKb,
                                         8192, 2048, 1024, 1024, 1024);
  // V transposed: Vt[hd][token] = wv @ xn^T + bv (row bias)  (256x128, grid 256)
  gemm256x128<1><<<256, 512, 0, stream>>>(wv_b, xn, bv, nullptr, nullptr, Vtb,
                                          1024, 8192, 1024, 1024, 1024);
  // attention (writes O into xn buffer)
  attn_fwd5<<<2048, 256, 0, stream>>>(QKb, Vtb, mask, xn);
  // out = X + O @ wo^T + bo  (256x128, grid 256)
  gemm256x128<2><<<256, 512, 0, stream>>>(xn, wo_b, bo, X, out, nullptr,
                                          8192, 1024, 1024, 1024, 1024);
  // LN2 (reads out, writes into xn region)
  ln_bf16<<<8192, 256, 0, stream>>>(out, xn, ln2a, ln2b);
  // FFN chunked along hidden dim: h half = [8192][2048] in hb (QKb region)
  for (int hc = 0; hc < 2; ++hc) {
    // h = relu(xn @ w1[hc*2048:(hc+1)*2048]^T + b1[hc*2048:])  (256^2)
    gemm256<1, 0><<<256, 512, 0, stream>>>(xn, w1_b + (size_t)hc * 2048 * 1024,
                                           b1 + hc * 2048, nullptr, 0, hb,
                                           8192, 2048, 1024, 1024, 1024);
    if (hc == 0)  // out = out + b2 + h_half @ w2[:, 0:2048]^T  (256x128)
      gemm256x128<2><<<256, 512, 0, stream>>>(hb, w2_b, b2, out, out, nullptr,
                                              8192, 1024, 2048, 2048, 4096);
    else          // out += h_half @ w2[:, 2048:4096]^T  (256x128)
      gemm256x128<3><<<256, 512, 0, stream>>>(hb, w2_b + 2048, nullptr, nullptr, out, nullptr,
                                              8192, 1024, 2048, 2048, 4096);
  }
}

// Round 9
// 364.854 us; speedup vs baseline: 1.5980x; 1.0073x over previous
//
#include <hip/hip_runtime.h>
#include <cstdint>
#include <cstddef>

// ---------- types ----------
typedef float f32x4 __attribute__((ext_vector_type(4)));
typedef short bf16x8 __attribute__((ext_vector_type(8)));

typedef __attribute__((address_space(1))) void void_g;
typedef __attribute__((address_space(3))) void void_l;

__device__ __forceinline__ void gld16(const void* g, void* l) {
  // async global->LDS, 16B per lane; LDS dest = wave-uniform base + lane*16
  __builtin_amdgcn_global_load_lds((void_g*)g, (void_l*)l, 16, 0, 0);
}

__device__ __forceinline__ unsigned short f2b(float f) {
  union { float f; uint32_t u; } c; c.f = f;
  uint32_t u = c.u;
  return (unsigned short)((u + 0x7fffu + ((u >> 16) & 1u)) >> 16);  // RNE
}

__device__ __forceinline__ uint32_t cvtpk(float lo, float hi) {
  uint32_t r;
  asm("v_cvt_pk_bf16_f32 %0, %1, %2" : "=v"(r) : "v"(lo), "v"(hi));
  return r;  // low16 = bf16(lo), high16 = bf16(hi)
}

__device__ __forceinline__ float exp2_fast(float x) {
  return __builtin_exp2f(x);  // lowers to v_exp_f32 (2^x) on gfx950
}

// ---------- all weight casts fp32 -> bf16 in one launch ----------
__global__ __launch_bounds__(256) void cast_all(const float* __restrict__ w1,
                                                const float* __restrict__ w2,
                                                const float* __restrict__ wq,
                                                const float* __restrict__ wk,
                                                const float* __restrict__ wv,
                                                const float* __restrict__ wo,
                                                unsigned short* __restrict__ d1,
                                                unsigned short* __restrict__ d2,
                                                unsigned short* __restrict__ dqk,
                                                unsigned short* __restrict__ dv,
                                                unsigned short* __restrict__ dod) {
  int blk = blockIdx.x;
  const float* s;
  unsigned short* d;
  int off;
  if (blk < 4096) { s = w1; d = d1; off = blk; }
  else if (blk < 8192) { s = w2; d = d2; off = blk - 4096; }
  else if (blk < 9216) { s = wq; d = dqk; off = blk - 8192; }
  else if (blk < 10240) { s = wk; d = dqk + (1 << 20); off = blk - 9216; }
  else if (blk < 11264) { s = wv; d = dv; off = blk - 10240; }
  else { s = wo; d = dod; off = blk - 11264; }
  int i = off * 256 + threadIdx.x;
  float4 v = ((const float4*)s)[i];
  ushort4 o;
  o.x = f2b(v.x); o.y = f2b(v.y); o.z = f2b(v.z); o.w = f2b(v.w);
  ((ushort4*)d)[i] = o;
}

// ---------- LayerNorm (unbiased std, scalar alpha/beta) -> bf16 ----------
__global__ __launch_bounds__(256) void ln_bf16(const float* __restrict__ X,
                                               unsigned short* __restrict__ out,
                                               const float* __restrict__ alpha,
                                               const float* __restrict__ beta) {
  int row = blockIdx.x;
  int tid = threadIdx.x;
  float4 v = ((const float4*)(X + (size_t)row * 1024))[tid];
  float s = v.x + v.y + v.z + v.w;
  float q = v.x * v.x + v.y * v.y + v.z * v.z + v.w * v.w;
#pragma unroll
  for (int m = 1; m < 64; m <<= 1) { s += __shfl_xor(s, m); q += __shfl_xor(q, m); }
  __shared__ float red[8];
  int wave = tid >> 6;
  if ((tid & 63) == 0) { red[wave] = s; red[4 + wave] = q; }
  __syncthreads();
  s = red[0] + red[1] + red[2] + red[3];
  q = red[4] + red[5] + red[6] + red[7];
  float mean = s * (1.0f / 1024.0f);
  float var = fmaxf((q - 1024.0f * mean * mean) * (1.0f / 1023.0f), 0.0f);
  float inv = alpha[0] / (sqrtf(var) + 1e-6f);
  float b = beta[0];
  ushort4 o;
  o.x = f2b((v.x - mean) * inv + b);
  o.y = f2b((v.y - mean) * inv + b);
  o.z = f2b((v.z - mean) * inv + b);
  o.w = f2b((v.w - mean) * inv + b);
  ((ushort4*)(out + (size_t)row * 1024))[tid] = o;
}

// ---------- GEMM 256x256 8-wave, BK=64, counted-vmcnt pipeline (T3+T4) ----------
template <int RELU, int BIAS2>
__global__ __launch_bounds__(512, 1) void gemm256(const unsigned short* __restrict__ A,
                                                  const unsigned short* __restrict__ W,
                                                  const float* __restrict__ bias,
                                                  const float* __restrict__ bias2, int b2off,
                                                  unsigned short* __restrict__ outB,
                                                  int M, int N, int K, int sA, int sW) {
  __shared__ unsigned short lds[2][4][128 * 64];  // 128 KB
  int nbn = N >> 8;
  int nwg = gridDim.x;
  int bid = blockIdx.x;
  int wg = (bid & 7) * (nwg >> 3) + (bid >> 3);  // XCD swizzle (nwg % 8 == 0)
  int tm = wg / nbn, tn = wg % nbn;
  int tid = threadIdx.x;
  int wave = tid >> 6, lane = tid & 63;
  int wr = wave >> 2, wc = wave & 3;  // 2 x 4 wave grid; per-wave C = 128 x 64
  int l15 = lane & 15, g = lane >> 4;
  int nt = K >> 6;

  const unsigned short* Abase = A + (size_t)(tm * 256) * sA;
  const unsigned short* Wbase = W + (size_t)(tn * 256) * sW;
  int srow = tid >> 3;
  int schunk = (tid & 7) ^ (srow & 7);

  f32x4 acc[8][4] = {};
  bf16x8 afr[2][2], bfr[2][4];

  auto stage = [&](int buf, int s, int kt) {
    const unsigned short* base = (s < 2) ? Abase : Wbase;
    int str = (s < 2) ? sA : sW;
    int rbase = (s & 1) * 128;
#pragma unroll
    for (int e = 0; e < 2; ++e) {
      gld16(base + (size_t)(rbase + srow + e * 64) * str + kt * 64 + schunk * 8,
            &lds[buf][s][wave * 512 + e * 4096]);
    }
  };

  stage(0, 2, 0); stage(0, 3, 0); stage(0, 0, 0); stage(0, 1, 0);
  stage(1, 2, 1); stage(1, 3, 1);
  asm volatile("s_waitcnt vmcnt(4)" ::: "memory");
  __builtin_amdgcn_s_barrier();

#define PHASE(q)                                                                     \
  {                                                                                  \
    __builtin_amdgcn_sched_barrier(0);                                               \
    if ((q) == 0 && t + 1 < nt) stage(buf ^ 1, 0, t + 1);                            \
    if ((q) == 1 && t + 1 < nt) stage(buf ^ 1, 1, t + 1);                            \
    if ((q) == 2 && t + 2 < nt) stage(buf, 2, t + 2);                                \
    if ((q) == 3 && t + 2 < nt) stage(buf, 3, t + 2);                                \
    if ((q) == 0) {                                                                  \
      const unsigned short* Bh = &lds[buf][2 + (wc >> 1)][0];                        \
      _Pragma("unroll") for (int kk = 0; kk < 2; ++kk)                               \
          _Pragma("unroll") for (int j = 0; j < 4; ++j) {                            \
        int br = (wc & 1) * 64 + j * 16 + l15;                                       \
        bfr[kk][j] = *(const bf16x8*)&Bh[br * 64 + (((kk * 4 + g) ^ (br & 7)) * 8)]; \
      }                                                                              \
    }                                                                                \
    {                                                                                \
      const unsigned short* Ah = &lds[buf][wr][0];                                   \
      _Pragma("unroll") for (int kk = 0; kk < 2; ++kk)                               \
          _Pragma("unroll") for (int ri = 0; ri < 2; ++ri) {                         \
        int ar = (q) * 32 + ri * 16 + l15;                                           \
        afr[kk][ri] = *(const bf16x8*)&Ah[ar * 64 + (((kk * 4 + g) ^ (ar & 7)) * 8)];\
      }                                                                              \
    }                                                                                \
    __builtin_amdgcn_s_setprio(1);                                                   \
    _Pragma("unroll") for (int kk = 0; kk < 2; ++kk)                                 \
        _Pragma("unroll") for (int ri = 0; ri < 2; ++ri)                             \
            _Pragma("unroll") for (int j = 0; j < 4; ++j)                            \
      acc[(q) * 2 + ri][j] = __builtin_amdgcn_mfma_f32_16x16x32_bf16(                \
          afr[kk][ri], bfr[kk][j], acc[(q) * 2 + ri][j], 0, 0, 0);                   \
    __builtin_amdgcn_s_setprio(0);                                                   \
    if ((q) == 3) {                                                                  \
      if (t + 2 < nt) asm volatile("s_waitcnt vmcnt(4)" ::: "memory");               \
      else asm volatile("s_waitcnt vmcnt(0)" ::: "memory");                          \
    }                                                                                \
    __builtin_amdgcn_s_barrier();                                                    \
  }

  for (int t = 0; t < nt; ++t) {
    int buf = t & 1;
    PHASE(0)
    PHASE(1)
    PHASE(2)
    PHASE(3)
  }
#undef PHASE

  int row0 = tm * 256 + wr * 128 + g * 4;
  int col0 = tn * 256 + wc * 64 + l15;
#pragma unroll
  for (int i = 0; i < 8; ++i) {
#pragma unroll
    for (int j = 0; j < 4; ++j) {
      int col = col0 + j * 16;
      float bb = (BIAS2 && col >= b2off) ? bias2[col - b2off] : bias[col];
#pragma unroll
      for (int r = 0; r < 4; ++r) {
        int row = row0 + i * 16 + r;
        float v = acc[i][j][r] + bb;
        if (RELU) v = fmaxf(v, 0.0f);
        outB[(size_t)row * N + col] = f2b(v);
      }
    }
  }
}

// ---------- GEMM 256x128 8-wave, BK=64, counted-vmcnt (for N%128 shapes) ----------
// MODE: 1 = bf16 out + row bias; 2 = fp32 out = resid + v + col bias; 3 = fp32 out += v.
template <int MODE>
__global__ __launch_bounds__(512, 1) void gemm256x128(const unsigned short* __restrict__ A,
                                                      const unsigned short* __restrict__ W,
                                                      const float* __restrict__ bias,
                                                      const float* __restrict__ resid,
                                                      float* __restrict__ outF,
                                                      unsigned short* __restrict__ outB,
                                                      int M, int N, int K, int sA, int sW) {
  __shared__ unsigned short lds[2][3][128 * 64];  // 96 KB
  int nbn = N >> 7;
  int nwg = gridDim.x;
  int bid = blockIdx.x;
  int wg = (bid & 7) * (nwg >> 3) + (bid >> 3);  // XCD swizzle (nwg % 8 == 0)
  int tm = wg / nbn, tn = wg % nbn;
  int tid = threadIdx.x;
  int wave = tid >> 6, lane = tid & 63;
  int wr = wave >> 2, wc = wave & 3;  // per-wave C = 128 rows x 32 cols
  int l15 = lane & 15, g = lane >> 4;
  int nt = K >> 6;

  const unsigned short* Abase = A + (size_t)(tm * 256) * sA;
  const unsigned short* Wbase = W + (size_t)(tn * 128) * sW;
  int srow = tid >> 3;
  int schunk = (tid & 7) ^ (srow & 7);

  f32x4 acc[8][2] = {};
  bf16x8 afr[2][2], bfr[2][2];

  auto stage = [&](int buf, int s, int kt) {
    const unsigned short* base = (s < 2) ? Abase : Wbase;
    int str = (s < 2) ? sA : sW;
    int rbase = (s & 1) * 128;  // s=2 -> 0
#pragma unroll
    for (int e = 0; e < 2; ++e) {
      gld16(base + (size_t)(rbase + srow + e * 64) * str + kt * 64 + schunk * 8,
            &lds[buf][s][wave * 512 + e * 4096]);
    }
  };

  stage(0, 2, 0); stage(0, 0, 0); stage(0, 1, 0);
  stage(1, 2, 1);
  asm volatile("s_waitcnt vmcnt(2)" ::: "memory");
  __builtin_amdgcn_s_barrier();

#define PHASE(q)                                                                     \
  {                                                                                  \
    __builtin_amdgcn_sched_barrier(0);                                               \
    if ((q) == 0 && t + 1 < nt) stage(buf ^ 1, 0, t + 1);                            \
    if ((q) == 1 && t + 1 < nt) stage(buf ^ 1, 1, t + 1);                            \
    if ((q) == 2 && t + 2 < nt) stage(buf, 2, t + 2);                                \
    if ((q) == 0) {                                                                  \
      const unsigned short* Bh = &lds[buf][2][0];                                    \
      _Pragma("unroll") for (int kk = 0; kk < 2; ++kk)                               \
          _Pragma("unroll") for (int j = 0; j < 2; ++j) {                            \
        int br = wc * 32 + j * 16 + l15;                                             \
        bfr[kk][j] = *(const bf16x8*)&Bh[br * 64 + (((kk * 4 + g) ^ (br & 7)) * 8)]; \
      }                                                                              \
    }                                                                                \
    {                                                                                \
      const unsigned short* Ah = &lds[buf][wr][0];                                   \
      _Pragma("unroll") for (int kk = 0; kk < 2; ++kk)                               \
          _Pragma("unroll") for (int ri = 0; ri < 2; ++ri) {                         \
        int ar = (q) * 32 + ri * 16 + l15;                                           \
        afr[kk][ri] = *(const bf16x8*)&Ah[ar * 64 + (((kk * 4 + g) ^ (ar & 7)) * 8)];\
      }                                                                              \
    }                                                                                \
    __builtin_amdgcn_s_setprio(1);                                                   \
    _Pragma("unroll") for (int kk = 0; kk < 2; ++kk)                                 \
        _Pragma("unroll") for (int ri = 0; ri < 2; ++ri)                             \
            _Pragma("unroll") for (int j = 0; j < 2; ++j)                            \
      acc[(q) * 2 + ri][j] = __builtin_amdgcn_mfma_f32_16x16x32_bf16(                \
          afr[kk][ri], bfr[kk][j], acc[(q) * 2 + ri][j], 0, 0, 0);                   \
    __builtin_amdgcn_s_setprio(0);                                                   \
    if ((q) == 3) {                                                                  \
      if (t + 2 < nt) asm volatile("s_waitcnt vmcnt(2)" ::: "memory");               \
      else asm volatile("s_waitcnt vmcnt(0)" ::: "memory");                          \
    }                                                                                \
    __builtin_amdgcn_s_barrier();                                                    \
  }

  for (int t = 0; t < nt; ++t) {
    int buf = t & 1;
    PHASE(0)
    PHASE(1)
    PHASE(2)
    PHASE(3)
  }
#undef PHASE

  int row0 = tm * 256 + wr * 128 + g * 4;
  int col0 = tn * 128 + wc * 32 + l15;
#pragma unroll
  for (int i = 0; i < 8; ++i) {
#pragma unroll
    for (int j = 0; j < 2; ++j) {
      int col = col0 + j * 16;
      float cb = (MODE == 2) ? bias[col] : 0.0f;
#pragma unroll
      for (int r = 0; r < 4; ++r) {
        int row = row0 + i * 16 + r;
        size_t idx = (size_t)row * N + col;
        float v = acc[i][j][r];
        if (MODE == 1) outB[idx] = f2b(v + bias[row]);
        else if (MODE == 2) outF[idx] = resid[idx] + v + cb;
        else outF[idx] += v;
      }
    }
  }
}

// ---------- flash attention v6: 2 q-tiles per block (shared K/V), no-max softmax ----------
// QK [tok][2048] bf16 (Q cols 0-1023, K cols 1024-2047), Vt [h*64+d][tok] bf16.
// 1 block = (b,h,128-row q-tile); 4 waves; each wave owns q rows {q0+w*16+l15}
// (set A) and {q0+64+w*16+l15} (set B). K/V LDS reads shared by both sets ->
// staging, addressing, and K/V HBM traffic amortized 2x. Fixed m=0 softmax.
__global__ __launch_bounds__(256) void attn_fwd6(const unsigned short* __restrict__ QK,
                                                 const unsigned short* __restrict__ Vt,
                                                 const int* __restrict__ mask,
                                                 unsigned short* __restrict__ O) {
  __shared__ unsigned short Kl[2][64 * 64];
  __shared__ unsigned short Vl[2][64 * 64];
  __shared__ float biasl[1024];
  int bid = blockIdx.x;
  int wg = (bid & 7) * 128 + (bid >> 3);  // XCD swizzle (nwg = 1024)
  int qt = wg & 7, bh = wg >> 3;
  int b = bh >> 4, h = bh & 15;
  int tid = threadIdx.x, wave = tid >> 6, lane = tid & 63;
  int l15 = lane & 15, g = lane >> 4;
  int q0 = qt * 128;

  for (int i = tid; i < 1024; i += 256)
    biasl[i] = (mask[b * 1024 + i] == 0) ? -1.4426950e9f : 0.0f;

  const unsigned short* QrowA = QK + ((size_t)(b * 1024 + q0 + wave * 16 + l15)) * 2048 + h * 64;
  const unsigned short* QrowB = QrowA + (size_t)64 * 2048;
  bf16x8 qa0 = *(const bf16x8*)(QrowA + g * 8);
  bf16x8 qa1 = *(const bf16x8*)(QrowA + 32 + g * 8);
  bf16x8 qb0 = *(const bf16x8*)(QrowB + g * 8);
  bf16x8 qb1 = *(const bf16x8*)(QrowB + 32 + g * 8);

  float l_a = 0.0f, l_b = 0.0f;   // lane-partial softmax denominators
  f32x4 oa[4] = {}, ob[4] = {};   // o[dt][r] = O[q][d = dt*16 + g*4 + r]

  int srow = lane >> 3;
  int clog = (lane & 7) ^ srow;
  int h7 = l15 & 7;
  const float SC = 0.125f * 1.44269504f;  // 1/sqrt(64) * log2(e)

  auto stageKV = [&](int buf, int kt) {
#pragma unroll
    for (int i = 0; i < 2; ++i) {
      int rk = wave * 16 + i * 8 + srow;
      gld16(QK + ((size_t)(b * 1024 + kt * 64 + rk)) * 2048 + 1024 + h * 64 + clog * 8,
            &Kl[buf][(wave * 16 + i * 8) * 64]);
      gld16(Vt + ((size_t)(h * 64 + rk)) * 8192 + b * 1024 + kt * 64 + clog * 8,
            &Vl[buf][(wave * 16 + i * 8) * 64]);
    }
  };

  stageKV(0, 0);
  __syncthreads();
  int cur = 0;

  for (int kt = 0; kt < 16; ++kt) {
    if (kt < 15) stageKV(cur ^ 1, kt + 1);

    // S^T = mfma(A=K, B=Q): one K-frag pair feeds both q-sets
    f32x4 sa[4], sb[4];
    __builtin_amdgcn_s_setprio(1);
#pragma unroll
    for (int j = 0; j < 4; ++j) {
      int kr = j * 16 + l15;
      bf16x8 ka = *(const bf16x8*)&Kl[cur][kr * 64 + ((g ^ h7) * 8)];
      bf16x8 kb = *(const bf16x8*)&Kl[cur][kr * 64 + (((4 + g) ^ h7) * 8)];
      f32x4 z = {};
      sa[j] = __builtin_amdgcn_mfma_f32_16x16x32_bf16(ka, qa0, z, 0, 0, 0);
      sa[j] = __builtin_amdgcn_mfma_f32_16x16x32_bf16(kb, qa1, sa[j], 0, 0, 0);
      sb[j] = __builtin_amdgcn_mfma_f32_16x16x32_bf16(ka, qb0, z, 0, 0, 0);
      sb[j] = __builtin_amdgcn_mfma_f32_16x16x32_bf16(kb, qb1, sb[j], 0, 0, 0);
    }
    __builtin_amdgcn_s_setprio(0);

    // P = exp2(score*SC + maskbias), lane-partial l; pack both sets
    union U8 { uint32_t u[4]; bf16x8 v; } pa[2], pb[2];
#pragma unroll
    for (int j = 0; j < 4; ++j) {
      float4 b4 = *(const float4*)&biasl[kt * 64 + j * 16 + g * 4];
      float ea0 = exp2_fast(sa[j][0] * SC + b4.x);
      float ea1 = exp2_fast(sa[j][1] * SC + b4.y);
      float ea2 = exp2_fast(sa[j][2] * SC + b4.z);
      float ea3 = exp2_fast(sa[j][3] * SC + b4.w);
      l_a += (ea0 + ea1) + (ea2 + ea3);
      pa[j >> 1].u[(j & 1) * 2 + 0] = cvtpk(ea0, ea1);
      pa[j >> 1].u[(j & 1) * 2 + 1] = cvtpk(ea2, ea3);
      float eb0 = exp2_fast(sb[j][0] * SC + b4.x);
      float eb1 = exp2_fast(sb[j][1] * SC + b4.y);
      float eb2 = exp2_fast(sb[j][2] * SC + b4.z);
      float eb3 = exp2_fast(sb[j][3] * SC + b4.w);
      l_b += (eb0 + eb1) + (eb2 + eb3);
      pb[j >> 1].u[(j & 1) * 2 + 0] = cvtpk(eb0, eb1);
      pb[j >> 1].u[(j & 1) * 2 + 1] = cvtpk(eb2, eb3);
    }

    // PV: one V-frag feeds both q-sets
#pragma unroll
    for (int kk = 0; kk < 2; ++kk) {
#pragma unroll
      for (int dt = 0; dt < 4; ++dt) {
        int vr = dt * 16 + l15;
        uint2 lo = *(const uint2*)&Vl[cur][vr * 64 + (((4 * kk + (g >> 1)) ^ h7) * 8) + (g & 1) * 4];
        uint2 hi = *(const uint2*)&Vl[cur][vr * 64 + (((4 * kk + 2 + (g >> 1)) ^ h7) * 8) + (g & 1) * 4];
        union U8 vbu;
        vbu.u[0] = lo.x; vbu.u[1] = lo.y; vbu.u[2] = hi.x; vbu.u[3] = hi.y;
        __builtin_amdgcn_s_setprio(1);
        oa[dt] = __builtin_amdgcn_mfma_f32_16x16x32_bf16(vbu.v, pa[kk].v, oa[dt], 0, 0, 0);
        ob[dt] = __builtin_amdgcn_mfma_f32_16x16x32_bf16(vbu.v, pb[kk].v, ob[dt], 0, 0, 0);
        __builtin_amdgcn_s_setprio(0);
      }
    }

    __syncthreads();
    cur ^= 1;
  }

  // final l reduce across the 4 lane-copies of each q, then lane-local epilogue
  l_a += __shfl_xor(l_a, 16);
  l_a += __shfl_xor(l_a, 32);
  l_b += __shfl_xor(l_b, 16);
  l_b += __shfl_xor(l_b, 32);
  float inva = 1.0f / l_a, invb = 1.0f / l_b;
  size_t orowA = ((size_t)(b * 1024 + q0 + wave * 16 + l15)) * 1024 + h * 64;
  size_t orowB = orowA + (size_t)64 * 1024;
#pragma unroll
  for (int dt = 0; dt < 4; ++dt) {
    uint2 wa, wb;
    wa.x = cvtpk(oa[dt][0] * inva, oa[dt][1] * inva);
    wa.y = cvtpk(oa[dt][2] * inva, oa[dt][3] * inva);
    *(uint2*)&O[orowA + dt * 16 + g * 4] = wa;
    wb.x = cvtpk(ob[dt][0] * invb, ob[dt][1] * invb);
    wb.y = cvtpk(ob[dt][2] * invb, ob[dt][3] * invb);
    *(uint2*)&O[orowB + dt * 16 + g * 4] = wb;
  }
}

// ---------- launch ----------
extern "C" void kernel_launch(void* const* d_in, const int* in_sizes, int n_in,
                              void* d_out, int out_size, void* d_ws, size_t ws_size,
                              hipStream_t stream) {
  const float* X = (const float*)d_in[0];
  const int* mask = (const int*)d_in[1];
  const float* wq = (const float*)d_in[2];
  const float* bq = (const float*)d_in[3];
  const float* wk = (const float*)d_in[4];
  const float* bk = (const float*)d_in[5];
  const float* wv = (const float*)d_in[6];
  const float* bv = (const float*)d_in[7];
  const float* wo = (const float*)d_in[8];
  const float* bo = (const float*)d_in[9];
  const float* w1 = (const float*)d_in[10];
  const float* b1 = (const float*)d_in[11];
  const float* w2 = (const float*)d_in[12];
  const float* b2 = (const float*)d_in[13];
  const float* ln1a = (const float*)d_in[14];
  const float* ln1b = (const float*)d_in[15];
  const float* ln2a = (const float*)d_in[16];
  const float* ln2b = (const float*)d_in[17];
  float* out = (float*)d_out;
  char* ws = (char*)d_ws;
  const size_t MB = 1024 * 1024;

  // layout (88MB): [0,8) w1_b | [8,16) w2_b | [16,20) wqk_b | [20,22) wv_b |
  // [22,24) wo_b | [24,40) xn (LN1 out -> attn O -> LN2 out) | [40,72) QKb -> hb |
  // [72,88) Vtb
  unsigned short* w1_b = (unsigned short*)(ws + 0 * MB);
  unsigned short* w2_b = (unsigned short*)(ws + 8 * MB);
  unsigned short* wqk_b = (unsigned short*)(ws + 16 * MB);
  unsigned short* wv_b = (unsigned short*)(ws + 20 * MB);
  unsigned short* wo_b = (unsigned short*)(ws + 22 * MB);
  unsigned short* xn = (unsigned short*)(ws + 24 * MB);
  unsigned short* QKb = (unsigned short*)(ws + 40 * MB);
  unsigned short* Vtb = (unsigned short*)(ws + 72 * MB);
  unsigned short* hb = QKb;

  // all weights -> bf16 in one launch (wq,wk stacked into wqk_b)
  cast_all<<<12288, 256, 0, stream>>>(w1, w2, wq, wk, wv, wo, w1_b, w2_b, wqk_b, wv_b, wo_b);

  // LN1
  ln_bf16<<<8192, 256, 0, stream>>>(X, xn, ln1a, ln1b);
  // fused Q+K projection: QK[token][2048]  (256^2 tile, grid 256 = 1/CU)
  gemm256<0, 1><<<256, 512, 0, stream>>>(xn, wqk_b, bq, bk, 1024, QKb,
                                         8192, 2048, 1024, 1024, 1024);
  // V transposed: Vt[hd][token] = wv @ xn^T + bv (row bias)  (256x128, grid 256)
  gemm256x128<1><<<256, 512, 0, stream>>>(wv_b, xn, bv, nullptr, nullptr, Vtb,
                                          1024, 8192, 1024, 1024, 1024);
  // attention (writes O into xn buffer); 1024 blocks = 4/CU
  attn_fwd6<<<1024, 256, 0, stream>>>(QKb, Vtb, mask, xn);
  // out = X + O @ wo^T + bo  (256x128, grid 256)
  gemm256x128<2><<<256, 512, 0, stream>>>(xn, wo_b, bo, X, out, nullptr,
                                          8192, 1024, 1024, 1024, 1024);
  // LN2 (reads out, writes into xn region)
  ln_bf16<<<8192, 256, 0, stream>>>(out, xn, ln2a, ln2b);
  // FFN chunked along hidden dim: h half = [8192][2048] in hb (QKb region)
  for (int hc = 0; hc < 2; ++hc) {
    // h = relu(xn @ w1[hc*2048:(hc+1)*2048]^T + b1[hc*2048:])  (256^2)
    gemm256<1, 0><<<256, 512, 0, stream>>>(xn, w1_b + (size_t)hc * 2048 * 1024,
                                           b1 + hc * 2048, nullptr, 0, hb,
                                           8192, 2048, 1024, 1024, 1024);
    if (hc == 0)  // out = out + b2 + h_half @ w2[:, 0:2048]^T  (256x128)
      gemm256x128<2><<<256, 512, 0, stream>>>(hb, w2_b, b2, out, out, nullptr,
                                              8192, 1024, 2048, 2048, 4096);
    else          // out += h_half @ w2[:, 2048:4096]^T  (256x128)
      gemm256x128<3><<<256, 512, 0, stream>>>(hb, w2_b + 2048, nullptr, nullptr, out, nullptr,
                                              8192, 1024, 2048, 2048, 4096);
  }
}

// Round 10
// 359.674 us; speedup vs baseline: 1.6210x; 1.0144x over previous
//
#include <hip/hip_runtime.h>
#include <cstdint>
#include <cstddef>

// ---------- types ----------
typedef float f32x4 __attribute__((ext_vector_type(4)));
typedef short bf16x8 __attribute__((ext_vector_type(8)));

typedef __attribute__((address_space(1))) void void_g;
typedef __attribute__((address_space(3))) void void_l;

__device__ __forceinline__ void gld16(const void* g, void* l) {
  // async global->LDS, 16B per lane; LDS dest = wave-uniform base + lane*16
  __builtin_amdgcn_global_load_lds((void_g*)g, (void_l*)l, 16, 0, 0);
}

__device__ __forceinline__ unsigned short f2b(float f) {
  union { float f; uint32_t u; } c; c.f = f;
  uint32_t u = c.u;
  return (unsigned short)((u + 0x7fffu + ((u >> 16) & 1u)) >> 16);  // RNE
}

__device__ __forceinline__ uint32_t cvtpk(float lo, float hi) {
  uint32_t r;
  asm("v_cvt_pk_bf16_f32 %0, %1, %2" : "=v"(r) : "v"(lo), "v"(hi));
  return r;  // low16 = bf16(lo), high16 = bf16(hi)
}

__device__ __forceinline__ float exp2_fast(float x) {
  return __builtin_exp2f(x);  // lowers to v_exp_f32 (2^x) on gfx950
}

// ---------- all weight casts fp32 -> bf16 in one launch ----------
__global__ __launch_bounds__(256) void cast_all(const float* __restrict__ w1,
                                                const float* __restrict__ w2,
                                                const float* __restrict__ wq,
                                                const float* __restrict__ wk,
                                                const float* __restrict__ wv,
                                                const float* __restrict__ wo,
                                                unsigned short* __restrict__ d1,
                                                unsigned short* __restrict__ d2,
                                                unsigned short* __restrict__ dqk,
                                                unsigned short* __restrict__ dv,
                                                unsigned short* __restrict__ dod) {
  int blk = blockIdx.x;
  const float* s;
  unsigned short* d;
  int off;
  if (blk < 4096) { s = w1; d = d1; off = blk; }
  else if (blk < 8192) { s = w2; d = d2; off = blk - 4096; }
  else if (blk < 9216) { s = wq; d = dqk; off = blk - 8192; }
  else if (blk < 10240) { s = wk; d = dqk + (1 << 20); off = blk - 9216; }
  else if (blk < 11264) { s = wv; d = dv; off = blk - 10240; }
  else { s = wo; d = dod; off = blk - 11264; }
  int i = off * 256 + threadIdx.x;
  float4 v = ((const float4*)s)[i];
  ushort4 o;
  o.x = f2b(v.x); o.y = f2b(v.y); o.z = f2b(v.z); o.w = f2b(v.w);
  ((ushort4*)d)[i] = o;
}

// ---------- LayerNorm (unbiased std, scalar alpha/beta) -> bf16 ----------
__global__ __launch_bounds__(256) void ln_bf16(const float* __restrict__ X,
                                               unsigned short* __restrict__ out,
                                               const float* __restrict__ alpha,
                                               const float* __restrict__ beta) {
  int row = blockIdx.x;
  int tid = threadIdx.x;
  float4 v = ((const float4*)(X + (size_t)row * 1024))[tid];
  float s = v.x + v.y + v.z + v.w;
  float q = v.x * v.x + v.y * v.y + v.z * v.z + v.w * v.w;
#pragma unroll
  for (int m = 1; m < 64; m <<= 1) { s += __shfl_xor(s, m); q += __shfl_xor(q, m); }
  __shared__ float red[8];
  int wave = tid >> 6;
  if ((tid & 63) == 0) { red[wave] = s; red[4 + wave] = q; }
  __syncthreads();
  s = red[0] + red[1] + red[2] + red[3];
  q = red[4] + red[5] + red[6] + red[7];
  float mean = s * (1.0f / 1024.0f);
  float var = fmaxf((q - 1024.0f * mean * mean) * (1.0f / 1023.0f), 0.0f);
  float inv = alpha[0] / (sqrtf(var) + 1e-6f);
  float b = beta[0];
  ushort4 o;
  o.x = f2b((v.x - mean) * inv + b);
  o.y = f2b((v.y - mean) * inv + b);
  o.z = f2b((v.z - mean) * inv + b);
  o.w = f2b((v.w - mean) * inv + b);
  ((ushort4*)(out + (size_t)row * 1024))[tid] = o;
}

// ---------- GEMM 256x256 8-wave, BK=64, counted-vmcnt + frag-prefetch pipeline ----------
// A-frags for phase q+1 are ds_read during phase q's MFMA (double afr set);
// phase 3 has zero ds_reads so MFMA covers the vmcnt drain.
template <int RELU, int BIAS2>
__global__ __launch_bounds__(512, 1) void gemm256(const unsigned short* __restrict__ A,
                                                  const unsigned short* __restrict__ W,
                                                  const float* __restrict__ bias,
                                                  const float* __restrict__ bias2, int b2off,
                                                  unsigned short* __restrict__ outB,
                                                  int M, int N, int K, int sA, int sW) {
  __shared__ unsigned short lds[2][4][128 * 64];  // 128 KB
  int nbn = N >> 8;
  int nwg = gridDim.x;
  int bid = blockIdx.x;
  int wg = (bid & 7) * (nwg >> 3) + (bid >> 3);  // XCD swizzle (nwg % 8 == 0)
  int tm = wg / nbn, tn = wg % nbn;
  int tid = threadIdx.x;
  int wave = tid >> 6, lane = tid & 63;
  int wr = wave >> 2, wc = wave & 3;  // 2 x 4 wave grid; per-wave C = 128 x 64
  int l15 = lane & 15, g = lane >> 4;
  int nt = K >> 6;

  const unsigned short* Abase = A + (size_t)(tm * 256) * sA;
  const unsigned short* Wbase = W + (size_t)(tn * 256) * sW;
  int srow = tid >> 3;
  int schunk = (tid & 7) ^ (srow & 7);

  f32x4 acc[8][4] = {};
  bf16x8 afrA[2][2], afrB[2][2], bfr[2][4];

  auto stage = [&](int buf, int s, int kt) {
    const unsigned short* base = (s < 2) ? Abase : Wbase;
    int str = (s < 2) ? sA : sW;
    int rbase = (s & 1) * 128;
#pragma unroll
    for (int e = 0; e < 2; ++e) {
      gld16(base + (size_t)(rbase + srow + e * 64) * str + kt * 64 + schunk * 8,
            &lds[buf][s][wave * 512 + e * 4096]);
    }
  };
  auto readB = [&](int buf) {
    const unsigned short* Bh = &lds[buf][2 + (wc >> 1)][0];
#pragma unroll
    for (int kk = 0; kk < 2; ++kk)
#pragma unroll
      for (int j = 0; j < 4; ++j) {
        int br = (wc & 1) * 64 + j * 16 + l15;
        bfr[kk][j] = *(const bf16x8*)&Bh[br * 64 + (((kk * 4 + g) ^ (br & 7)) * 8)];
      }
  };
  auto readA = [&](bf16x8 (&dst)[2][2], int buf, int q) {
    const unsigned short* Ah = &lds[buf][wr][0];
#pragma unroll
    for (int kk = 0; kk < 2; ++kk)
#pragma unroll
      for (int ri = 0; ri < 2; ++ri) {
        int ar = q * 32 + ri * 16 + l15;
        dst[kk][ri] = *(const bf16x8*)&Ah[ar * 64 + (((kk * 4 + g) ^ (ar & 7)) * 8)];
      }
  };
  auto mfma16 = [&](bf16x8 (&af)[2][2], int q) {
    __builtin_amdgcn_s_setprio(1);
#pragma unroll
    for (int kk = 0; kk < 2; ++kk)
#pragma unroll
      for (int ri = 0; ri < 2; ++ri)
#pragma unroll
        for (int j = 0; j < 4; ++j)
          acc[q * 2 + ri][j] = __builtin_amdgcn_mfma_f32_16x16x32_bf16(
              af[kk][ri], bfr[kk][j], acc[q * 2 + ri][j], 0, 0, 0);
    __builtin_amdgcn_s_setprio(0);
  };

  stage(0, 2, 0); stage(0, 3, 0); stage(0, 0, 0); stage(0, 1, 0);
  stage(1, 2, 1); stage(1, 3, 1);
  asm volatile("s_waitcnt vmcnt(4)" ::: "memory");
  __builtin_amdgcn_s_barrier();

  for (int t = 0; t < nt; ++t) {
    int buf = t & 1;
    // phase 0: B frags + afrA(q0) + prefetch afrB(q1)
    __builtin_amdgcn_sched_barrier(0);
    if (t + 1 < nt) stage(buf ^ 1, 0, t + 1);
    readB(buf);
    readA(afrA, buf, 0);
    readA(afrB, buf, 1);
    mfma16(afrA, 0);
    __builtin_amdgcn_s_barrier();
    // phase 1: prefetch afrA(q2)
    __builtin_amdgcn_sched_barrier(0);
    if (t + 1 < nt) stage(buf ^ 1, 1, t + 1);
    readA(afrA, buf, 2);
    mfma16(afrB, 1);
    __builtin_amdgcn_s_barrier();
    // phase 2: prefetch afrB(q3)
    __builtin_amdgcn_sched_barrier(0);
    if (t + 2 < nt) stage(buf, 2, t + 2);
    readA(afrB, buf, 3);
    mfma16(afrA, 2);
    __builtin_amdgcn_s_barrier();
    // phase 3: no ds_reads; MFMA covers vmcnt drain
    __builtin_amdgcn_sched_barrier(0);
    if (t + 2 < nt) stage(buf, 3, t + 2);
    mfma16(afrB, 3);
    if (t + 2 < nt) asm volatile("s_waitcnt vmcnt(4)" ::: "memory");
    else asm volatile("s_waitcnt vmcnt(0)" ::: "memory");
    __builtin_amdgcn_s_barrier();
  }

  int row0 = tm * 256 + wr * 128 + g * 4;
  int col0 = tn * 256 + wc * 64 + l15;
#pragma unroll
  for (int i = 0; i < 8; ++i) {
#pragma unroll
    for (int j = 0; j < 4; ++j) {
      int col = col0 + j * 16;
      float bb = (BIAS2 && col >= b2off) ? bias2[col - b2off] : bias[col];
#pragma unroll
      for (int r = 0; r < 4; ++r) {
        int row = row0 + i * 16 + r;
        float v = acc[i][j][r] + bb;
        if (RELU) v = fmaxf(v, 0.0f);
        outB[(size_t)row * N + col] = f2b(v);
      }
    }
  }
}

// ---------- GEMM 256x128 8-wave, BK=64, counted-vmcnt + frag-prefetch ----------
// MODE: 1 = bf16 out + row bias; 2 = fp32 out = resid + v + col bias; 3 = fp32 out += v.
template <int MODE>
__global__ __launch_bounds__(512, 1) void gemm256x128(const unsigned short* __restrict__ A,
                                                      const unsigned short* __restrict__ W,
                                                      const float* __restrict__ bias,
                                                      const float* __restrict__ resid,
                                                      float* __restrict__ outF,
                                                      unsigned short* __restrict__ outB,
                                                      int M, int N, int K, int sA, int sW) {
  __shared__ unsigned short lds[2][3][128 * 64];  // 96 KB
  int nbn = N >> 7;
  int nwg = gridDim.x;
  int bid = blockIdx.x;
  int wg = (bid & 7) * (nwg >> 3) + (bid >> 3);  // XCD swizzle (nwg % 8 == 0)
  int tm = wg / nbn, tn = wg % nbn;
  int tid = threadIdx.x;
  int wave = tid >> 6, lane = tid & 63;
  int wr = wave >> 2, wc = wave & 3;  // per-wave C = 128 rows x 32 cols
  int l15 = lane & 15, g = lane >> 4;
  int nt = K >> 6;

  const unsigned short* Abase = A + (size_t)(tm * 256) * sA;
  const unsigned short* Wbase = W + (size_t)(tn * 128) * sW;
  int srow = tid >> 3;
  int schunk = (tid & 7) ^ (srow & 7);

  f32x4 acc[8][2] = {};
  bf16x8 afrA[2][2], afrB[2][2], bfr[2][2];

  auto stage = [&](int buf, int s, int kt) {
    const unsigned short* base = (s < 2) ? Abase : Wbase;
    int str = (s < 2) ? sA : sW;
    int rbase = (s & 1) * 128;  // s=2 -> 0
#pragma unroll
    for (int e = 0; e < 2; ++e) {
      gld16(base + (size_t)(rbase + srow + e * 64) * str + kt * 64 + schunk * 8,
            &lds[buf][s][wave * 512 + e * 4096]);
    }
  };
  auto readB = [&](int buf) {
    const unsigned short* Bh = &lds[buf][2][0];
#pragma unroll
    for (int kk = 0; kk < 2; ++kk)
#pragma unroll
      for (int j = 0; j < 2; ++j) {
        int br = wc * 32 + j * 16 + l15;
        bfr[kk][j] = *(const bf16x8*)&Bh[br * 64 + (((kk * 4 + g) ^ (br & 7)) * 8)];
      }
  };
  auto readA = [&](bf16x8 (&dst)[2][2], int buf, int q) {
    const unsigned short* Ah = &lds[buf][wr][0];
#pragma unroll
    for (int kk = 0; kk < 2; ++kk)
#pragma unroll
      for (int ri = 0; ri < 2; ++ri) {
        int ar = q * 32 + ri * 16 + l15;
        dst[kk][ri] = *(const bf16x8*)&Ah[ar * 64 + (((kk * 4 + g) ^ (ar & 7)) * 8)];
      }
  };
  auto mfma8 = [&](bf16x8 (&af)[2][2], int q) {
    __builtin_amdgcn_s_setprio(1);
#pragma unroll
    for (int kk = 0; kk < 2; ++kk)
#pragma unroll
      for (int ri = 0; ri < 2; ++ri)
#pragma unroll
        for (int j = 0; j < 2; ++j)
          acc[q * 2 + ri][j] = __builtin_amdgcn_mfma_f32_16x16x32_bf16(
              af[kk][ri], bfr[kk][j], acc[q * 2 + ri][j], 0, 0, 0);
    __builtin_amdgcn_s_setprio(0);
  };

  stage(0, 2, 0); stage(0, 0, 0); stage(0, 1, 0);
  stage(1, 2, 1);
  asm volatile("s_waitcnt vmcnt(2)" ::: "memory");
  __builtin_amdgcn_s_barrier();

  for (int t = 0; t < nt; ++t) {
    int buf = t & 1;
    // phase 0
    __builtin_amdgcn_sched_barrier(0);
    if (t + 1 < nt) stage(buf ^ 1, 0, t + 1);
    readB(buf);
    readA(afrA, buf, 0);
    readA(afrB, buf, 1);
    mfma8(afrA, 0);
    __builtin_amdgcn_s_barrier();
    // phase 1
    __builtin_amdgcn_sched_barrier(0);
    if (t + 1 < nt) stage(buf ^ 1, 1, t + 1);
    readA(afrA, buf, 2);
    mfma8(afrB, 1);
    __builtin_amdgcn_s_barrier();
    // phase 2
    __builtin_amdgcn_sched_barrier(0);
    if (t + 2 < nt) stage(buf, 2, t + 2);
    readA(afrB, buf, 3);
    mfma8(afrA, 2);
    __builtin_amdgcn_s_barrier();
    // phase 3: no ds_reads
    __builtin_amdgcn_sched_barrier(0);
    mfma8(afrB, 3);
    if (t + 2 < nt) asm volatile("s_waitcnt vmcnt(2)" ::: "memory");
    else asm volatile("s_waitcnt vmcnt(0)" ::: "memory");
    __builtin_amdgcn_s_barrier();
  }

  int row0 = tm * 256 + wr * 128 + g * 4;
  int col0 = tn * 128 + wc * 32 + l15;
#pragma unroll
  for (int i = 0; i < 8; ++i) {
#pragma unroll
    for (int j = 0; j < 2; ++j) {
      int col = col0 + j * 16;
      float cb = (MODE == 2) ? bias[col] : 0.0f;
#pragma unroll
      for (int r = 0; r < 4; ++r) {
        int row = row0 + i * 16 + r;
        size_t idx = (size_t)row * N + col;
        float v = acc[i][j][r];
        if (MODE == 1) outB[idx] = f2b(v + bias[row]);
        else if (MODE == 2) outF[idx] = resid[idx] + v + cb;
        else outF[idx] += v;
      }
    }
  }
}

// ---------- flash attention v6b: 2 q-tiles per block, no-max softmax, hoisted setprio ----------
__global__ __launch_bounds__(256) void attn_fwd6(const unsigned short* __restrict__ QK,
                                                 const unsigned short* __restrict__ Vt,
                                                 const int* __restrict__ mask,
                                                 unsigned short* __restrict__ O) {
  __shared__ unsigned short Kl[2][64 * 64];
  __shared__ unsigned short Vl[2][64 * 64];
  __shared__ float biasl[1024];
  int bid = blockIdx.x;
  int wg = (bid & 7) * 128 + (bid >> 3);  // XCD swizzle (nwg = 1024)
  int qt = wg & 7, bh = wg >> 3;
  int b = bh >> 4, h = bh & 15;
  int tid = threadIdx.x, wave = tid >> 6, lane = tid & 63;
  int l15 = lane & 15, g = lane >> 4;
  int q0 = qt * 128;

  for (int i = tid; i < 1024; i += 256)
    biasl[i] = (mask[b * 1024 + i] == 0) ? -1.4426950e9f : 0.0f;

  const unsigned short* QrowA = QK + ((size_t)(b * 1024 + q0 + wave * 16 + l15)) * 2048 + h * 64;
  const unsigned short* QrowB = QrowA + (size_t)64 * 2048;
  bf16x8 qa0 = *(const bf16x8*)(QrowA + g * 8);
  bf16x8 qa1 = *(const bf16x8*)(QrowA + 32 + g * 8);
  bf16x8 qb0 = *(const bf16x8*)(QrowB + g * 8);
  bf16x8 qb1 = *(const bf16x8*)(QrowB + 32 + g * 8);

  float l_a = 0.0f, l_b = 0.0f;   // lane-partial softmax denominators
  f32x4 oa[4] = {}, ob[4] = {};   // o[dt][r] = O[q][d = dt*16 + g*4 + r]

  int srow = lane >> 3;
  int clog = (lane & 7) ^ srow;
  int h7 = l15 & 7;
  const float SC = 0.125f * 1.44269504f;  // 1/sqrt(64) * log2(e)

  auto stageKV = [&](int buf, int kt) {
#pragma unroll
    for (int i = 0; i < 2; ++i) {
      int rk = wave * 16 + i * 8 + srow;
      gld16(QK + ((size_t)(b * 1024 + kt * 64 + rk)) * 2048 + 1024 + h * 64 + clog * 8,
            &Kl[buf][(wave * 16 + i * 8) * 64]);
      gld16(Vt + ((size_t)(h * 64 + rk)) * 8192 + b * 1024 + kt * 64 + clog * 8,
            &Vl[buf][(wave * 16 + i * 8) * 64]);
    }
  };

  stageKV(0, 0);
  __syncthreads();
  int cur = 0;

  for (int kt = 0; kt < 16; ++kt) {
    if (kt < 15) stageKV(cur ^ 1, kt + 1);

    // S^T = mfma(A=K, B=Q): one K-frag pair feeds both q-sets
    f32x4 sa[4], sb[4];
    __builtin_amdgcn_s_setprio(1);
#pragma unroll
    for (int j = 0; j < 4; ++j) {
      int kr = j * 16 + l15;
      bf16x8 ka = *(const bf16x8*)&Kl[cur][kr * 64 + ((g ^ h7) * 8)];
      bf16x8 kb = *(const bf16x8*)&Kl[cur][kr * 64 + (((4 + g) ^ h7) * 8)];
      f32x4 z = {};
      sa[j] = __builtin_amdgcn_mfma_f32_16x16x32_bf16(ka, qa0, z, 0, 0, 0);
      sa[j] = __builtin_amdgcn_mfma_f32_16x16x32_bf16(kb, qa1, sa[j], 0, 0, 0);
      sb[j] = __builtin_amdgcn_mfma_f32_16x16x32_bf16(ka, qb0, z, 0, 0, 0);
      sb[j] = __builtin_amdgcn_mfma_f32_16x16x32_bf16(kb, qb1, sb[j], 0, 0, 0);
    }
    __builtin_amdgcn_s_setprio(0);

    // P = exp2(score*SC + maskbias), lane-partial l; pack both sets
    union U8 { uint32_t u[4]; bf16x8 v; } pa[2], pb[2];
#pragma unroll
    for (int j = 0; j < 4; ++j) {
      float4 b4 = *(const float4*)&biasl[kt * 64 + j * 16 + g * 4];
      float ea0 = exp2_fast(sa[j][0] * SC + b4.x);
      float ea1 = exp2_fast(sa[j][1] * SC + b4.y);
      float ea2 = exp2_fast(sa[j][2] * SC + b4.z);
      float ea3 = exp2_fast(sa[j][3] * SC + b4.w);
      l_a += (ea0 + ea1) + (ea2 + ea3);
      pa[j >> 1].u[(j & 1) * 2 + 0] = cvtpk(ea0, ea1);
      pa[j >> 1].u[(j & 1) * 2 + 1] = cvtpk(ea2, ea3);
      float eb0 = exp2_fast(sb[j][0] * SC + b4.x);
      float eb1 = exp2_fast(sb[j][1] * SC + b4.y);
      float eb2 = exp2_fast(sb[j][2] * SC + b4.z);
      float eb3 = exp2_fast(sb[j][3] * SC + b4.w);
      l_b += (eb0 + eb1) + (eb2 + eb3);
      pb[j >> 1].u[(j & 1) * 2 + 0] = cvtpk(eb0, eb1);
      pb[j >> 1].u[(j & 1) * 2 + 1] = cvtpk(eb2, eb3);
    }

    // PV: one V-frag feeds both q-sets (single setprio region)
    __builtin_amdgcn_s_setprio(1);
#pragma unroll
    for (int kk = 0; kk < 2; ++kk) {
#pragma unroll
      for (int dt = 0; dt < 4; ++dt) {
        int vr = dt * 16 + l15;
        uint2 lo = *(const uint2*)&Vl[cur][vr * 64 + (((4 * kk + (g >> 1)) ^ h7) * 8) + (g & 1) * 4];
        uint2 hi = *(const uint2*)&Vl[cur][vr * 64 + (((4 * kk + 2 + (g >> 1)) ^ h7) * 8) + (g & 1) * 4];
        union U8 vbu;
        vbu.u[0] = lo.x; vbu.u[1] = lo.y; vbu.u[2] = hi.x; vbu.u[3] = hi.y;
        oa[dt] = __builtin_amdgcn_mfma_f32_16x16x32_bf16(vbu.v, pa[kk].v, oa[dt], 0, 0, 0);
        ob[dt] = __builtin_amdgcn_mfma_f32_16x16x32_bf16(vbu.v, pb[kk].v, ob[dt], 0, 0, 0);
      }
    }
    __builtin_amdgcn_s_setprio(0);

    __syncthreads();
    cur ^= 1;
  }

  // final l reduce across the 4 lane-copies of each q, then lane-local epilogue
  l_a += __shfl_xor(l_a, 16);
  l_a += __shfl_xor(l_a, 32);
  l_b += __shfl_xor(l_b, 16);
  l_b += __shfl_xor(l_b, 32);
  float inva = 1.0f / l_a, invb = 1.0f / l_b;
  size_t orowA = ((size_t)(b * 1024 + q0 + wave * 16 + l15)) * 1024 + h * 64;
  size_t orowB = orowA + (size_t)64 * 1024;
#pragma unroll
  for (int dt = 0; dt < 4; ++dt) {
    uint2 wa, wb;
    wa.x = cvtpk(oa[dt][0] * inva, oa[dt][1] * inva);
    wa.y = cvtpk(oa[dt][2] * inva, oa[dt][3] * inva);
    *(uint2*)&O[orowA + dt * 16 + g * 4] = wa;
    wb.x = cvtpk(ob[dt][0] * invb, ob[dt][1] * invb);
    wb.y = cvtpk(ob[dt][2] * invb, ob[dt][3] * invb);
    *(uint2*)&O[orowB + dt * 16 + g * 4] = wb;
  }
}

// ---------- launch ----------
extern "C" void kernel_launch(void* const* d_in, const int* in_sizes, int n_in,
                              void* d_out, int out_size, void* d_ws, size_t ws_size,
                              hipStream_t stream) {
  const float* X = (const float*)d_in[0];
  const int* mask = (const int*)d_in[1];
  const float* wq = (const float*)d_in[2];
  const float* bq = (const float*)d_in[3];
  const float* wk = (const float*)d_in[4];
  const float* bk = (const float*)d_in[5];
  const float* wv = (const float*)d_in[6];
  const float* bv = (const float*)d_in[7];
  const float* wo = (const float*)d_in[8];
  const float* bo = (const float*)d_in[9];
  const float* w1 = (const float*)d_in[10];
  const float* b1 = (const float*)d_in[11];
  const float* w2 = (const float*)d_in[12];
  const float* b2 = (const float*)d_in[13];
  const float* ln1a = (const float*)d_in[14];
  const float* ln1b = (const float*)d_in[15];
  const float* ln2a = (const float*)d_in[16];
  const float* ln2b = (const float*)d_in[17];
  float* out = (float*)d_out;
  char* ws = (char*)d_ws;
  const size_t MB = 1024 * 1024;

  // layout (88MB): [0,8) w1_b | [8,16) w2_b | [16,20) wqk_b | [20,22) wv_b |
  // [22,24) wo_b | [24,40) xn (LN1 out -> attn O -> LN2 out) | [40,72) QKb -> hb |
  // [72,88) Vtb
  unsigned short* w1_b = (unsigned short*)(ws + 0 * MB);
  unsigned short* w2_b = (unsigned short*)(ws + 8 * MB);
  unsigned short* wqk_b = (unsigned short*)(ws + 16 * MB);
  unsigned short* wv_b = (unsigned short*)(ws + 20 * MB);
  unsigned short* wo_b = (unsigned short*)(ws + 22 * MB);
  unsigned short* xn = (unsigned short*)(ws + 24 * MB);
  unsigned short* QKb = (unsigned short*)(ws + 40 * MB);
  unsigned short* Vtb = (unsigned short*)(ws + 72 * MB);
  unsigned short* hb = QKb;

  // all weights -> bf16 in one launch (wq,wk stacked into wqk_b)
  cast_all<<<12288, 256, 0, stream>>>(w1, w2, wq, wk, wv, wo, w1_b, w2_b, wqk_b, wv_b, wo_b);

  // LN1
  ln_bf16<<<8192, 256, 0, stream>>>(X, xn, ln1a, ln1b);
  // fused Q+K projection: QK[token][2048]  (256^2 tile, grid 256 = 1/CU)
  gemm256<0, 1><<<256, 512, 0, stream>>>(xn, wqk_b, bq, bk, 1024, QKb,
                                         8192, 2048, 1024, 1024, 1024);
  // V transposed: Vt[hd][token] = wv @ xn^T + bv (row bias)  (256x128, grid 256)
  gemm256x128<1><<<256, 512, 0, stream>>>(wv_b, xn, bv, nullptr, nullptr, Vtb,
                                          1024, 8192, 1024, 1024, 1024);
  // attention (writes O into xn buffer); 1024 blocks = 4/CU
  attn_fwd6<<<1024, 256, 0, stream>>>(QKb, Vtb, mask, xn);
  // out = X + O @ wo^T + bo  (256x128, grid 256)
  gemm256x128<2><<<256, 512, 0, stream>>>(xn, wo_b, bo, X, out, nullptr,
                                          8192, 1024, 1024, 1024, 1024);
  // LN2 (reads out, writes into xn region)
  ln_bf16<<<8192, 256, 0, stream>>>(out, xn, ln2a, ln2b);
  // FFN chunked along hidden dim: h half = [8192][2048] in hb (QKb region)
  for (int hc = 0; hc < 2; ++hc) {
    // h = relu(xn @ w1[hc*2048:(hc+1)*2048]^T + b1[hc*2048:])  (256^2)
    gemm256<1, 0><<<256, 512, 0, stream>>>(xn, w1_b + (size_t)hc * 2048 * 1024,
                                           b1 + hc * 2048, nullptr, 0, hb,
                                           8192, 2048, 1024, 1024, 1024);
    if (hc == 0)  // out = out + b2 + h_half @ w2[:, 0:2048]^T  (256x128)
      gemm256x128<2><<<256, 512, 0, stream>>>(hb, w2_b, b2, out, out, nullptr,
                                              8192, 1024, 2048, 2048, 4096);
    else          // out += h_half @ w2[:, 2048:4096]^T  (256x128)
      gemm256x128<3><<<256, 512, 0, stream>>>(hb, w2_b + 2048, nullptr, nullptr, out, nullptr,
                                              8192, 1024, 2048, 2048, 4096);
  }
}

// Round 11
// 358.843 us; speedup vs baseline: 1.6248x; 1.0023x over previous
//
#include <hip/hip_runtime.h>
#include <cstdint>
#include <cstddef>

// ---------- types ----------
typedef float f32x4 __attribute__((ext_vector_type(4)));
typedef short bf16x8 __attribute__((ext_vector_type(8)));

typedef __attribute__((address_space(1))) void void_g;
typedef __attribute__((address_space(3))) void void_l;

__device__ __forceinline__ void gld16(const void* g, void* l) {
  // async global->LDS, 16B per lane; LDS dest = wave-uniform base + lane*16
  __builtin_amdgcn_global_load_lds((void_g*)g, (void_l*)l, 16, 0, 0);
}

__device__ __forceinline__ unsigned short f2b(float f) {
  union { float f; uint32_t u; } c; c.f = f;
  uint32_t u = c.u;
  return (unsigned short)((u + 0x7fffu + ((u >> 16) & 1u)) >> 16);  // RNE
}

__device__ __forceinline__ uint32_t cvtpk(float lo, float hi) {
  uint32_t r;
  asm("v_cvt_pk_bf16_f32 %0, %1, %2" : "=v"(r) : "v"(lo), "v"(hi));
  return r;  // low16 = bf16(lo), high16 = bf16(hi)
}

__device__ __forceinline__ float exp2_fast(float x) {
  return __builtin_exp2f(x);  // lowers to v_exp_f32 (2^x) on gfx950
}

// ---------- all weight casts fp32 -> bf16 in one launch ----------
__global__ __launch_bounds__(256) void cast_all(const float* __restrict__ w1,
                                                const float* __restrict__ w2,
                                                const float* __restrict__ wq,
                                                const float* __restrict__ wk,
                                                const float* __restrict__ wv,
                                                const float* __restrict__ wo,
                                                unsigned short* __restrict__ d1,
                                                unsigned short* __restrict__ d2,
                                                unsigned short* __restrict__ dqk,
                                                unsigned short* __restrict__ dv,
                                                unsigned short* __restrict__ dod) {
  int blk = blockIdx.x;
  const float* s;
  unsigned short* d;
  int off;
  if (blk < 4096) { s = w1; d = d1; off = blk; }
  else if (blk < 8192) { s = w2; d = d2; off = blk - 4096; }
  else if (blk < 9216) { s = wq; d = dqk; off = blk - 8192; }
  else if (blk < 10240) { s = wk; d = dqk + (1 << 20); off = blk - 9216; }
  else if (blk < 11264) { s = wv; d = dv; off = blk - 10240; }
  else { s = wo; d = dod; off = blk - 11264; }
  int i = off * 256 + threadIdx.x;
  float4 v = ((const float4*)s)[i];
  ushort4 o;
  o.x = f2b(v.x); o.y = f2b(v.y); o.z = f2b(v.z); o.w = f2b(v.w);
  ((ushort4*)d)[i] = o;
}

// ---------- LayerNorm (unbiased std, scalar alpha/beta) -> bf16 ----------
__global__ __launch_bounds__(256) void ln_bf16(const float* __restrict__ X,
                                               unsigned short* __restrict__ out,
                                               const float* __restrict__ alpha,
                                               const float* __restrict__ beta) {
  int row = blockIdx.x;
  int tid = threadIdx.x;
  float4 v = ((const float4*)(X + (size_t)row * 1024))[tid];
  float s = v.x + v.y + v.z + v.w;
  float q = v.x * v.x + v.y * v.y + v.z * v.z + v.w * v.w;
#pragma unroll
  for (int m = 1; m < 64; m <<= 1) { s += __shfl_xor(s, m); q += __shfl_xor(q, m); }
  __shared__ float red[8];
  int wave = tid >> 6;
  if ((tid & 63) == 0) { red[wave] = s; red[4 + wave] = q; }
  __syncthreads();
  s = red[0] + red[1] + red[2] + red[3];
  q = red[4] + red[5] + red[6] + red[7];
  float mean = s * (1.0f / 1024.0f);
  float var = fmaxf((q - 1024.0f * mean * mean) * (1.0f / 1023.0f), 0.0f);
  float inv = alpha[0] / (sqrtf(var) + 1e-6f);
  float b = beta[0];
  ushort4 o;
  o.x = f2b((v.x - mean) * inv + b);
  o.y = f2b((v.y - mean) * inv + b);
  o.z = f2b((v.z - mean) * inv + b);
  o.w = f2b((v.w - mean) * inv + b);
  ((ushort4*)(out + (size_t)row * 1024))[tid] = o;
}

// ---------- GEMM 256x256 8-wave, BK=64, counted-vmcnt + frag-prefetch pipeline ----------
template <int RELU, int BIAS2>
__global__ __launch_bounds__(512, 1) void gemm256(const unsigned short* __restrict__ A,
                                                  const unsigned short* __restrict__ W,
                                                  const float* __restrict__ bias,
                                                  const float* __restrict__ bias2, int b2off,
                                                  unsigned short* __restrict__ outB,
                                                  int M, int N, int K, int sA, int sW) {
  __shared__ unsigned short lds[2][4][128 * 64];  // 128 KB
  int nbn = N >> 8;
  int nwg = gridDim.x;
  int bid = blockIdx.x;
  int wg = (bid & 7) * (nwg >> 3) + (bid >> 3);  // XCD swizzle (nwg % 8 == 0)
  int tm = wg / nbn, tn = wg % nbn;
  int tid = threadIdx.x;
  int wave = tid >> 6, lane = tid & 63;
  int wr = wave >> 2, wc = wave & 3;  // 2 x 4 wave grid; per-wave C = 128 x 64
  int l15 = lane & 15, g = lane >> 4;
  int nt = K >> 6;

  const unsigned short* Abase = A + (size_t)(tm * 256) * sA;
  const unsigned short* Wbase = W + (size_t)(tn * 256) * sW;
  int srow = tid >> 3;
  int schunk = (tid & 7) ^ (srow & 7);

  f32x4 acc[8][4] = {};
  bf16x8 afrA[2][2], afrB[2][2], bfr[2][4];

  auto stage = [&](int buf, int s, int kt) {
    const unsigned short* base = (s < 2) ? Abase : Wbase;
    int str = (s < 2) ? sA : sW;
    int rbase = (s & 1) * 128;
#pragma unroll
    for (int e = 0; e < 2; ++e) {
      gld16(base + (size_t)(rbase + srow + e * 64) * str + kt * 64 + schunk * 8,
            &lds[buf][s][wave * 512 + e * 4096]);
    }
  };
  auto readB = [&](int buf) {
    const unsigned short* Bh = &lds[buf][2 + (wc >> 1)][0];
#pragma unroll
    for (int kk = 0; kk < 2; ++kk)
#pragma unroll
      for (int j = 0; j < 4; ++j) {
        int br = (wc & 1) * 64 + j * 16 + l15;
        bfr[kk][j] = *(const bf16x8*)&Bh[br * 64 + (((kk * 4 + g) ^ (br & 7)) * 8)];
      }
  };
  auto readA = [&](bf16x8 (&dst)[2][2], int buf, int q) {
    const unsigned short* Ah = &lds[buf][wr][0];
#pragma unroll
    for (int kk = 0; kk < 2; ++kk)
#pragma unroll
      for (int ri = 0; ri < 2; ++ri) {
        int ar = q * 32 + ri * 16 + l15;
        dst[kk][ri] = *(const bf16x8*)&Ah[ar * 64 + (((kk * 4 + g) ^ (ar & 7)) * 8)];
      }
  };
  auto mfma16 = [&](bf16x8 (&af)[2][2], int q) {
    __builtin_amdgcn_s_setprio(1);
#pragma unroll
    for (int kk = 0; kk < 2; ++kk)
#pragma unroll
      for (int ri = 0; ri < 2; ++ri)
#pragma unroll
        for (int j = 0; j < 4; ++j)
          acc[q * 2 + ri][j] = __builtin_amdgcn_mfma_f32_16x16x32_bf16(
              af[kk][ri], bfr[kk][j], acc[q * 2 + ri][j], 0, 0, 0);
    __builtin_amdgcn_s_setprio(0);
  };

  stage(0, 2, 0); stage(0, 3, 0); stage(0, 0, 0); stage(0, 1, 0);
  stage(1, 2, 1); stage(1, 3, 1);
  asm volatile("s_waitcnt vmcnt(4)" ::: "memory");
  __builtin_amdgcn_s_barrier();

  for (int t = 0; t < nt; ++t) {
    int buf = t & 1;
    // phase 0: B frags + afrA(q0) + prefetch afrB(q1)
    __builtin_amdgcn_sched_barrier(0);
    if (t + 1 < nt) stage(buf ^ 1, 0, t + 1);
    readB(buf);
    readA(afrA, buf, 0);
    readA(afrB, buf, 1);
    mfma16(afrA, 0);
    __builtin_amdgcn_s_barrier();
    // phase 1: prefetch afrA(q2)
    __builtin_amdgcn_sched_barrier(0);
    if (t + 1 < nt) stage(buf ^ 1, 1, t + 1);
    readA(afrA, buf, 2);
    mfma16(afrB, 1);
    __builtin_amdgcn_s_barrier();
    // phase 2: prefetch afrB(q3)
    __builtin_amdgcn_sched_barrier(0);
    if (t + 2 < nt) stage(buf, 2, t + 2);
    readA(afrB, buf, 3);
    mfma16(afrA, 2);
    __builtin_amdgcn_s_barrier();
    // phase 3: no ds_reads; MFMA covers vmcnt drain
    __builtin_amdgcn_sched_barrier(0);
    if (t + 2 < nt) stage(buf, 3, t + 2);
    mfma16(afrB, 3);
    if (t + 2 < nt) asm volatile("s_waitcnt vmcnt(4)" ::: "memory");
    else asm volatile("s_waitcnt vmcnt(0)" ::: "memory");
    __builtin_amdgcn_s_barrier();
  }

  int row0 = tm * 256 + wr * 128 + g * 4;
  int col0 = tn * 256 + wc * 64 + l15;
#pragma unroll
  for (int i = 0; i < 8; ++i) {
#pragma unroll
    for (int j = 0; j < 4; ++j) {
      int col = col0 + j * 16;
      float bb = (BIAS2 && col >= b2off) ? bias2[col - b2off] : bias[col];
#pragma unroll
      for (int r = 0; r < 4; ++r) {
        int row = row0 + i * 16 + r;
        float v = acc[i][j][r] + bb;
        if (RELU) v = fmaxf(v, 0.0f);
        outB[(size_t)row * N + col] = f2b(v);
      }
    }
  }
}

// ---------- GEMM 256x128 8-wave, BK=64, counted-vmcnt + frag-prefetch ----------
// MODE: 1 = bf16 out + row bias; 2 = fp32 out = resid + v + col bias; 3 = fp32 out += v.
template <int MODE>
__global__ __launch_bounds__(512, 1) void gemm256x128(const unsigned short* __restrict__ A,
                                                      const unsigned short* __restrict__ W,
                                                      const float* __restrict__ bias,
                                                      const float* __restrict__ resid,
                                                      float* __restrict__ outF,
                                                      unsigned short* __restrict__ outB,
                                                      int M, int N, int K, int sA, int sW) {
  __shared__ unsigned short lds[2][3][128 * 64];  // 96 KB
  int nbn = N >> 7;
  int nwg = gridDim.x;
  int bid = blockIdx.x;
  int wg = (bid & 7) * (nwg >> 3) + (bid >> 3);  // XCD swizzle (nwg % 8 == 0)
  int tm = wg / nbn, tn = wg % nbn;
  int tid = threadIdx.x;
  int wave = tid >> 6, lane = tid & 63;
  int wr = wave >> 2, wc = wave & 3;  // per-wave C = 128 rows x 32 cols
  int l15 = lane & 15, g = lane >> 4;
  int nt = K >> 6;

  const unsigned short* Abase = A + (size_t)(tm * 256) * sA;
  const unsigned short* Wbase = W + (size_t)(tn * 128) * sW;
  int srow = tid >> 3;
  int schunk = (tid & 7) ^ (srow & 7);

  f32x4 acc[8][2] = {};
  bf16x8 afrA[2][2], afrB[2][2], bfr[2][2];

  auto stage = [&](int buf, int s, int kt) {
    const unsigned short* base = (s < 2) ? Abase : Wbase;
    int str = (s < 2) ? sA : sW;
    int rbase = (s & 1) * 128;  // s=2 -> 0
#pragma unroll
    for (int e = 0; e < 2; ++e) {
      gld16(base + (size_t)(rbase + srow + e * 64) * str + kt * 64 + schunk * 8,
            &lds[buf][s][wave * 512 + e * 4096]);
    }
  };
  auto readB = [&](int buf) {
    const unsigned short* Bh = &lds[buf][2][0];
#pragma unroll
    for (int kk = 0; kk < 2; ++kk)
#pragma unroll
      for (int j = 0; j < 2; ++j) {
        int br = wc * 32 + j * 16 + l15;
        bfr[kk][j] = *(const bf16x8*)&Bh[br * 64 + (((kk * 4 + g) ^ (br & 7)) * 8)];
      }
  };
  auto readA = [&](bf16x8 (&dst)[2][2], int buf, int q) {
    const unsigned short* Ah = &lds[buf][wr][0];
#pragma unroll
    for (int kk = 0; kk < 2; ++kk)
#pragma unroll
      for (int ri = 0; ri < 2; ++ri) {
        int ar = q * 32 + ri * 16 + l15;
        dst[kk][ri] = *(const bf16x8*)&Ah[ar * 64 + (((kk * 4 + g) ^ (ar & 7)) * 8)];
      }
  };
  auto mfma8 = [&](bf16x8 (&af)[2][2], int q) {
    __builtin_amdgcn_s_setprio(1);
#pragma unroll
    for (int kk = 0; kk < 2; ++kk)
#pragma unroll
      for (int ri = 0; ri < 2; ++ri)
#pragma unroll
        for (int j = 0; j < 2; ++j)
          acc[q * 2 + ri][j] = __builtin_amdgcn_mfma_f32_16x16x32_bf16(
              af[kk][ri], bfr[kk][j], acc[q * 2 + ri][j], 0, 0, 0);
    __builtin_amdgcn_s_setprio(0);
  };

  stage(0, 2, 0); stage(0, 0, 0); stage(0, 1, 0);
  stage(1, 2, 1);
  asm volatile("s_waitcnt vmcnt(2)" ::: "memory");
  __builtin_amdgcn_s_barrier();

  for (int t = 0; t < nt; ++t) {
    int buf = t & 1;
    // phase 0
    __builtin_amdgcn_sched_barrier(0);
    if (t + 1 < nt) stage(buf ^ 1, 0, t + 1);
    readB(buf);
    readA(afrA, buf, 0);
    readA(afrB, buf, 1);
    mfma8(afrA, 0);
    __builtin_amdgcn_s_barrier();
    // phase 1
    __builtin_amdgcn_sched_barrier(0);
    if (t + 1 < nt) stage(buf ^ 1, 1, t + 1);
    readA(afrA, buf, 2);
    mfma8(afrB, 1);
    __builtin_amdgcn_s_barrier();
    // phase 2
    __builtin_amdgcn_sched_barrier(0);
    if (t + 2 < nt) stage(buf, 2, t + 2);
    readA(afrB, buf, 3);
    mfma8(afrA, 2);
    __builtin_amdgcn_s_barrier();
    // phase 3: no ds_reads
    __builtin_amdgcn_sched_barrier(0);
    mfma8(afrB, 3);
    if (t + 2 < nt) asm volatile("s_waitcnt vmcnt(2)" ::: "memory");
    else asm volatile("s_waitcnt vmcnt(0)" ::: "memory");
    __builtin_amdgcn_s_barrier();
  }

  int row0 = tm * 256 + wr * 128 + g * 4;
  int col0 = tn * 128 + wc * 32 + l15;
#pragma unroll
  for (int i = 0; i < 8; ++i) {
#pragma unroll
    for (int j = 0; j < 2; ++j) {
      int col = col0 + j * 16;
      float cb = (MODE == 2) ? bias[col] : 0.0f;
#pragma unroll
      for (int r = 0; r < 4; ++r) {
        int row = row0 + i * 16 + r;
        size_t idx = (size_t)row * N + col;
        float v = acc[i][j][r];
        if (MODE == 1) outB[idx] = f2b(v + bias[row]);
        else if (MODE == 2) outF[idx] = resid[idx] + v + cb;
        else outF[idx] += v;
      }
    }
  }
}

// ---------- flash attention v7: 8 waves x 16 q-rows (512 thr), no-max softmax ----------
// QK [tok][2048] bf16 (Q cols 0-1023, K cols 1024-2047), Vt [h*64+d][tok] bf16.
// 1 block = (b,h,128-row q-tile); 8 waves, each owns q rows q0+wave*16+l15 (one set).
// Halved per-wave critical path + 2x resident waves vs v6 for latency hiding.
// K/V staged once per block per kt (each of 512 threads issues 1 K + 1 V gld16).
__global__ __launch_bounds__(512, 6) void attn_fwd7(const unsigned short* __restrict__ QK,
                                                    const unsigned short* __restrict__ Vt,
                                                    const int* __restrict__ mask,
                                                    unsigned short* __restrict__ O) {
  __shared__ unsigned short Kl[2][64 * 64];
  __shared__ unsigned short Vl[2][64 * 64];
  __shared__ float biasl[1024];
  int bid = blockIdx.x;
  int wg = (bid & 7) * 128 + (bid >> 3);  // XCD swizzle (nwg = 1024)
  int qt = wg & 7, bh = wg >> 3;
  int b = bh >> 4, h = bh & 15;
  int tid = threadIdx.x, wave = tid >> 6, lane = tid & 63;
  int l15 = lane & 15, g = lane >> 4;
  int q0 = qt * 128;

  for (int i = tid; i < 1024; i += 512)
    biasl[i] = (mask[b * 1024 + i] == 0) ? -1.4426950e9f : 0.0f;

  const unsigned short* Qrow = QK + ((size_t)(b * 1024 + q0 + wave * 16 + l15)) * 2048 + h * 64;
  bf16x8 qf0 = *(const bf16x8*)(Qrow + g * 8);
  bf16x8 qf1 = *(const bf16x8*)(Qrow + 32 + g * 8);

  float l_q = 0.0f;   // lane-partial softmax denominator (q = l15)
  f32x4 o[4] = {};    // o[dt][r] = O[q=l15][d = dt*16 + g*4 + r]

  int srow = tid >> 3;              // 0..63: staged row
  int clog = (tid & 7) ^ (srow & 7);  // inverse-swizzled chunk
  int h7 = l15 & 7;
  const float SC = 0.125f * 1.44269504f;  // 1/sqrt(64) * log2(e)

  auto stageKV = [&](int buf, int kt) {
    gld16(QK + ((size_t)(b * 1024 + kt * 64 + srow)) * 2048 + 1024 + h * 64 + clog * 8,
          &Kl[buf][(wave * 8) * 64]);
    gld16(Vt + ((size_t)(h * 64 + srow)) * 8192 + b * 1024 + kt * 64 + clog * 8,
          &Vl[buf][(wave * 8) * 64]);
  };

  stageKV(0, 0);
  __syncthreads();
  int cur = 0;

  for (int kt = 0; kt < 16; ++kt) {
    if (kt < 15) stageKV(cur ^ 1, kt + 1);

    // S^T[key][q] = mfma(A=K, B=Q): lane holds q=l15, keys j*16+g*4+r
    f32x4 st[4];
    __builtin_amdgcn_s_setprio(1);
#pragma unroll
    for (int j = 0; j < 4; ++j) {
      int kr = j * 16 + l15;
      bf16x8 ka = *(const bf16x8*)&Kl[cur][kr * 64 + ((g ^ h7) * 8)];
      bf16x8 kb = *(const bf16x8*)&Kl[cur][kr * 64 + (((4 + g) ^ h7) * 8)];
      f32x4 z = {};
      st[j] = __builtin_amdgcn_mfma_f32_16x16x32_bf16(ka, qf0, z, 0, 0, 0);
      st[j] = __builtin_amdgcn_mfma_f32_16x16x32_bf16(kb, qf1, st[j], 0, 0, 0);
    }
    __builtin_amdgcn_s_setprio(0);

    // P = exp2(score*SC + maskbias); lane-partial l; pack via cvt_pk
    union U8 { uint32_t u[4]; bf16x8 v; } pa[2];
#pragma unroll
    for (int j = 0; j < 4; ++j) {
      float4 b4 = *(const float4*)&biasl[kt * 64 + j * 16 + g * 4];
      float e0 = exp2_fast(st[j][0] * SC + b4.x);
      float e1 = exp2_fast(st[j][1] * SC + b4.y);
      float e2 = exp2_fast(st[j][2] * SC + b4.z);
      float e3 = exp2_fast(st[j][3] * SC + b4.w);
      l_q += (e0 + e1) + (e2 + e3);
      pa[j >> 1].u[(j & 1) * 2 + 0] = cvtpk(e0, e1);
      pa[j >> 1].u[(j & 1) * 2 + 1] = cvtpk(e2, e3);
    }

    // PV: O^T = mfma(A=V^T, B=P), same permuted key order on both operands
    __builtin_amdgcn_s_setprio(1);
#pragma unroll
    for (int kk = 0; kk < 2; ++kk) {
#pragma unroll
      for (int dt = 0; dt < 4; ++dt) {
        int vr = dt * 16 + l15;
        uint2 lo = *(const uint2*)&Vl[cur][vr * 64 + (((4 * kk + (g >> 1)) ^ h7) * 8) + (g & 1) * 4];
        uint2 hi = *(const uint2*)&Vl[cur][vr * 64 + (((4 * kk + 2 + (g >> 1)) ^ h7) * 8) + (g & 1) * 4];
        union U8 vbu;
        vbu.u[0] = lo.x; vbu.u[1] = lo.y; vbu.u[2] = hi.x; vbu.u[3] = hi.y;
        o[dt] = __builtin_amdgcn_mfma_f32_16x16x32_bf16(vbu.v, pa[kk].v, o[dt], 0, 0, 0);
      }
    }
    __builtin_amdgcn_s_setprio(0);

    __syncthreads();
    cur ^= 1;
  }

  // final l reduce across the 4 lane-copies of q=l15, then lane-local epilogue
  l_q += __shfl_xor(l_q, 16);
  l_q += __shfl_xor(l_q, 32);
  float inv = 1.0f / l_q;
  size_t orow = ((size_t)(b * 1024 + q0 + wave * 16 + l15)) * 1024 + h * 64;
#pragma unroll
  for (int dt = 0; dt < 4; ++dt) {
    uint2 w;
    w.x = cvtpk(o[dt][0] * inv, o[dt][1] * inv);
    w.y = cvtpk(o[dt][2] * inv, o[dt][3] * inv);
    *(uint2*)&O[orow + dt * 16 + g * 4] = w;
  }
}

// ---------- launch ----------
extern "C" void kernel_launch(void* const* d_in, const int* in_sizes, int n_in,
                              void* d_out, int out_size, void* d_ws, size_t ws_size,
                              hipStream_t stream) {
  const float* X = (const float*)d_in[0];
  const int* mask = (const int*)d_in[1];
  const float* wq = (const float*)d_in[2];
  const float* bq = (const float*)d_in[3];
  const float* wk = (const float*)d_in[4];
  const float* bk = (const float*)d_in[5];
  const float* wv = (const float*)d_in[6];
  const float* bv = (const float*)d_in[7];
  const float* wo = (const float*)d_in[8];
  const float* bo = (const float*)d_in[9];
  const float* w1 = (const float*)d_in[10];
  const float* b1 = (const float*)d_in[11];
  const float* w2 = (const float*)d_in[12];
  const float* b2 = (const float*)d_in[13];
  const float* ln1a = (const float*)d_in[14];
  const float* ln1b = (const float*)d_in[15];
  const float* ln2a = (const float*)d_in[16];
  const float* ln2b = (const float*)d_in[17];
  float* out = (float*)d_out;
  char* ws = (char*)d_ws;
  const size_t MB = 1024 * 1024;

  // layout (88MB): [0,8) w1_b | [8,16) w2_b | [16,20) wqk_b | [20,22) wv_b |
  // [22,24) wo_b | [24,40) xn (LN1 out -> attn O -> LN2 out) | [40,72) QKb -> hb |
  // [72,88) Vtb
  unsigned short* w1_b = (unsigned short*)(ws + 0 * MB);
  unsigned short* w2_b = (unsigned short*)(ws + 8 * MB);
  unsigned short* wqk_b = (unsigned short*)(ws + 16 * MB);
  unsigned short* wv_b = (unsigned short*)(ws + 20 * MB);
  unsigned short* wo_b = (unsigned short*)(ws + 22 * MB);
  unsigned short* xn = (unsigned short*)(ws + 24 * MB);
  unsigned short* QKb = (unsigned short*)(ws + 40 * MB);
  unsigned short* Vtb = (unsigned short*)(ws + 72 * MB);
  unsigned short* hb = QKb;

  // all weights -> bf16 in one launch (wq,wk stacked into wqk_b)
  cast_all<<<12288, 256, 0, stream>>>(w1, w2, wq, wk, wv, wo, w1_b, w2_b, wqk_b, wv_b, wo_b);

  // LN1
  ln_bf16<<<8192, 256, 0, stream>>>(X, xn, ln1a, ln1b);
  // fused Q+K projection: QK[token][2048]  (256^2 tile, grid 256 = 1/CU)
  gemm256<0, 1><<<256, 512, 0, stream>>>(xn, wqk_b, bq, bk, 1024, QKb,
                                         8192, 2048, 1024, 1024, 1024);
  // V transposed: Vt[hd][token] = wv @ xn^T + bv (row bias)  (256x128, grid 256)
  gemm256x128<1><<<256, 512, 0, stream>>>(wv_b, xn, bv, nullptr, nullptr, Vtb,
                                          1024, 8192, 1024, 1024, 1024);
  // attention (writes O into xn buffer); 1024 blocks x 512 thr = 4 blocks/CU
  attn_fwd7<<<1024, 512, 0, stream>>>(QKb, Vtb, mask, xn);
  // out = X + O @ wo^T + bo  (256x128, grid 256)
  gemm256x128<2><<<256, 512, 0, stream>>>(xn, wo_b, bo, X, out, nullptr,
                                          8192, 1024, 1024, 1024, 1024);
  // LN2 (reads out, writes into xn region)
  ln_bf16<<<8192, 256, 0, stream>>>(out, xn, ln2a, ln2b);
  // FFN chunked along hidden dim: h half = [8192][2048] in hb (QKb region)
  for (int hc = 0; hc < 2; ++hc) {
    // h = relu(xn @ w1[hc*2048:(hc+1)*2048]^T + b1[hc*2048:])  (256^2)
    gemm256<1, 0><<<256, 512, 0, stream>>>(xn, w1_b + (size_t)hc * 2048 * 1024,
                                           b1 + hc * 2048, nullptr, 0, hb,
                                           8192, 2048, 1024, 1024, 1024);
    if (hc == 0)  // out = out + b2 + h_half @ w2[:, 0:2048]^T  (256x128)
      gemm256x128<2><<<256, 512, 0, stream>>>(hb, w2_b, b2, out, out, nullptr,
                                              8192, 1024, 2048, 2048, 4096);
    else          // out += h_half @ w2[:, 2048:4096]^T  (256x128)
      gemm256x128<3><<<256, 512, 0, stream>>>(hb, w2_b + 2048, nullptr, nullptr, out, nullptr,
                                              8192, 1024, 2048, 2048, 4096);
  }
}